// Round 2
// baseline (4540.709 us; speedup 1.0000x reference)
//
#include <hip/hip_runtime.h>
#include <cstdint>
#include <cstddef>

#define NAT 16384
#define NED 65536
#define ETOT (NED + NAT)
#define BGR 256
#define MAXQ 64
#define FIN 64
#define HID 256
#define LPN 1024
#define HD 64

// ---------------- sortable-uint float encoding for atomicMax ----------------
__device__ __forceinline__ unsigned f2s(float f) {
    unsigned u = __float_as_uint(f);
    return (u & 0x80000000u) ? ~u : (u | 0x80000000u);
}
__device__ __forceinline__ float s2f(unsigned u) {
    return (u & 0x80000000u) ? __uint_as_float(u ^ 0x80000000u) : __uint_as_float(~u);
}

// ---------------- generic fp32 GEMM: C = act(A@B + bias) ----------------
// A[M,K] row-major, B[K,N] row-major. M%64==0, K%16==0, N arbitrary (guarded).
// ACT: 0 none, 1 relu, 2 gelu(exact)
template<int ACT>
__global__ __launch_bounds__(256) void gemm_k(const float* __restrict__ A,
    const float* __restrict__ Bm, const float* __restrict__ bias,
    float* __restrict__ C, int M, int Nn, int K)
{
    __shared__ float As[16][68];
    __shared__ float Bs[16][68];
    const int t  = threadIdx.x;
    const int m0 = blockIdx.y * 64, n0 = blockIdx.x * 64;
    const int tm = (t & 15) * 4, tn = (t >> 4) * 4;
    const int lm = t >> 2,  lkc = (t & 3) * 4;
    const int lkk = t >> 4, lnc = (t & 15) * 4;
    float acc[4][4] = {};
    for (int k0 = 0; k0 < K; k0 += 16) {
        float4 av = *(const float4*)(A + (size_t)(m0 + lm) * K + k0 + lkc);
        As[lkc + 0][lm] = av.x; As[lkc + 1][lm] = av.y;
        As[lkc + 2][lm] = av.z; As[lkc + 3][lm] = av.w;
        if (n0 + lnc + 3 < Nn) {
            float4 bv = *(const float4*)(Bm + (size_t)(k0 + lkk) * Nn + n0 + lnc);
            Bs[lkk][lnc + 0] = bv.x; Bs[lkk][lnc + 1] = bv.y;
            Bs[lkk][lnc + 2] = bv.z; Bs[lkk][lnc + 3] = bv.w;
        } else {
            for (int j = 0; j < 4; j++) {
                int n = n0 + lnc + j;
                Bs[lkk][lnc + j] = (n < Nn) ? Bm[(size_t)(k0 + lkk) * Nn + n] : 0.f;
            }
        }
        __syncthreads();
#pragma unroll
        for (int kk = 0; kk < 16; kk++) {
            float4 af = *(const float4*)&As[kk][tm];
            float4 bf = *(const float4*)&Bs[kk][tn];
            float a_[4] = {af.x, af.y, af.z, af.w};
            float b_[4] = {bf.x, bf.y, bf.z, bf.w};
#pragma unroll
            for (int i = 0; i < 4; i++)
#pragma unroll
                for (int j = 0; j < 4; j++) acc[i][j] += a_[i] * b_[j];
        }
        __syncthreads();
    }
#pragma unroll
    for (int i = 0; i < 4; i++) {
#pragma unroll
        for (int j = 0; j < 4; j++) {
            int n = n0 + tn + j;
            if (n < Nn) {
                float v = acc[i][j] + (bias ? bias[n] : 0.f);
                if (ACT == 1) v = fmaxf(v, 0.f);
                if (ACT == 2) v = 0.5f * v * (1.f + erff(v * 0.70710678118654752f));
                C[(size_t)(m0 + tm + i) * Nn + n] = v;
            }
        }
    }
}

// ---------------- conv1d as implicit GEMM with fused embedding gather ----------------
// Processes a chunk: local rows [0, CB*1024), global graph = b_base + local_row/1024.
__global__ __launch_bounds__(256) void conv_k(const int* __restrict__ seq,
    const float* __restrict__ emb, const float* __restrict__ wt,
    const float* __restrict__ bias, float* __restrict__ C, int b_base)
{
    __shared__ float As[16][68];
    __shared__ float Bs[16][68];
    __shared__ int toks[66];
    const int t  = threadIdx.x;
    const int m0 = blockIdx.y * 64, n0 = blockIdx.x * 64;
    const int b  = b_base + (m0 >> 10), l0 = m0 & 1023;
    if (t < 66) {
        int l = l0 + t - 1;
        toks[t] = (l >= 0 && l < LPN) ? seq[b * LPN + l] : -1;
    }
    const int tm = (t & 15) * 4, tn = (t >> 4) * 4;
    const int lm = t >> 2,  lkc = (t & 3) * 4;
    const int lkk = t >> 4, lnc = (t & 15) * 4;
    float acc[4][4] = {};
    __syncthreads();
    for (int k0 = 0; k0 < 768; k0 += 16) {
        int dl = k0 >> 8;
        int tok = toks[lm + dl];
        float4 av = make_float4(0.f, 0.f, 0.f, 0.f);
        if (tok >= 0) av = *(const float4*)(emb + (size_t)tok * HID + (k0 & 255) + lkc);
        As[lkc + 0][lm] = av.x; As[lkc + 1][lm] = av.y;
        As[lkc + 2][lm] = av.z; As[lkc + 3][lm] = av.w;
        float4 bv = *(const float4*)(wt + (size_t)(k0 + lkk) * 256 + n0 + lnc);
        Bs[lkk][lnc + 0] = bv.x; Bs[lkk][lnc + 1] = bv.y;
        Bs[lkk][lnc + 2] = bv.z; Bs[lkk][lnc + 3] = bv.w;
        __syncthreads();
#pragma unroll
        for (int kk = 0; kk < 16; kk++) {
            float4 af = *(const float4*)&As[kk][tm];
            float4 bf = *(const float4*)&Bs[kk][tn];
            float a_[4] = {af.x, af.y, af.z, af.w};
            float b_[4] = {bf.x, bf.y, bf.z, bf.w};
#pragma unroll
            for (int i = 0; i < 4; i++)
#pragma unroll
                for (int j = 0; j < 4; j++) acc[i][j] += a_[i] * b_[j];
        }
        __syncthreads();
    }
#pragma unroll
    for (int i = 0; i < 4; i++)
#pragma unroll
        for (int j = 0; j < 4; j++) {
            int n = n0 + tn + j;
            float v = fmaxf(acc[i][j] + bias[n], 0.f);
            C[(size_t)(m0 + tm + i) * 256 + n] = v;
        }
}

// wt[(dl*256+kk)*256+n] = conv_w[n*768 + kk*3 + dl]
__global__ void transw_k(const float* __restrict__ cw, float* __restrict__ wt)
{
    int tid = blockIdx.x * 256 + threadIdx.x;       // < 196608
    int dl = tid / 65536; int r = tid & 65535;
    int kk = r >> 8; int n = r & 255;
    wt[tid] = cw[(size_t)n * 768 + kk * 3 + dl];
}

// ---------------- GAT pieces ----------------
__global__ __launch_bounds__(256) void asad_k(const float* __restrict__ hg,
    const float* __restrict__ as_, const float* __restrict__ ad_,
    float* __restrict__ a_s, float* __restrict__ a_d)
{
    int n = blockIdx.x, t = threadIdx.x;
    float h0 = hg[(size_t)n * 512 + t];
    float h1 = hg[(size_t)n * 512 + 256 + t];
    float p0 = h0 * as_[t], p1 = h1 * as_[256 + t];
    float p2 = h0 * ad_[t], p3 = h1 * ad_[256 + t];
#pragma unroll
    for (int off = 32; off >= 1; off >>= 1) {
        p0 += __shfl_down(p0, off, 64);
        p1 += __shfl_down(p1, off, 64);
        p2 += __shfl_down(p2, off, 64);
        p3 += __shfl_down(p3, off, 64);
    }
    __shared__ float red[4][4];
    int wave = t >> 6, lane = t & 63;
    if (lane == 0) { red[wave][0] = p0; red[wave][1] = p1; red[wave][2] = p2; red[wave][3] = p3; }
    __syncthreads();
    if (t < 4) {
        float v = red[0][t] + red[1][t] + red[2][t] + red[3][t];
        if (t == 0) a_s[n * 2 + 0] = v;
        if (t == 1) a_s[n * 2 + 1] = v;
        if (t == 2) a_d[n * 2 + 0] = v;
        if (t == 3) a_d[n * 2 + 1] = v;
    }
}

__global__ void edge1_k(const int* __restrict__ ei, const float* __restrict__ a_s,
    const float* __restrict__ a_d, float* __restrict__ ebuf, unsigned* __restrict__ emaxU)
{
    int e = blockIdx.x * 256 + threadIdx.x;
    if (e >= ETOT) return;
    int s, d;
    if (e < NED) { s = ei[e]; d = ei[NED + e]; } else { s = d = e - NED; }
#pragma unroll
    for (int g = 0; g < 2; g++) {
        float v = a_s[s * 2 + g] + a_d[d * 2 + g];
        v = (v > 0.f) ? v : 0.2f * v;
        ebuf[(size_t)e * 2 + g] = v;
        atomicMax(&emaxU[d * 2 + g], f2s(v));
    }
}

__global__ void edge2_k(const int* __restrict__ ei, const float* __restrict__ ebuf,
    const unsigned* __restrict__ emaxU, float* __restrict__ exbuf, float* __restrict__ den)
{
    int e = blockIdx.x * 256 + threadIdx.x;
    if (e >= ETOT) return;
    int d;
    if (e < NED) { d = ei[NED + e]; } else { d = e - NED; }
#pragma unroll
    for (int g = 0; g < 2; g++) {
        float mx = s2f(emaxU[d * 2 + g]);
        float ex = __expf(ebuf[(size_t)e * 2 + g] - mx);
        exbuf[(size_t)e * 2 + g] = ex;
        atomicAdd(&den[d * 2 + g], ex);
    }
}

__global__ __launch_bounds__(512) void edge3_k(const int* __restrict__ ei,
    const float* __restrict__ hg, const float* __restrict__ exbuf,
    const float* __restrict__ den, float* __restrict__ og)
{
    int e = blockIdx.x;
    int ch = threadIdx.x;     // 0..511
    int s, d;
    if (e < NED) { s = ei[e]; d = ei[NED + e]; } else { s = d = e - NED; }
    int g = ch >> 8;
    float alpha = exbuf[(size_t)e * 2 + g] / den[d * 2 + g];
    atomicAdd(&og[(size_t)d * 512 + ch], hg[(size_t)s * 512 + ch] * alpha);
}

// elu(mean over heads + bias)
__global__ void gatfin_k(const float* __restrict__ og, const float* __restrict__ bias,
                         float* __restrict__ out)
{
    int n = blockIdx.x, c = threadIdx.x;
    float v = 0.5f * (og[(size_t)n * 512 + c] + og[(size_t)n * 512 + 256 + c]) + bias[c];
    out[(size_t)n * 256 + c] = (v > 0.f) ? v : expm1f(v);
}

// ---------------- fused cross-attention (online softmax) ----------------
// block = (local b, h). Q scaled by 1/8 at load. K tiles of 64 over LP=1024.
// K/V buffers are chunk-local (graph b0+bl at local row bl). LDS kept < 64 KB
// by aliasing the P tile onto the K tile (K reads complete before P writes).
__global__ __launch_bounds__(256) void attn_k(const float* __restrict__ Q,
    const float* __restrict__ Kp, const float* __restrict__ Vp,
    const int* __restrict__ seq, float* __restrict__ O, int b0)
{
    __shared__ float Qs[64][68], Ks[64][68], Vs[64][68];
    __shared__ float stats[64][17];
    __shared__ float m_run[64], l_run[64], alpha_s[64], mnew_s[64], mask_s[64];
    float (*Ps)[68] = Ks;   // alias: P tile reuses K tile storage
    const int t = threadIdx.x;
    const int bl = blockIdx.x >> 2, h = blockIdx.x & 3;
    const int b = b0 + bl;
    const int qt = (t & 15) * 4, dt = (t >> 4) * 4;
    const int lr = t >> 4, lc = (t & 15) * 4;
#pragma unroll
    for (int p = 0; p < 4; p++) {
        int q = lr + p * 16;
        float4 v = *(const float4*)(Q + (size_t)(b * 64 + q) * HID + h * HD + lc);
        Qs[lc + 0][q] = v.x * 0.125f; Qs[lc + 1][q] = v.y * 0.125f;
        Qs[lc + 2][q] = v.z * 0.125f; Qs[lc + 3][q] = v.w * 0.125f;
    }
    if (t < 64) { m_run[t] = -3e38f; l_run[t] = 0.f; }
    float ctx[4][4] = {};
    __syncthreads();
    for (int kp0 = 0; kp0 < LPN; kp0 += 64) {
#pragma unroll
        for (int p = 0; p < 4; p++) {
            int kk = lr + p * 16;
            size_t row = (size_t)(bl * LPN + kp0 + kk) * HID + h * HD + lc;
            float4 kv = *(const float4*)(Kp + row);
            Ks[lc + 0][kk] = kv.x; Ks[lc + 1][kk] = kv.y;
            Ks[lc + 2][kk] = kv.z; Ks[lc + 3][kk] = kv.w;
            float4 vv = *(const float4*)(Vp + row);
            *(float4*)&Vs[kk][lc] = vv;
        }
        if (t < 64) mask_s[t] = (seq[b * LPN + kp0 + t] == 0) ? -1e9f : 0.f;
        __syncthreads();
        float S[4][4] = {};
#pragma unroll 8
        for (int d = 0; d < 64; d++) {
            float4 af = *(const float4*)&Qs[d][qt];
            float4 bf = *(const float4*)&Ks[d][dt];
            float a_[4] = {af.x, af.y, af.z, af.w};
            float b_[4] = {bf.x, bf.y, bf.z, bf.w};
#pragma unroll
            for (int i = 0; i < 4; i++)
#pragma unroll
                for (int j = 0; j < 4; j++) S[i][j] += a_[i] * b_[j];
        }
        float rmax[4];
#pragma unroll
        for (int i = 0; i < 4; i++) {
            rmax[i] = -3e38f;
#pragma unroll
            for (int j = 0; j < 4; j++) {
                S[i][j] += mask_s[dt + j];
                rmax[i] = fmaxf(rmax[i], S[i][j]);
            }
            stats[qt + i][lr] = rmax[i];
        }
        __syncthreads();               // K-tile reads all complete here
        if (t < 64) {
            float tm_ = stats[t][0];
#pragma unroll
            for (int g = 1; g < 16; g++) tm_ = fmaxf(tm_, stats[t][g]);
            float mn = fmaxf(m_run[t], tm_);
            mnew_s[t] = mn;
            alpha_s[t] = __expf(m_run[t] - mn);
            m_run[t] = mn;
        }
        __syncthreads();
#pragma unroll
        for (int i = 0; i < 4; i++) {
            float mn = mnew_s[qt + i];
            float rs = 0.f;
#pragma unroll
            for (int j = 0; j < 4; j++) {
                float pv = __expf(S[i][j] - mn);
                Ps[dt + j][qt + i] = pv;   // overwrites Ks storage — safe post-sync
                rs += pv;
            }
            stats[qt + i][lr] = rs;
        }
        __syncthreads();
        if (t < 64) {
            float s = 0.f;
#pragma unroll
            for (int g = 0; g < 16; g++) s += stats[t][g];
            l_run[t] = l_run[t] * alpha_s[t] + s;
        }
        float al4[4];
#pragma unroll
        for (int i = 0; i < 4; i++) al4[i] = alpha_s[qt + i];
#pragma unroll
        for (int i = 0; i < 4; i++)
#pragma unroll
            for (int j = 0; j < 4; j++) ctx[i][j] *= al4[i];
#pragma unroll 8
        for (int kk = 0; kk < 64; kk++) {
            float4 pf = *(const float4*)&Ps[kk][qt];
            float4 vf = *(const float4*)&Vs[kk][dt];
            float p_[4] = {pf.x, pf.y, pf.z, pf.w};
            float v_[4] = {vf.x, vf.y, vf.z, vf.w};
#pragma unroll
            for (int i = 0; i < 4; i++)
#pragma unroll
                for (int j = 0; j < 4; j++) ctx[i][j] += p_[i] * v_[j];
        }
        __syncthreads();
    }
#pragma unroll
    for (int i = 0; i < 4; i++) {
        float inv = 1.f / l_run[qt + i];
        float4 o;
        o.x = ctx[i][0] * inv; o.y = ctx[i][1] * inv;
        o.z = ctx[i][2] * inv; o.w = ctx[i][3] * inv;
        *(float4*)(O + (size_t)(b * 64 + qt + i) * HID + h * HD + dt) = o;
    }
}

// ---------------- LayerNorm(residual) ----------------
__device__ __forceinline__ float blockSum256(float v, float* red)
{
#pragma unroll
    for (int off = 32; off >= 1; off >>= 1) v += __shfl_down(v, off, 64);
    int wave = threadIdx.x >> 6, lane = threadIdx.x & 63;
    if (lane == 0) red[wave] = v;
    __syncthreads();
    float s = red[0] + red[1] + red[2] + red[3];
    __syncthreads();
    return s;
}

__global__ __launch_bounds__(256) void lnres_k(const float* __restrict__ A,
    const float* __restrict__ Bb, const float* __restrict__ g,
    const float* __restrict__ be, float* __restrict__ Y)
{
    __shared__ float red[4];
    int r = blockIdx.x, t = threadIdx.x;
    float v = A[(size_t)r * 256 + t] + Bb[(size_t)r * 256 + t];
    float mean = blockSum256(v, red) * (1.f / 256.f);
    float d = v - mean;
    float var = blockSum256(d * d, red) * (1.f / 256.f);
    Y[(size_t)r * 256 + t] = d * rsqrtf(var + 1e-5f) * g[t] + be[t];
}

// ---------------- mean pool (all 64 atoms valid; divisor 64 + 1e-6) ----------------
__global__ void pool_k(const float* __restrict__ Y, float* __restrict__ P)
{
    int b = blockIdx.x, c = threadIdx.x;
    float s = 0.f;
#pragma unroll 8
    for (int q = 0; q < 64; q++) s += Y[(size_t)(b * 64 + q) * 256 + c];
    P[(size_t)b * 256 + c] = s / (64.f + 1e-6f);
}

// ---------------- launch ----------------
extern "C" void kernel_launch(void* const* d_in, const int* in_sizes, int n_in,
                              void* d_out, int out_size, void* d_ws, size_t ws_size,
                              hipStream_t stream)
{
    const float* x     = (const float*)d_in[0];
    const int*   ei    = (const int*)d_in[1];
    const int*   pseq  = (const int*)d_in[3];
    const float* w1  = (const float*)d_in[4];
    const float* as1 = (const float*)d_in[5];
    const float* ad1 = (const float*)d_in[6];
    const float* b1  = (const float*)d_in[7];
    const float* w2  = (const float*)d_in[8];
    const float* as2 = (const float*)d_in[9];
    const float* ad2 = (const float*)d_in[10];
    const float* b2  = (const float*)d_in[11];
    const float* w3  = (const float*)d_in[12];
    const float* as3 = (const float*)d_in[13];
    const float* ad3 = (const float*)d_in[14];
    const float* b3  = (const float*)d_in[15];
    const float* emb    = (const float*)d_in[16];
    const float* conv_w = (const float*)d_in[17];
    const float* conv_b = (const float*)d_in[18];
    const float* wq = (const float*)d_in[19];
    const float* bq = (const float*)d_in[20];
    const float* wk = (const float*)d_in[21];
    const float* bk = (const float*)d_in[22];
    const float* wv = (const float*)d_in[23];
    const float* bv = (const float*)d_in[24];
    const float* wo = (const float*)d_in[25];
    const float* bo = (const float*)d_in[26];
    const float* ln1_g = (const float*)d_in[27];
    const float* ln1_b = (const float*)d_in[28];
    const float* ffw1  = (const float*)d_in[29];
    const float* ffb1  = (const float*)d_in[30];
    const float* ffw2  = (const float*)d_in[31];
    const float* ffb2  = (const float*)d_in[32];
    const float* ln2_g = (const float*)d_in[33];
    const float* ln2_b = (const float*)d_in[34];
    const float* fc1_w = (const float*)d_in[35];
    const float* fc1_b = (const float*)d_in[36];
    const float* fc2_w = (const float*)d_in[37];
    const float* fc2_b = (const float*)d_in[38];
    (void)in_sizes; (void)n_in; (void)out_size;

    char* ws = (char*)d_ws;
    size_t off = 0;
    auto alloc = [&](size_t bytes) -> char* {
        char* p = ws + off;
        off += (bytes + 255) & ~(size_t)255;
        return p;
    };
    // ---- fixed arena (~150 MB) ----
    float* hg    = (float*)alloc((size_t)NAT * 512 * 4);   // 32 MB; later qbuf|ctxb
    float* og    = (float*)alloc((size_t)NAT * 512 * 4);   // 32 MB; later attno|ybuf
    float* hb0   = (float*)alloc((size_t)NAT * 256 * 4);   // 16 MB (lig)
    float* hb1   = (float*)alloc((size_t)NAT * 256 * 4);   // 16 MB; later ff2o
    float* a_s   = (float*)alloc((size_t)NAT * 2 * 4);
    float* a_d   = (float*)alloc((size_t)NAT * 2 * 4);
    float* ebuf  = (float*)alloc((size_t)ETOT * 2 * 4);
    float* exbuf = (float*)alloc((size_t)ETOT * 2 * 4);
    unsigned* emaxU = (unsigned*)alloc((size_t)NAT * 2 * 4);
    float* den   = (float*)alloc((size_t)NAT * 2 * 4);
    float* wt    = (float*)alloc((size_t)768 * 256 * 4);
    float* pooled = (float*)alloc((size_t)256 * 256 * 4);
    float* fc1o   = (float*)alloc((size_t)256 * 256 * 4);
    // ---- variable region: protein chunks, then FFN buffers ----
    size_t fixed_end = off;
    size_t rem = (ws_size > fixed_end) ? ws_size - fixed_end : 0;
    const size_t MB1 = (size_t)LPN * 256 * 4;              // 1 MB per graph per buffer
    const size_t ffneed = (size_t)NAT * 1024 * 4 + (size_t)NAT * 256 * 4;  // 80 MB
    int CB = 8;
    {
        const int cands[4] = {64, 32, 16, 8};
        for (int ci = 0; ci < 4; ci++) {
            size_t regneed = 3 * (size_t)cands[ci] * MB1;
            if (regneed < ffneed) regneed = ffneed;
            if (regneed <= rem) { CB = cands[ci]; break; }
        }
    }
    char* region  = ws + fixed_end;
    float* pconv  = (float*)region;
    float* kbuf   = (float*)(region + (size_t)CB * MB1);
    float* vbuf   = (float*)(region + 2 * (size_t)CB * MB1);
    float* ffbuf  = (float*)region;                         // after protein phase
    float* y2     = (float*)(region + (size_t)NAT * 1024 * 4);
    // aliases of fixed buffers whose lifetime has ended:
    float* qbuf  = hg;
    float* ctxb  = hg + (size_t)NAT * 256;
    float* attno = og;
    float* ybuf  = og + (size_t)NAT * 256;
    float* ff2o  = hb1;

    // ---------------- ligand GNN: 3 GAT layers ----------------
    const float* Wl[3]  = {w1, w2, w3};
    const float* asl[3] = {as1, as2, as3};
    const float* adl[3] = {ad1, ad2, ad3};
    const float* bl[3]  = {b1, b2, b3};
    float* houts[3] = {hb0, hb1, hb0};
    const float* hin = x;
    int Kdim = FIN;
    for (int l = 0; l < 3; l++) {
        gemm_k<0><<<dim3(8, NAT / 64), 256, 0, stream>>>(hin, Wl[l], nullptr, hg, NAT, 512, Kdim);
        asad_k<<<NAT, 256, 0, stream>>>(hg, asl[l], adl[l], a_s, a_d);
        hipMemsetAsync(emaxU, 0, (size_t)NAT * 2 * 4, stream);
        hipMemsetAsync(den, 0, (size_t)NAT * 2 * 4, stream);
        hipMemsetAsync(og, 0, (size_t)NAT * 512 * 4, stream);
        edge1_k<<<(ETOT + 255) / 256, 256, 0, stream>>>(ei, a_s, a_d, ebuf, emaxU);
        edge2_k<<<(ETOT + 255) / 256, 256, 0, stream>>>(ei, ebuf, emaxU, exbuf, den);
        edge3_k<<<ETOT, 512, 0, stream>>>(ei, hg, exbuf, den, og);
        gatfin_k<<<NAT, 256, 0, stream>>>(og, bl[l], houts[l]);
        hin = houts[l];
        Kdim = HID;
    }
    const float* lig = hb0;

    // ---------------- Q projection (lig is final GAT output) ----------------
    gemm_k<0><<<dim3(4, NAT / 64), 256, 0, stream>>>(lig, wq, bq, qbuf, NAT, 256, 256);

    // ---------------- protein branch + attention, chunked over graphs ----------------
    transw_k<<<768, 256, 0, stream>>>(conv_w, wt);
    for (int b0 = 0; b0 < BGR; b0 += CB) {
        int Mc = CB * LPN;
        conv_k<<<dim3(4, Mc / 64), 256, 0, stream>>>(pseq, emb, wt, conv_b, pconv, b0);
        gemm_k<0><<<dim3(4, Mc / 64), 256, 0, stream>>>(pconv, wk, bk, kbuf, Mc, 256, 256);
        gemm_k<0><<<dim3(4, Mc / 64), 256, 0, stream>>>(pconv, wv, bv, vbuf, Mc, 256, 256);
        attn_k<<<CB * 4, 256, 0, stream>>>(qbuf, kbuf, vbuf, pseq, ctxb, b0);
    }

    // ---------------- attention out proj + LN + FFN + LN ----------------
    gemm_k<0><<<dim3(4, NAT / 64), 256, 0, stream>>>(ctxb, wo, bo, attno, NAT, 256, 256);
    lnres_k<<<NAT, 256, 0, stream>>>(lig, attno, ln1_g, ln1_b, ybuf);
    gemm_k<2><<<dim3(16, NAT / 64), 256, 0, stream>>>(ybuf, ffw1, ffb1, ffbuf, NAT, 1024, 256);
    gemm_k<0><<<dim3(4, NAT / 64), 256, 0, stream>>>(ffbuf, ffw2, ffb2, ff2o, NAT, 256, 1024);
    lnres_k<<<NAT, 256, 0, stream>>>(ybuf, ff2o, ln2_g, ln2_b, y2);

    // ---------------- pool + MLP head ----------------
    pool_k<<<BGR, 256, 0, stream>>>(y2, pooled);
    gemm_k<1><<<dim3(4, 4), 256, 0, stream>>>(pooled, fc1_w, fc1_b, fc1o, 256, 256, 256);
    gemm_k<0><<<dim3(1, 4), 256, 0, stream>>>(fc1o, fc2_w, fc2_b, (float*)d_out, 256, 1, 256);
}

// Round 3
// 2426.082 us; speedup vs baseline: 1.8716x; 1.8716x over previous
//
#include <hip/hip_runtime.h>
#include <hip/hip_bf16.h>
#include <cstdint>
#include <cstddef>

#define NAT 16384
#define NED 65536
#define ETOT (NED + NAT)
#define BGR 256
#define MAXQ 64
#define FIN 64
#define HID 256
#define LPN 1024
#define HD 64

typedef __bf16 bf16x8 __attribute__((ext_vector_type(8)));
typedef float floatx4 __attribute__((ext_vector_type(4)));

// ---------------- sortable-uint float encoding for atomicMax ----------------
__device__ __forceinline__ unsigned f2s(float f) {
    unsigned u = __float_as_uint(f);
    return (u & 0x80000000u) ? ~u : (u | 0x80000000u);
}
__device__ __forceinline__ float s2f(unsigned u) {
    return (u & 0x80000000u) ? __uint_as_float(u ^ 0x80000000u) : __uint_as_float(~u);
}

// ---------------- generic fp32 GEMM: C = act(A@B + bias) ----------------
template<int ACT>
__global__ __launch_bounds__(256) void gemm_k(const float* __restrict__ A,
    const float* __restrict__ Bm, const float* __restrict__ bias,
    float* __restrict__ C, int M, int Nn, int K)
{
    __shared__ float As[16][68];
    __shared__ float Bs[16][68];
    const int t  = threadIdx.x;
    const int m0 = blockIdx.y * 64, n0 = blockIdx.x * 64;
    const int tm = (t & 15) * 4, tn = (t >> 4) * 4;
    const int lm = t >> 2,  lkc = (t & 3) * 4;
    const int lkk = t >> 4, lnc = (t & 15) * 4;
    float acc[4][4] = {};
    for (int k0 = 0; k0 < K; k0 += 16) {
        float4 av = *(const float4*)(A + (size_t)(m0 + lm) * K + k0 + lkc);
        As[lkc + 0][lm] = av.x; As[lkc + 1][lm] = av.y;
        As[lkc + 2][lm] = av.z; As[lkc + 3][lm] = av.w;
        if (n0 + lnc + 3 < Nn) {
            float4 bv = *(const float4*)(Bm + (size_t)(k0 + lkk) * Nn + n0 + lnc);
            Bs[lkk][lnc + 0] = bv.x; Bs[lkk][lnc + 1] = bv.y;
            Bs[lkk][lnc + 2] = bv.z; Bs[lkk][lnc + 3] = bv.w;
        } else {
            for (int j = 0; j < 4; j++) {
                int n = n0 + lnc + j;
                Bs[lkk][lnc + j] = (n < Nn) ? Bm[(size_t)(k0 + lkk) * Nn + n] : 0.f;
            }
        }
        __syncthreads();
#pragma unroll
        for (int kk = 0; kk < 16; kk++) {
            float4 af = *(const float4*)&As[kk][tm];
            float4 bf = *(const float4*)&Bs[kk][tn];
            float a_[4] = {af.x, af.y, af.z, af.w};
            float b_[4] = {bf.x, bf.y, bf.z, bf.w};
#pragma unroll
            for (int i = 0; i < 4; i++)
#pragma unroll
                for (int j = 0; j < 4; j++) acc[i][j] += a_[i] * b_[j];
        }
        __syncthreads();
    }
#pragma unroll
    for (int i = 0; i < 4; i++) {
#pragma unroll
        for (int j = 0; j < 4; j++) {
            int n = n0 + tn + j;
            if (n < Nn) {
                float v = acc[i][j] + (bias ? bias[n] : 0.f);
                if (ACT == 1) v = fmaxf(v, 0.f);
                if (ACT == 2) v = 0.5f * v * (1.f + erff(v * 0.70710678118654752f));
                C[(size_t)(m0 + tm + i) * Nn + n] = v;
            }
        }
    }
}

// ---------------- bf16 MFMA GEMM: C = act(A@Bt^T + bias) ----------------
// A[M,K] bf16 row-major, Bt[N,K] bf16 row-major (i.e. B transposed).
// M%128==0, N%128==0, K%32==0. 128x128 tile, 4 waves, 64x64 per wave.
// OUTBF16: 1 -> C is __bf16, else fp32. ACT: 0 none, 1 relu.
template<int ACT, int OUTBF16>
__global__ __launch_bounds__(256) void gemm_mfma(const __bf16* __restrict__ A,
    const __bf16* __restrict__ Bt, const float* __restrict__ bias,
    void* __restrict__ Cout, int M, int Nn, int K)
{
    __shared__ __bf16 As[128][40];
    __shared__ __bf16 Bs[128][40];
    const int t = threadIdx.x;
    const int m0 = blockIdx.y * 128, n0 = blockIdx.x * 128;
    const int wave = t >> 6, lane = t & 63;
    const int wm = (wave >> 1) * 64, wn = (wave & 1) * 64;
    const int quad = lane >> 4, l16 = lane & 15;
    floatx4 acc[4][4] = {};
    for (int k0 = 0; k0 < K; k0 += 32) {
#pragma unroll
        for (int i = 0; i < 2; i++) {
            int idx = t + i * 256;
            int r = idx >> 2, sg = (idx & 3) * 8;
            *(uint4*)&As[r][sg] = *(const uint4*)(A + (size_t)(m0 + r) * K + k0 + sg);
            *(uint4*)&Bs[r][sg] = *(const uint4*)(Bt + (size_t)(n0 + r) * K + k0 + sg);
        }
        __syncthreads();
        bf16x8 af[4], bfr[4];
#pragma unroll
        for (int mi = 0; mi < 4; mi++) af[mi]  = *(const bf16x8*)&As[wm + mi * 16 + l16][quad * 8];
#pragma unroll
        for (int nj = 0; nj < 4; nj++) bfr[nj] = *(const bf16x8*)&Bs[wn + nj * 16 + l16][quad * 8];
#pragma unroll
        for (int mi = 0; mi < 4; mi++)
#pragma unroll
            for (int nj = 0; nj < 4; nj++)
                acc[mi][nj] = __builtin_amdgcn_mfma_f32_16x16x32_bf16(af[mi], bfr[nj], acc[mi][nj], 0, 0, 0);
        __syncthreads();
    }
#pragma unroll
    for (int mi = 0; mi < 4; mi++)
#pragma unroll
        for (int nj = 0; nj < 4; nj++) {
            int col = n0 + wn + nj * 16 + l16;
            float bval = bias ? bias[col] : 0.f;
#pragma unroll
            for (int r = 0; r < 4; r++) {
                int row = m0 + wm + mi * 16 + quad * 4 + r;
                float v = acc[mi][nj][r] + bval;
                if (ACT == 1) v = fmaxf(v, 0.f);
                if (OUTBF16) ((__bf16*)Cout)[(size_t)row * Nn + col] = (__bf16)v;
                else         ((float*)Cout)[(size_t)row * Nn + col] = v;
            }
        }
}

// ---------------- conv1d as bf16 MFMA implicit GEMM, fused embedding gather ----
// Local rows [0, CB*1024); graph = b_base + row/1024. K = 768 = 3 taps x 256.
// Output bf16 pconv[row][n] = relu(conv + bias).
__global__ __launch_bounds__(256) void conv_mfma(const int* __restrict__ seq,
    const __bf16* __restrict__ embb, const __bf16* __restrict__ wtb,
    const float* __restrict__ bias, __bf16* __restrict__ C, int b_base)
{
    __shared__ __bf16 As[128][40];
    __shared__ __bf16 Bs[128][40];
    __shared__ int toks[130];
    const int t = threadIdx.x;
    const int m0 = blockIdx.y * 128, n0 = blockIdx.x * 128;
    const int b = b_base + (m0 >> 10), l0 = m0 & 1023;
    if (t < 130) {
        int l = l0 + t - 1;
        toks[t] = (l >= 0 && l < LPN) ? seq[b * LPN + l] : -1;
    }
    const int wave = t >> 6, lane = t & 63;
    const int wm = (wave >> 1) * 64, wn = (wave & 1) * 64;
    const int quad = lane >> 4, l16 = lane & 15;
    floatx4 acc[4][4] = {};
    __syncthreads();
    for (int k0 = 0; k0 < 768; k0 += 32) {
        int dl = k0 >> 8, c0 = k0 & 255;
#pragma unroll
        for (int i = 0; i < 2; i++) {
            int idx = t + i * 256;
            int r = idx >> 2, sg = (idx & 3) * 8;
            int tok = toks[r + dl];
            uint4 av = make_uint4(0u, 0u, 0u, 0u);
            if (tok >= 0) av = *(const uint4*)(embb + (size_t)tok * HID + c0 + sg);
            *(uint4*)&As[r][sg] = av;
            *(uint4*)&Bs[r][sg] = *(const uint4*)(wtb + (size_t)(n0 + r) * 768 + k0 + sg);
        }
        __syncthreads();
        bf16x8 af[4], bfr[4];
#pragma unroll
        for (int mi = 0; mi < 4; mi++) af[mi]  = *(const bf16x8*)&As[wm + mi * 16 + l16][quad * 8];
#pragma unroll
        for (int nj = 0; nj < 4; nj++) bfr[nj] = *(const bf16x8*)&Bs[wn + nj * 16 + l16][quad * 8];
#pragma unroll
        for (int mi = 0; mi < 4; mi++)
#pragma unroll
            for (int nj = 0; nj < 4; nj++)
                acc[mi][nj] = __builtin_amdgcn_mfma_f32_16x16x32_bf16(af[mi], bfr[nj], acc[mi][nj], 0, 0, 0);
        __syncthreads();
    }
#pragma unroll
    for (int mi = 0; mi < 4; mi++)
#pragma unroll
        for (int nj = 0; nj < 4; nj++) {
            int col = n0 + wn + nj * 16 + l16;
            float bval = bias[col];
#pragma unroll
            for (int r = 0; r < 4; r++) {
                int row = m0 + wm + mi * 16 + quad * 4 + r;
                float v = fmaxf(acc[mi][nj][r] + bval, 0.f);
                C[(size_t)row * 256 + col] = (__bf16)v;
            }
        }
}

// ---------------- weight conversion kernels ----------------
__global__ void cvt_k(const float* __restrict__ in, __bf16* __restrict__ out, int n)
{
    int i = blockIdx.x * 256 + threadIdx.x;
    if (i < n) out[i] = (__bf16)in[i];
}

// out[n*K + k] = (bf16) in[k*N + n]   (transpose-convert, K=N=256 here)
__global__ void cvtT_k(const float* __restrict__ in, __bf16* __restrict__ out, int K, int N)
{
    int i = blockIdx.x * 256 + threadIdx.x;
    if (i >= K * N) return;
    int n = i / K, k = i - n * K;
    out[i] = (__bf16)in[(size_t)k * N + n];
}

// wtb[n*768 + dl*256 + kk] = (bf16) conv_w[n*768 + kk*3 + dl]
__global__ void cvtwt_k(const float* __restrict__ cw, __bf16* __restrict__ wtb)
{
    int i = blockIdx.x * 256 + threadIdx.x;     // < 196608
    int n = i / 768, r = i - n * 768;
    int dl = r >> 8, kk = r & 255;
    wtb[i] = (__bf16)cw[(size_t)n * 768 + kk * 3 + dl];
}

// ---------------- GAT pieces ----------------
__global__ __launch_bounds__(256) void asad_k(const float* __restrict__ hg,
    const float* __restrict__ as_, const float* __restrict__ ad_,
    float* __restrict__ a_s, float* __restrict__ a_d)
{
    int n = blockIdx.x, t = threadIdx.x;
    float h0 = hg[(size_t)n * 512 + t];
    float h1 = hg[(size_t)n * 512 + 256 + t];
    float p0 = h0 * as_[t], p1 = h1 * as_[256 + t];
    float p2 = h0 * ad_[t], p3 = h1 * ad_[256 + t];
#pragma unroll
    for (int off = 32; off >= 1; off >>= 1) {
        p0 += __shfl_down(p0, off, 64);
        p1 += __shfl_down(p1, off, 64);
        p2 += __shfl_down(p2, off, 64);
        p3 += __shfl_down(p3, off, 64);
    }
    __shared__ float red[4][4];
    int wave = t >> 6, lane = t & 63;
    if (lane == 0) { red[wave][0] = p0; red[wave][1] = p1; red[wave][2] = p2; red[wave][3] = p3; }
    __syncthreads();
    if (t < 4) {
        float v = red[0][t] + red[1][t] + red[2][t] + red[3][t];
        if (t == 0) a_s[n * 2 + 0] = v;
        if (t == 1) a_s[n * 2 + 1] = v;
        if (t == 2) a_d[n * 2 + 0] = v;
        if (t == 3) a_d[n * 2 + 1] = v;
    }
}

__global__ void edge1_k(const int* __restrict__ ei, const float* __restrict__ a_s,
    const float* __restrict__ a_d, float* __restrict__ ebuf, unsigned* __restrict__ emaxU)
{
    int e = blockIdx.x * 256 + threadIdx.x;
    if (e >= ETOT) return;
    int s, d;
    if (e < NED) { s = ei[e]; d = ei[NED + e]; } else { s = d = e - NED; }
#pragma unroll
    for (int g = 0; g < 2; g++) {
        float v = a_s[s * 2 + g] + a_d[d * 2 + g];
        v = (v > 0.f) ? v : 0.2f * v;
        ebuf[(size_t)e * 2 + g] = v;
        atomicMax(&emaxU[d * 2 + g], f2s(v));
    }
}

__global__ void edge2_k(const int* __restrict__ ei, const float* __restrict__ ebuf,
    const unsigned* __restrict__ emaxU, float* __restrict__ exbuf, float* __restrict__ den)
{
    int e = blockIdx.x * 256 + threadIdx.x;
    if (e >= ETOT) return;
    int d;
    if (e < NED) { d = ei[NED + e]; } else { d = e - NED; }
#pragma unroll
    for (int g = 0; g < 2; g++) {
        float mx = s2f(emaxU[d * 2 + g]);
        float ex = __expf(ebuf[(size_t)e * 2 + g] - mx);
        exbuf[(size_t)e * 2 + g] = ex;
        atomicAdd(&den[d * 2 + g], ex);
    }
}

__global__ __launch_bounds__(512) void edge3_k(const int* __restrict__ ei,
    const float* __restrict__ hg, const float* __restrict__ exbuf,
    const float* __restrict__ den, float* __restrict__ og)
{
    int e = blockIdx.x;
    int ch = threadIdx.x;     // 0..511
    int s, d;
    if (e < NED) { s = ei[e]; d = ei[NED + e]; } else { s = d = e - NED; }
    int g = ch >> 8;
    float alpha = exbuf[(size_t)e * 2 + g] / den[d * 2 + g];
    atomicAdd(&og[(size_t)d * 512 + ch], hg[(size_t)s * 512 + ch] * alpha);
}

// elu(mean over heads + bias)
__global__ void gatfin_k(const float* __restrict__ og, const float* __restrict__ bias,
                         float* __restrict__ out)
{
    int n = blockIdx.x, c = threadIdx.x;
    float v = 0.5f * (og[(size_t)n * 512 + c] + og[(size_t)n * 512 + 256 + c]) + bias[c];
    out[(size_t)n * 256 + c] = (v > 0.f) ? v : expm1f(v);
}

// ---------------- fused cross-attention (online softmax) ----------------
__global__ __launch_bounds__(256) void attn_k(const float* __restrict__ Q,
    const float* __restrict__ Kp, const float* __restrict__ Vp,
    const int* __restrict__ seq, float* __restrict__ O, int b0)
{
    __shared__ float Qs[64][68], Ks[64][68], Vs[64][68];
    __shared__ float stats[64][17];
    __shared__ float m_run[64], l_run[64], alpha_s[64], mnew_s[64], mask_s[64];
    float (*Ps)[68] = Ks;   // alias: P tile reuses K tile storage
    const int t = threadIdx.x;
    const int bl = blockIdx.x >> 2, h = blockIdx.x & 3;
    const int b = b0 + bl;
    const int qt = (t & 15) * 4, dt = (t >> 4) * 4;
    const int lr = t >> 4, lc = (t & 15) * 4;
#pragma unroll
    for (int p = 0; p < 4; p++) {
        int q = lr + p * 16;
        float4 v = *(const float4*)(Q + (size_t)(b * 64 + q) * HID + h * HD + lc);
        Qs[lc + 0][q] = v.x * 0.125f; Qs[lc + 1][q] = v.y * 0.125f;
        Qs[lc + 2][q] = v.z * 0.125f; Qs[lc + 3][q] = v.w * 0.125f;
    }
    if (t < 64) { m_run[t] = -3e38f; l_run[t] = 0.f; }
    float ctx[4][4] = {};
    __syncthreads();
    for (int kp0 = 0; kp0 < LPN; kp0 += 64) {
#pragma unroll
        for (int p = 0; p < 4; p++) {
            int kk = lr + p * 16;
            size_t row = (size_t)(bl * LPN + kp0 + kk) * HID + h * HD + lc;
            float4 kv = *(const float4*)(Kp + row);
            Ks[lc + 0][kk] = kv.x; Ks[lc + 1][kk] = kv.y;
            Ks[lc + 2][kk] = kv.z; Ks[lc + 3][kk] = kv.w;
            float4 vv = *(const float4*)(Vp + row);
            *(float4*)&Vs[kk][lc] = vv;
        }
        if (t < 64) mask_s[t] = (seq[b * LPN + kp0 + t] == 0) ? -1e9f : 0.f;
        __syncthreads();
        float S[4][4] = {};
#pragma unroll 8
        for (int d = 0; d < 64; d++) {
            float4 af = *(const float4*)&Qs[d][qt];
            float4 bf = *(const float4*)&Ks[d][dt];
            float a_[4] = {af.x, af.y, af.z, af.w};
            float b_[4] = {bf.x, bf.y, bf.z, bf.w};
#pragma unroll
            for (int i = 0; i < 4; i++)
#pragma unroll
                for (int j = 0; j < 4; j++) S[i][j] += a_[i] * b_[j];
        }
        float rmax[4];
#pragma unroll
        for (int i = 0; i < 4; i++) {
            rmax[i] = -3e38f;
#pragma unroll
            for (int j = 0; j < 4; j++) {
                S[i][j] += mask_s[dt + j];
                rmax[i] = fmaxf(rmax[i], S[i][j]);
            }
            stats[qt + i][lr] = rmax[i];
        }
        __syncthreads();               // K-tile reads all complete here
        if (t < 64) {
            float tm_ = stats[t][0];
#pragma unroll
            for (int g = 1; g < 16; g++) tm_ = fmaxf(tm_, stats[t][g]);
            float mn = fmaxf(m_run[t], tm_);
            mnew_s[t] = mn;
            alpha_s[t] = __expf(m_run[t] - mn);
            m_run[t] = mn;
        }
        __syncthreads();
#pragma unroll
        for (int i = 0; i < 4; i++) {
            float mn = mnew_s[qt + i];
            float rs = 0.f;
#pragma unroll
            for (int j = 0; j < 4; j++) {
                float pv = __expf(S[i][j] - mn);
                Ps[dt + j][qt + i] = pv;   // overwrites Ks storage — safe post-sync
                rs += pv;
            }
            stats[qt + i][lr] = rs;
        }
        __syncthreads();
        if (t < 64) {
            float s = 0.f;
#pragma unroll
            for (int g = 0; g < 16; g++) s += stats[t][g];
            l_run[t] = l_run[t] * alpha_s[t] + s;
        }
        float al4[4];
#pragma unroll
        for (int i = 0; i < 4; i++) al4[i] = alpha_s[qt + i];
#pragma unroll
        for (int i = 0; i < 4; i++)
#pragma unroll
            for (int j = 0; j < 4; j++) ctx[i][j] *= al4[i];
#pragma unroll 8
        for (int kk = 0; kk < 64; kk++) {
            float4 pf = *(const float4*)&Ps[kk][qt];
            float4 vf = *(const float4*)&Vs[kk][dt];
            float p_[4] = {pf.x, pf.y, pf.z, pf.w};
            float v_[4] = {vf.x, vf.y, vf.z, vf.w};
#pragma unroll
            for (int i = 0; i < 4; i++)
#pragma unroll
                for (int j = 0; j < 4; j++) ctx[i][j] += p_[i] * v_[j];
        }
        __syncthreads();
    }
#pragma unroll
    for (int i = 0; i < 4; i++) {
        float inv = 1.f / l_run[qt + i];
        float4 o;
        o.x = ctx[i][0] * inv; o.y = ctx[i][1] * inv;
        o.z = ctx[i][2] * inv; o.w = ctx[i][3] * inv;
        *(float4*)(O + (size_t)(b * 64 + qt + i) * HID + h * HD + dt) = o;
    }
}

// ---------------- LayerNorm(residual) ----------------
__device__ __forceinline__ float blockSum256(float v, float* red)
{
#pragma unroll
    for (int off = 32; off >= 1; off >>= 1) v += __shfl_down(v, off, 64);
    int wave = threadIdx.x >> 6, lane = threadIdx.x & 63;
    if (lane == 0) red[wave] = v;
    __syncthreads();
    float s = red[0] + red[1] + red[2] + red[3];
    __syncthreads();
    return s;
}

__global__ __launch_bounds__(256) void lnres_k(const float* __restrict__ A,
    const float* __restrict__ Bb, const float* __restrict__ g,
    const float* __restrict__ be, float* __restrict__ Y)
{
    __shared__ float red[4];
    int r = blockIdx.x, t = threadIdx.x;
    float v = A[(size_t)r * 256 + t] + Bb[(size_t)r * 256 + t];
    float mean = blockSum256(v, red) * (1.f / 256.f);
    float d = v - mean;
    float var = blockSum256(d * d, red) * (1.f / 256.f);
    Y[(size_t)r * 256 + t] = d * rsqrtf(var + 1e-5f) * g[t] + be[t];
}

// ---------------- mean pool ----------------
__global__ void pool_k(const float* __restrict__ Y, float* __restrict__ P)
{
    int b = blockIdx.x, c = threadIdx.x;
    float s = 0.f;
#pragma unroll 8
    for (int q = 0; q < 64; q++) s += Y[(size_t)(b * 64 + q) * 256 + c];
    P[(size_t)b * 256 + c] = s / (64.f + 1e-6f);
}

// ---------------- launch ----------------
extern "C" void kernel_launch(void* const* d_in, const int* in_sizes, int n_in,
                              void* d_out, int out_size, void* d_ws, size_t ws_size,
                              hipStream_t stream)
{
    const float* x     = (const float*)d_in[0];
    const int*   ei    = (const int*)d_in[1];
    const int*   pseq  = (const int*)d_in[3];
    const float* w1  = (const float*)d_in[4];
    const float* as1 = (const float*)d_in[5];
    const float* ad1 = (const float*)d_in[6];
    const float* b1  = (const float*)d_in[7];
    const float* w2  = (const float*)d_in[8];
    const float* as2 = (const float*)d_in[9];
    const float* ad2 = (const float*)d_in[10];
    const float* b2  = (const float*)d_in[11];
    const float* w3  = (const float*)d_in[12];
    const float* as3 = (const float*)d_in[13];
    const float* ad3 = (const float*)d_in[14];
    const float* b3  = (const float*)d_in[15];
    const float* emb    = (const float*)d_in[16];
    const float* conv_w = (const float*)d_in[17];
    const float* conv_b = (const float*)d_in[18];
    const float* wq = (const float*)d_in[19];
    const float* bq = (const float*)d_in[20];
    const float* wk = (const float*)d_in[21];
    const float* bk = (const float*)d_in[22];
    const float* wv = (const float*)d_in[23];
    const float* bv = (const float*)d_in[24];
    const float* wo = (const float*)d_in[25];
    const float* bo = (const float*)d_in[26];
    const float* ln1_g = (const float*)d_in[27];
    const float* ln1_b = (const float*)d_in[28];
    const float* ffw1  = (const float*)d_in[29];
    const float* ffb1  = (const float*)d_in[30];
    const float* ffw2  = (const float*)d_in[31];
    const float* ffb2  = (const float*)d_in[32];
    const float* ln2_g = (const float*)d_in[33];
    const float* ln2_b = (const float*)d_in[34];
    const float* fc1_w = (const float*)d_in[35];
    const float* fc1_b = (const float*)d_in[36];
    const float* fc2_w = (const float*)d_in[37];
    const float* fc2_b = (const float*)d_in[38];
    (void)in_sizes; (void)n_in; (void)out_size;

    char* ws = (char*)d_ws;
    size_t off = 0;
    auto alloc = [&](size_t bytes) -> char* {
        char* p = ws + off;
        off += (bytes + 255) & ~(size_t)255;
        return p;
    };
    // ---- fixed arena ----
    float* hg    = (float*)alloc((size_t)NAT * 512 * 4);   // 32 MB; later qbuf|ctxb
    float* og    = (float*)alloc((size_t)NAT * 512 * 4);   // 32 MB; later attno|ybuf
    float* hb0   = (float*)alloc((size_t)NAT * 256 * 4);   // 16 MB (lig)
    float* hb1   = (float*)alloc((size_t)NAT * 256 * 4);   // 16 MB; later ff2o
    float* a_s   = (float*)alloc((size_t)NAT * 2 * 4);
    float* a_d   = (float*)alloc((size_t)NAT * 2 * 4);
    float* ebuf  = (float*)alloc((size_t)ETOT * 2 * 4);
    float* exbuf = (float*)alloc((size_t)ETOT * 2 * 4);
    unsigned* emaxU = (unsigned*)alloc((size_t)NAT * 2 * 4);
    float* den   = (float*)alloc((size_t)NAT * 2 * 4);
    float* pooled = (float*)alloc((size_t)256 * 256 * 4);
    float* fc1o   = (float*)alloc((size_t)256 * 256 * 4);
    __bf16* embb = (__bf16*)alloc((size_t)22 * 256 * 2);
    __bf16* wtb  = (__bf16*)alloc((size_t)256 * 768 * 2);
    __bf16* wkT  = (__bf16*)alloc((size_t)256 * 256 * 2);
    __bf16* wvT  = (__bf16*)alloc((size_t)256 * 256 * 2);
    // ---- variable region: protein chunks, then FFN buffers ----
    size_t fixed_end = off;
    size_t rem = (ws_size > fixed_end) ? ws_size - fixed_end : 0;
    const size_t PCB1 = (size_t)LPN * 256 * 2;             // 0.5 MB bf16 pconv / graph
    const size_t KVB1 = (size_t)LPN * 256 * 4;             // 1 MB fp32 K or V / graph
    const size_t ffneed = (size_t)NAT * 1024 * 4 + (size_t)NAT * 256 * 4;  // 80 MB
    int CB = 8;
    {
        const int cands[4] = {64, 32, 16, 8};
        for (int ci = 0; ci < 4; ci++) {
            size_t regneed = (size_t)cands[ci] * (PCB1 + 2 * KVB1);
            if (regneed < ffneed) regneed = ffneed;
            if (regneed <= rem) { CB = cands[ci]; break; }
        }
    }
    char* region   = ws + fixed_end;
    __bf16* pconvb = (__bf16*)region;
    float* kbuf    = (float*)(region + (size_t)CB * PCB1);
    float* vbuf    = (float*)(region + (size_t)CB * (PCB1 + KVB1));
    float* ffbuf   = (float*)region;                        // after protein phase
    float* y2      = (float*)(region + (size_t)NAT * 1024 * 4);
    // aliases of fixed buffers whose lifetime has ended:
    float* qbuf  = hg;
    float* ctxb  = hg + (size_t)NAT * 256;
    float* attno = og;
    float* ybuf  = og + (size_t)NAT * 256;
    float* ff2o  = hb1;

    // ---------------- ligand GNN: 3 GAT layers ----------------
    const float* Wl[3]  = {w1, w2, w3};
    const float* asl[3] = {as1, as2, as3};
    const float* adl[3] = {ad1, ad2, ad3};
    const float* bl[3]  = {b1, b2, b3};
    float* houts[3] = {hb0, hb1, hb0};
    const float* hin = x;
    int Kdim = FIN;
    for (int l = 0; l < 3; l++) {
        gemm_k<0><<<dim3(8, NAT / 64), 256, 0, stream>>>(hin, Wl[l], nullptr, hg, NAT, 512, Kdim);
        asad_k<<<NAT, 256, 0, stream>>>(hg, asl[l], adl[l], a_s, a_d);
        hipMemsetAsync(emaxU, 0, (size_t)NAT * 2 * 4, stream);
        hipMemsetAsync(den, 0, (size_t)NAT * 2 * 4, stream);
        hipMemsetAsync(og, 0, (size_t)NAT * 512 * 4, stream);
        edge1_k<<<(ETOT + 255) / 256, 256, 0, stream>>>(ei, a_s, a_d, ebuf, emaxU);
        edge2_k<<<(ETOT + 255) / 256, 256, 0, stream>>>(ei, ebuf, emaxU, exbuf, den);
        edge3_k<<<ETOT, 512, 0, stream>>>(ei, hg, exbuf, den, og);
        gatfin_k<<<NAT, 256, 0, stream>>>(og, bl[l], houts[l]);
        hin = houts[l];
        Kdim = HID;
    }
    const float* lig = hb0;

    // ---------------- Q projection ----------------
    gemm_k<0><<<dim3(4, NAT / 64), 256, 0, stream>>>(lig, wq, bq, qbuf, NAT, 256, 256);

    // ---------------- weight conversions (bf16) ----------------
    cvt_k<<<(22 * 256 + 255) / 256, 256, 0, stream>>>(emb, embb, 22 * 256);
    cvtwt_k<<<768, 256, 0, stream>>>(conv_w, wtb);
    cvtT_k<<<256, 256, 0, stream>>>(wk, wkT, 256, 256);
    cvtT_k<<<256, 256, 0, stream>>>(wv, wvT, 256, 256);

    // ---------------- protein branch + attention, chunked over graphs ----------
    for (int b0 = 0; b0 < BGR; b0 += CB) {
        int Mc = CB * LPN;
        conv_mfma<<<dim3(2, Mc / 128), 256, 0, stream>>>(pseq, embb, wtb, conv_b, pconvb, b0);
        gemm_mfma<0, 0><<<dim3(2, Mc / 128), 256, 0, stream>>>(pconvb, wkT, bk, kbuf, Mc, 256, 256);
        gemm_mfma<0, 0><<<dim3(2, Mc / 128), 256, 0, stream>>>(pconvb, wvT, bv, vbuf, Mc, 256, 256);
        attn_k<<<CB * 4, 256, 0, stream>>>(qbuf, kbuf, vbuf, pseq, ctxb, b0);
    }

    // ---------------- attention out proj + LN + FFN + LN ----------------
    gemm_k<0><<<dim3(4, NAT / 64), 256, 0, stream>>>(ctxb, wo, bo, attno, NAT, 256, 256);
    lnres_k<<<NAT, 256, 0, stream>>>(lig, attno, ln1_g, ln1_b, ybuf);
    gemm_k<2><<<dim3(16, NAT / 64), 256, 0, stream>>>(ybuf, ffw1, ffb1, ffbuf, NAT, 1024, 256);
    gemm_k<0><<<dim3(4, NAT / 64), 256, 0, stream>>>(ffbuf, ffw2, ffb2, ff2o, NAT, 256, 1024);
    lnres_k<<<NAT, 256, 0, stream>>>(ybuf, ff2o, ln2_g, ln2_b, y2);

    // ---------------- pool + MLP head ----------------
    pool_k<<<BGR, 256, 0, stream>>>(y2, pooled);
    gemm_k<1><<<dim3(4, 4), 256, 0, stream>>>(pooled, fc1_w, fc1_b, fc1o, 256, 256, 256);
    gemm_k<0><<<dim3(1, 4), 256, 0, stream>>>(fc1o, fc2_w, fc2_b, (float*)d_out, 256, 1, 256);
}

// Round 4
// 1584.188 us; speedup vs baseline: 2.8663x; 1.5314x over previous
//
#include <hip/hip_runtime.h>
#include <hip/hip_bf16.h>
#include <cstdint>
#include <cstddef>

#define NAT 16384
#define NED 65536
#define ETOT (NED + NAT)
#define BGR 256
#define MAXQ 64
#define FIN 64
#define HID 256
#define LPN 1024
#define HD 64

typedef __bf16 bf16x8 __attribute__((ext_vector_type(8)));
typedef float floatx4 __attribute__((ext_vector_type(4)));

// ---------------- sortable-uint float encoding for atomicMax ----------------
__device__ __forceinline__ unsigned f2s(float f) {
    unsigned u = __float_as_uint(f);
    return (u & 0x80000000u) ? ~u : (u | 0x80000000u);
}
__device__ __forceinline__ float s2f(unsigned u) {
    return (u & 0x80000000u) ? __uint_as_float(u ^ 0x80000000u) : __uint_as_float(~u);
}

// ---------------- fp32 GEMM (small head matmuls only) ----------------
template<int ACT>
__global__ __launch_bounds__(256) void gemm_k(const float* __restrict__ A,
    const float* __restrict__ Bm, const float* __restrict__ bias,
    float* __restrict__ C, int M, int Nn, int K)
{
    __shared__ float As[16][68];
    __shared__ float Bs[16][68];
    const int t  = threadIdx.x;
    const int m0 = blockIdx.y * 64, n0 = blockIdx.x * 64;
    const int tm = (t & 15) * 4, tn = (t >> 4) * 4;
    const int lm = t >> 2,  lkc = (t & 3) * 4;
    const int lkk = t >> 4, lnc = (t & 15) * 4;
    float acc[4][4] = {};
    for (int k0 = 0; k0 < K; k0 += 16) {
        float4 av = *(const float4*)(A + (size_t)(m0 + lm) * K + k0 + lkc);
        As[lkc + 0][lm] = av.x; As[lkc + 1][lm] = av.y;
        As[lkc + 2][lm] = av.z; As[lkc + 3][lm] = av.w;
        if (n0 + lnc + 3 < Nn) {
            float4 bv = *(const float4*)(Bm + (size_t)(k0 + lkk) * Nn + n0 + lnc);
            Bs[lkk][lnc + 0] = bv.x; Bs[lkk][lnc + 1] = bv.y;
            Bs[lkk][lnc + 2] = bv.z; Bs[lkk][lnc + 3] = bv.w;
        } else {
            for (int j = 0; j < 4; j++) {
                int n = n0 + lnc + j;
                Bs[lkk][lnc + j] = (n < Nn) ? Bm[(size_t)(k0 + lkk) * Nn + n] : 0.f;
            }
        }
        __syncthreads();
#pragma unroll
        for (int kk = 0; kk < 16; kk++) {
            float4 af = *(const float4*)&As[kk][tm];
            float4 bf = *(const float4*)&Bs[kk][tn];
            float a_[4] = {af.x, af.y, af.z, af.w};
            float b_[4] = {bf.x, bf.y, bf.z, bf.w};
#pragma unroll
            for (int i = 0; i < 4; i++)
#pragma unroll
                for (int j = 0; j < 4; j++) acc[i][j] += a_[i] * b_[j];
        }
        __syncthreads();
    }
#pragma unroll
    for (int i = 0; i < 4; i++) {
#pragma unroll
        for (int j = 0; j < 4; j++) {
            int n = n0 + tn + j;
            if (n < Nn) {
                float v = acc[i][j] + (bias ? bias[n] : 0.f);
                if (ACT == 1) v = fmaxf(v, 0.f);
                C[(size_t)(m0 + tm + i) * Nn + n] = v;
            }
        }
    }
}

// ---------------- bf16 MFMA GEMM: C = act((A@Bt^T + bias) * escale) ----------
// A[M,K] bf16 rm, Bt[N,K] bf16 rm. M%128==0, N%128==0, K%32==0.
// ACT: 0 none, 1 relu, 2 gelu(exact). OUTBF16: C dtype. BIASROW: bias[row].
template<int ACT, int OUTBF16, int BIASROW>
__global__ __launch_bounds__(256) void gemm_mfma(const __bf16* __restrict__ A,
    const __bf16* __restrict__ Bt, const float* __restrict__ bias,
    void* __restrict__ Cout, int M, int Nn, int K, float escale)
{
    __shared__ __bf16 As[128][40];
    __shared__ __bf16 Bs[128][40];
    const int t = threadIdx.x;
    const int m0 = blockIdx.y * 128, n0 = blockIdx.x * 128;
    const int wave = t >> 6, lane = t & 63;
    const int wm = (wave >> 1) * 64, wn = (wave & 1) * 64;
    const int quad = lane >> 4, l16 = lane & 15;
    floatx4 acc[4][4] = {};
    for (int k0 = 0; k0 < K; k0 += 32) {
#pragma unroll
        for (int i = 0; i < 2; i++) {
            int idx = t + i * 256;
            int r = idx >> 2, sg = (idx & 3) * 8;
            *(uint4*)&As[r][sg] = *(const uint4*)(A + (size_t)(m0 + r) * K + k0 + sg);
            *(uint4*)&Bs[r][sg] = *(const uint4*)(Bt + (size_t)(n0 + r) * K + k0 + sg);
        }
        __syncthreads();
        bf16x8 af[4], bfr[4];
#pragma unroll
        for (int mi = 0; mi < 4; mi++) af[mi]  = *(const bf16x8*)&As[wm + mi * 16 + l16][quad * 8];
#pragma unroll
        for (int nj = 0; nj < 4; nj++) bfr[nj] = *(const bf16x8*)&Bs[wn + nj * 16 + l16][quad * 8];
#pragma unroll
        for (int mi = 0; mi < 4; mi++)
#pragma unroll
            for (int nj = 0; nj < 4; nj++)
                acc[mi][nj] = __builtin_amdgcn_mfma_f32_16x16x32_bf16(af[mi], bfr[nj], acc[mi][nj], 0, 0, 0);
        __syncthreads();
    }
#pragma unroll
    for (int mi = 0; mi < 4; mi++)
#pragma unroll
        for (int nj = 0; nj < 4; nj++) {
            int col = n0 + wn + nj * 16 + l16;
#pragma unroll
            for (int r = 0; r < 4; r++) {
                int row = m0 + wm + mi * 16 + quad * 4 + r;
                float bval = bias ? (BIASROW ? bias[row] : bias[col]) : 0.f;
                float v = (acc[mi][nj][r] + bval) * escale;
                if (ACT == 1) v = fmaxf(v, 0.f);
                if (ACT == 2) v = 0.5f * v * (1.f + erff(v * 0.70710678118654752f));
                if (OUTBF16) ((__bf16*)Cout)[(size_t)row * Nn + col] = (__bf16)v;
                else         ((float*)Cout)[(size_t)row * Nn + col] = v;
            }
        }
}

// ---------------- conv1d as bf16 MFMA implicit GEMM, fused embedding gather ----
__global__ __launch_bounds__(256) void conv_mfma(const int* __restrict__ seq,
    const __bf16* __restrict__ embb, const __bf16* __restrict__ wtb,
    const float* __restrict__ bias, __bf16* __restrict__ C, int b_base)
{
    __shared__ __bf16 As[128][40];
    __shared__ __bf16 Bs[128][40];
    __shared__ int toks[130];
    const int t = threadIdx.x;
    const int m0 = blockIdx.y * 128, n0 = blockIdx.x * 128;
    const int b = b_base + (m0 >> 10), l0 = m0 & 1023;
    if (t < 130) {
        int l = l0 + t - 1;
        toks[t] = (l >= 0 && l < LPN) ? seq[b * LPN + l] : -1;
    }
    const int wave = t >> 6, lane = t & 63;
    const int wm = (wave >> 1) * 64, wn = (wave & 1) * 64;
    const int quad = lane >> 4, l16 = lane & 15;
    floatx4 acc[4][4] = {};
    __syncthreads();
    for (int k0 = 0; k0 < 768; k0 += 32) {
        int dl = k0 >> 8, c0 = k0 & 255;
#pragma unroll
        for (int i = 0; i < 2; i++) {
            int idx = t + i * 256;
            int r = idx >> 2, sg = (idx & 3) * 8;
            int tok = toks[r + dl];
            uint4 av = make_uint4(0u, 0u, 0u, 0u);
            if (tok >= 0) av = *(const uint4*)(embb + (size_t)tok * HID + c0 + sg);
            *(uint4*)&As[r][sg] = av;
            *(uint4*)&Bs[r][sg] = *(const uint4*)(wtb + (size_t)(n0 + r) * 768 + k0 + sg);
        }
        __syncthreads();
        bf16x8 af[4], bfr[4];
#pragma unroll
        for (int mi = 0; mi < 4; mi++) af[mi]  = *(const bf16x8*)&As[wm + mi * 16 + l16][quad * 8];
#pragma unroll
        for (int nj = 0; nj < 4; nj++) bfr[nj] = *(const bf16x8*)&Bs[wn + nj * 16 + l16][quad * 8];
#pragma unroll
        for (int mi = 0; mi < 4; mi++)
#pragma unroll
            for (int nj = 0; nj < 4; nj++)
                acc[mi][nj] = __builtin_amdgcn_mfma_f32_16x16x32_bf16(af[mi], bfr[nj], acc[mi][nj], 0, 0, 0);
        __syncthreads();
    }
#pragma unroll
    for (int mi = 0; mi < 4; mi++)
#pragma unroll
        for (int nj = 0; nj < 4; nj++) {
            int col = n0 + wn + nj * 16 + l16;
            float bval = bias[col];
#pragma unroll
            for (int r = 0; r < 4; r++) {
                int row = m0 + wm + mi * 16 + quad * 4 + r;
                float v = fmaxf(acc[mi][nj][r] + bval, 0.f);
                C[(size_t)row * 256 + col] = (__bf16)v;
            }
        }
}

// ---------------- conversion kernels ----------------
__global__ void cvt_k(const float* __restrict__ in, __bf16* __restrict__ out, int n)
{
    int i = blockIdx.x * 256 + threadIdx.x;
    if (i < n) out[i] = (__bf16)in[i];
}

// out[n*K + k] = (bf16) in[k*N + n]
__global__ void cvtT_k(const float* __restrict__ in, __bf16* __restrict__ out, int K, int N)
{
    int i = blockIdx.x * 256 + threadIdx.x;
    if (i >= K * N) return;
    int n = i / K, k = i - n * K;
    out[i] = (__bf16)in[(size_t)k * N + n];
}

// wtb[n*768 + dl*256 + kk] = (bf16) conv_w[n*768 + kk*3 + dl]
__global__ void cvtwt_k(const float* __restrict__ cw, __bf16* __restrict__ wtb)
{
    int i = blockIdx.x * 256 + threadIdx.x;     // < 196608
    int n = i / 768, r = i - n * 768;
    int dl = r >> 8, kk = r & 255;
    wtb[i] = (__bf16)cw[(size_t)n * 768 + kk * 3 + dl];
}

// ---------------- GAT pieces ----------------
__global__ __launch_bounds__(256) void asad_k(const float* __restrict__ hg,
    const float* __restrict__ as_, const float* __restrict__ ad_,
    float* __restrict__ a_s, float* __restrict__ a_d)
{
    int n = blockIdx.x, t = threadIdx.x;
    float h0 = hg[(size_t)n * 512 + t];
    float h1 = hg[(size_t)n * 512 + 256 + t];
    float p0 = h0 * as_[t], p1 = h1 * as_[256 + t];
    float p2 = h0 * ad_[t], p3 = h1 * ad_[256 + t];
#pragma unroll
    for (int off = 32; off >= 1; off >>= 1) {
        p0 += __shfl_down(p0, off, 64);
        p1 += __shfl_down(p1, off, 64);
        p2 += __shfl_down(p2, off, 64);
        p3 += __shfl_down(p3, off, 64);
    }
    __shared__ float red[4][4];
    int wave = t >> 6, lane = t & 63;
    if (lane == 0) { red[wave][0] = p0; red[wave][1] = p1; red[wave][2] = p2; red[wave][3] = p3; }
    __syncthreads();
    if (t < 4) {
        float v = red[0][t] + red[1][t] + red[2][t] + red[3][t];
        if (t == 0) a_s[n * 2 + 0] = v;
        if (t == 1) a_s[n * 2 + 1] = v;
        if (t == 2) a_d[n * 2 + 0] = v;
        if (t == 3) a_d[n * 2 + 1] = v;
    }
}

__global__ void edge1_k(const int* __restrict__ ei, const float* __restrict__ a_s,
    const float* __restrict__ a_d, float* __restrict__ ebuf, unsigned* __restrict__ emaxU)
{
    int e = blockIdx.x * 256 + threadIdx.x;
    if (e >= ETOT) return;
    int s, d;
    if (e < NED) { s = ei[e]; d = ei[NED + e]; } else { s = d = e - NED; }
#pragma unroll
    for (int g = 0; g < 2; g++) {
        float v = a_s[s * 2 + g] + a_d[d * 2 + g];
        v = (v > 0.f) ? v : 0.2f * v;
        ebuf[(size_t)e * 2 + g] = v;
        atomicMax(&emaxU[d * 2 + g], f2s(v));
    }
}

__global__ void edge2_k(const int* __restrict__ ei, const float* __restrict__ ebuf,
    const unsigned* __restrict__ emaxU, float* __restrict__ exbuf, float* __restrict__ den)
{
    int e = blockIdx.x * 256 + threadIdx.x;
    if (e >= ETOT) return;
    int d;
    if (e < NED) { d = ei[NED + e]; } else { d = e - NED; }
#pragma unroll
    for (int g = 0; g < 2; g++) {
        float mx = s2f(emaxU[d * 2 + g]);
        float ex = __expf(ebuf[(size_t)e * 2 + g] - mx);
        exbuf[(size_t)e * 2 + g] = ex;
        atomicAdd(&den[d * 2 + g], ex);
    }
}

__global__ __launch_bounds__(512) void edge3_k(const int* __restrict__ ei,
    const float* __restrict__ hg, const float* __restrict__ exbuf,
    const float* __restrict__ den, float* __restrict__ og)
{
    int e = blockIdx.x;
    int ch = threadIdx.x;     // 0..511
    int s, d;
    if (e < NED) { s = ei[e]; d = ei[NED + e]; } else { s = d = e - NED; }
    int g = ch >> 8;
    float alpha = exbuf[(size_t)e * 2 + g] / den[d * 2 + g];
    atomicAdd(&og[(size_t)d * 512 + ch], hg[(size_t)s * 512 + ch] * alpha);
}

// elu(mean over heads + bias) -> fp32 + bf16
__global__ void gatfin_k(const float* __restrict__ og, const float* __restrict__ bias,
                         float* __restrict__ out, __bf16* __restrict__ outb)
{
    int n = blockIdx.x, c = threadIdx.x;
    float v = 0.5f * (og[(size_t)n * 512 + c] + og[(size_t)n * 512 + 256 + c]) + bias[c];
    v = (v > 0.f) ? v : expm1f(v);
    out[(size_t)n * 256 + c] = v;
    outb[(size_t)n * 256 + c] = (__bf16)v;
}

// ---------------- MFMA flash cross-attention ----------------
// block=(local graph bl, head h), 4 waves x 16 q-rows. Q pre-scaled by 1/8.
// Kb row-major bf16 [CB*1024, 256]; Vtb bf16 [256, CB*1024] (ld=ldV).
// Only LDS: per-wave P tile (C->A layout round trip; intra-wave, no barrier)
// + mask. Output ctx bf16.
__global__ __launch_bounds__(256) void attn2_k(const __bf16* __restrict__ Qb,
    const __bf16* __restrict__ Kb, const __bf16* __restrict__ Vtb,
    const int* __restrict__ seq, __bf16* __restrict__ O, int b0, int ldV)
{
    __shared__ __bf16 Ps[4][16][72];
    __shared__ float mask_s[LPN];
    const int t = threadIdx.x;
    const int bl = blockIdx.x >> 2, h = blockIdx.x & 3;
    const int b = b0 + bl;
    const int w = t >> 6, lane = t & 63;
    const int quad = lane >> 4, l16 = lane & 15;
    for (int i = t; i < LPN; i += 256)
        mask_s[i] = (seq[b * LPN + i] == 0) ? -1e9f : 0.f;
    // Q A-fragments for this wave's 16 q rows (held for whole kernel)
    const __bf16* qrow = Qb + (size_t)(b * 64 + w * 16 + l16) * HID + h * HD;
    bf16x8 aq0 = *(const bf16x8*)(qrow + quad * 8);
    bf16x8 aq1 = *(const bf16x8*)(qrow + 32 + quad * 8);
    float m_run[4] = {-3e38f, -3e38f, -3e38f, -3e38f};
    float l_run[4] = {0.f, 0.f, 0.f, 0.f};
    floatx4 ctx[4] = {};
    __syncthreads();
    for (int kp0 = 0; kp0 < LPN; kp0 += 64) {
        // ---- S = Q @ K^T (16q x 64k per wave) ----
        floatx4 s[4];
#pragma unroll
        for (int nj = 0; nj < 4; nj++) {
            const __bf16* krow = Kb + (size_t)(bl * LPN + kp0 + nj * 16 + l16) * HID + h * HD;
            bf16x8 bk0 = *(const bf16x8*)(krow + quad * 8);
            bf16x8 bk1 = *(const bf16x8*)(krow + 32 + quad * 8);
            floatx4 z = {0.f, 0.f, 0.f, 0.f};
            s[nj] = __builtin_amdgcn_mfma_f32_16x16x32_bf16(aq0, bk0, z, 0, 0, 0);
            s[nj] = __builtin_amdgcn_mfma_f32_16x16x32_bf16(aq1, bk1, s[nj], 0, 0, 0);
        }
        // ---- mask ----
#pragma unroll
        for (int nj = 0; nj < 4; nj++) {
            float mval = mask_s[kp0 + nj * 16 + l16];
#pragma unroll
            for (int r = 0; r < 4; r++) s[nj][r] += mval;
        }
        // ---- online softmax, rows owned per-quad, reduce over l16 lanes ----
        float alpha[4];
#pragma unroll
        for (int r = 0; r < 4; r++) {
            float mx = fmaxf(fmaxf(s[0][r], s[1][r]), fmaxf(s[2][r], s[3][r]));
#pragma unroll
            for (int off = 1; off < 16; off <<= 1) mx = fmaxf(mx, __shfl_xor(mx, off, 64));
            float mn = fmaxf(m_run[r], mx);
            alpha[r] = __expf(m_run[r] - mn);
            m_run[r] = mn;
            float rs = 0.f;
#pragma unroll
            for (int nj = 0; nj < 4; nj++) {
                float p = __expf(s[nj][r] - mn);
                s[nj][r] = p;
                rs += p;
            }
#pragma unroll
            for (int off = 1; off < 16; off <<= 1) rs += __shfl_xor(rs, off, 64);
            l_run[r] = l_run[r] * alpha[r] + rs;
        }
        // ---- P (C/D layout) -> LDS -> A-layout frags (intra-wave only) ----
#pragma unroll
        for (int nj = 0; nj < 4; nj++)
#pragma unroll
            for (int r = 0; r < 4; r++)
                Ps[w][quad * 4 + r][nj * 16 + l16] = (__bf16)s[nj][r];
        bf16x8 pa0 = *(const bf16x8*)&Ps[w][l16][quad * 8];
        bf16x8 pa1 = *(const bf16x8*)&Ps[w][l16][32 + quad * 8];
        // ---- ctx = ctx*alpha + P @ V ----
#pragma unroll
        for (int dj = 0; dj < 4; dj++) {
#pragma unroll
            for (int r = 0; r < 4; r++) ctx[dj][r] *= alpha[r];
            const __bf16* vrow = Vtb + (size_t)(h * HD + dj * 16 + l16) * ldV + bl * LPN + kp0;
            bf16x8 bv0 = *(const bf16x8*)(vrow + quad * 8);
            bf16x8 bv1 = *(const bf16x8*)(vrow + 32 + quad * 8);
            ctx[dj] = __builtin_amdgcn_mfma_f32_16x16x32_bf16(pa0, bv0, ctx[dj], 0, 0, 0);
            ctx[dj] = __builtin_amdgcn_mfma_f32_16x16x32_bf16(pa1, bv1, ctx[dj], 0, 0, 0);
        }
    }
#pragma unroll
    for (int dj = 0; dj < 4; dj++)
#pragma unroll
        for (int r = 0; r < 4; r++) {
            int q = b * 64 + w * 16 + quad * 4 + r;
            int d = h * HD + dj * 16 + l16;
            O[(size_t)q * HID + d] = (__bf16)(ctx[dj][r] / l_run[r]);
        }
}

// ---------------- LayerNorm(residual) -> fp32 (+ optional bf16) ----------------
__device__ __forceinline__ float blockSum256(float v, float* red)
{
#pragma unroll
    for (int off = 32; off >= 1; off >>= 1) v += __shfl_down(v, off, 64);
    int wave = threadIdx.x >> 6, lane = threadIdx.x & 63;
    if (lane == 0) red[wave] = v;
    __syncthreads();
    float s = red[0] + red[1] + red[2] + red[3];
    __syncthreads();
    return s;
}

__global__ __launch_bounds__(256) void lnres_k(const float* __restrict__ A,
    const float* __restrict__ Bb, const float* __restrict__ g,
    const float* __restrict__ be, float* __restrict__ Y, __bf16* __restrict__ Yb)
{
    __shared__ float red[4];
    int r = blockIdx.x, t = threadIdx.x;
    float v = A[(size_t)r * 256 + t] + Bb[(size_t)r * 256 + t];
    float mean = blockSum256(v, red) * (1.f / 256.f);
    float d = v - mean;
    float var = blockSum256(d * d, red) * (1.f / 256.f);
    float o = d * rsqrtf(var + 1e-5f) * g[t] + be[t];
    Y[(size_t)r * 256 + t] = o;
    if (Yb) Yb[(size_t)r * 256 + t] = (__bf16)o;
}

// ---------------- mean pool ----------------
__global__ void pool_k(const float* __restrict__ Y, float* __restrict__ P)
{
    int b = blockIdx.x, c = threadIdx.x;
    float s = 0.f;
#pragma unroll 8
    for (int q = 0; q < 64; q++) s += Y[(size_t)(b * 64 + q) * 256 + c];
    P[(size_t)b * 256 + c] = s / (64.f + 1e-6f);
}

// ---------------- launch ----------------
extern "C" void kernel_launch(void* const* d_in, const int* in_sizes, int n_in,
                              void* d_out, int out_size, void* d_ws, size_t ws_size,
                              hipStream_t stream)
{
    const float* x     = (const float*)d_in[0];
    const int*   ei    = (const int*)d_in[1];
    const int*   pseq  = (const int*)d_in[3];
    const float* w1  = (const float*)d_in[4];
    const float* as1 = (const float*)d_in[5];
    const float* ad1 = (const float*)d_in[6];
    const float* b1  = (const float*)d_in[7];
    const float* w2  = (const float*)d_in[8];
    const float* as2 = (const float*)d_in[9];
    const float* ad2 = (const float*)d_in[10];
    const float* b2  = (const float*)d_in[11];
    const float* w3  = (const float*)d_in[12];
    const float* as3 = (const float*)d_in[13];
    const float* ad3 = (const float*)d_in[14];
    const float* b3  = (const float*)d_in[15];
    const float* emb    = (const float*)d_in[16];
    const float* conv_w = (const float*)d_in[17];
    const float* conv_b = (const float*)d_in[18];
    const float* wq = (const float*)d_in[19];
    const float* bq = (const float*)d_in[20];
    const float* wk = (const float*)d_in[21];
    const float* bk = (const float*)d_in[22];
    const float* wv = (const float*)d_in[23];
    const float* bv = (const float*)d_in[24];
    const float* wo = (const float*)d_in[25];
    const float* bo = (const float*)d_in[26];
    const float* ln1_g = (const float*)d_in[27];
    const float* ln1_b = (const float*)d_in[28];
    const float* ffw1  = (const float*)d_in[29];
    const float* ffb1  = (const float*)d_in[30];
    const float* ffw2  = (const float*)d_in[31];
    const float* ffb2  = (const float*)d_in[32];
    const float* ln2_g = (const float*)d_in[33];
    const float* ln2_b = (const float*)d_in[34];
    const float* fc1_w = (const float*)d_in[35];
    const float* fc1_b = (const float*)d_in[36];
    const float* fc2_w = (const float*)d_in[37];
    const float* fc2_b = (const float*)d_in[38];
    (void)in_sizes; (void)n_in; (void)out_size;

    char* ws = (char*)d_ws;
    size_t off = 0;
    auto alloc = [&](size_t bytes) -> char* {
        char* p = ws + off;
        off += (bytes + 255) & ~(size_t)255;
        return p;
    };
    // ---- fixed arena ----
    float* hg    = (float*)alloc((size_t)NAT * 512 * 4);   // 32 MB
    float* og    = (float*)alloc((size_t)NAT * 512 * 4);   // 32 MB; later attno|ybuf
    float* hb0   = (float*)alloc((size_t)NAT * 256 * 4);   // lig fp32
    float* hb1   = (float*)alloc((size_t)NAT * 256 * 4);   // later ff2o
    __bf16* xb   = (__bf16*)alloc((size_t)NAT * FIN * 2);
    __bf16* hbb  = (__bf16*)alloc((size_t)NAT * 256 * 2);  // per-layer bf16 feats; final = ligb
    __bf16* qbb  = (__bf16*)alloc((size_t)NAT * 256 * 2);
    __bf16* ctxbb= (__bf16*)alloc((size_t)NAT * 256 * 2);
    __bf16* ybb  = (__bf16*)alloc((size_t)NAT * 256 * 2);
    float* a_s   = (float*)alloc((size_t)NAT * 2 * 4);
    float* a_d   = (float*)alloc((size_t)NAT * 2 * 4);
    float* ebuf  = (float*)alloc((size_t)ETOT * 2 * 4);
    float* exbuf = (float*)alloc((size_t)ETOT * 2 * 4);
    unsigned* emaxU = (unsigned*)alloc((size_t)NAT * 2 * 4);
    float* den   = (float*)alloc((size_t)NAT * 2 * 4);
    float* pooled = (float*)alloc((size_t)256 * 256 * 4);
    float* fc1o   = (float*)alloc((size_t)256 * 256 * 4);
    __bf16* embb = (__bf16*)alloc((size_t)22 * 256 * 2);
    __bf16* wtb  = (__bf16*)alloc((size_t)256 * 768 * 2);
    __bf16* w1T  = (__bf16*)alloc((size_t)512 * 64 * 2);
    __bf16* w2T  = (__bf16*)alloc((size_t)512 * 256 * 2);
    __bf16* w3T  = (__bf16*)alloc((size_t)512 * 256 * 2);
    __bf16* wkT  = (__bf16*)alloc((size_t)256 * 256 * 2);
    __bf16* wvT  = (__bf16*)alloc((size_t)256 * 256 * 2);
    __bf16* wqT  = (__bf16*)alloc((size_t)256 * 256 * 2);
    __bf16* woT  = (__bf16*)alloc((size_t)256 * 256 * 2);
    __bf16* f1T  = (__bf16*)alloc((size_t)1024 * 256 * 2);
    __bf16* f2T  = (__bf16*)alloc((size_t)256 * 1024 * 2);
    // ---- variable region: protein chunks, then FFN buffers ----
    size_t fixed_end = off;
    size_t rem = (ws_size > fixed_end) ? ws_size - fixed_end : 0;
    const size_t G1 = (size_t)LPN * 256 * 2;               // 0.5 MB per graph per bf16 buf
    const size_t ffneed = (size_t)NAT * 1024 * 2 + (size_t)NAT * 256 * 4;
    int CB = 8;
    {
        const int cands[5] = {128, 64, 32, 16, 8};
        for (int ci = 0; ci < 5; ci++) {
            size_t regneed = 3 * (size_t)cands[ci] * G1;
            if (regneed < ffneed) regneed = ffneed;
            if (regneed <= rem) { CB = cands[ci]; break; }
        }
    }
    char* region   = ws + fixed_end;
    __bf16* pconvb = (__bf16*)region;
    __bf16* kbb    = (__bf16*)(region + (size_t)CB * G1);
    __bf16* vtb    = (__bf16*)(region + 2 * (size_t)CB * G1);
    __bf16* ffbb   = (__bf16*)region;                       // after protein phase
    float*  y2     = (float*)(region + (size_t)NAT * 1024 * 2);
    // aliases of fixed buffers whose lifetime has ended:
    float* attno = og;
    float* ybuf  = og + (size_t)NAT * 256;
    float* ff2o  = hb1;

    // ---------------- weight / input conversions ----------------
    cvt_k<<<(NAT * FIN + 255) / 256, 256, 0, stream>>>(x, xb, NAT * FIN);
    cvt_k<<<(22 * 256 + 255) / 256, 256, 0, stream>>>(emb, embb, 22 * 256);
    cvtwt_k<<<768, 256, 0, stream>>>(conv_w, wtb);
    cvtT_k<<<(64 * 512 + 255) / 256, 256, 0, stream>>>(w1, w1T, 64, 512);
    cvtT_k<<<(256 * 512 + 255) / 256, 256, 0, stream>>>(w2, w2T, 256, 512);
    cvtT_k<<<(256 * 512 + 255) / 256, 256, 0, stream>>>(w3, w3T, 256, 512);
    cvtT_k<<<256, 256, 0, stream>>>(wk, wkT, 256, 256);
    cvtT_k<<<256, 256, 0, stream>>>(wv, wvT, 256, 256);
    cvtT_k<<<256, 256, 0, stream>>>(wq, wqT, 256, 256);
    cvtT_k<<<256, 256, 0, stream>>>(wo, woT, 256, 256);
    cvtT_k<<<1024, 256, 0, stream>>>(ffw1, f1T, 256, 1024);
    cvtT_k<<<1024, 256, 0, stream>>>(ffw2, f2T, 1024, 256);

    // ---------------- ligand GNN: 3 GAT layers ----------------
    const __bf16* WT[3] = {w1T, w2T, w3T};
    const float* asl[3] = {as1, as2, as3};
    const float* adl[3] = {ad1, ad2, ad3};
    const float* bl[3]  = {b1, b2, b3};
    float* houts[3] = {hb0, hb1, hb0};
    const __bf16* hinb = xb;
    int Kdim = FIN;
    for (int l = 0; l < 3; l++) {
        gemm_mfma<0, 0, 0><<<dim3(4, NAT / 128), 256, 0, stream>>>(hinb, WT[l], nullptr, hg, NAT, 512, Kdim, 1.f);
        asad_k<<<NAT, 256, 0, stream>>>(hg, asl[l], adl[l], a_s, a_d);
        hipMemsetAsync(emaxU, 0, (size_t)NAT * 2 * 4, stream);
        hipMemsetAsync(den, 0, (size_t)NAT * 2 * 4, stream);
        hipMemsetAsync(og, 0, (size_t)NAT * 512 * 4, stream);
        edge1_k<<<(ETOT + 255) / 256, 256, 0, stream>>>(ei, a_s, a_d, ebuf, emaxU);
        edge2_k<<<(ETOT + 255) / 256, 256, 0, stream>>>(ei, ebuf, emaxU, exbuf, den);
        edge3_k<<<ETOT, 512, 0, stream>>>(ei, hg, exbuf, den, og);
        gatfin_k<<<NAT, 256, 0, stream>>>(og, bl[l], houts[l], hbb);
        hinb = hbb;
        Kdim = HID;
    }
    const float* lig = hb0;
    const __bf16* ligb = hbb;

    // ---------------- Q projection (scale 1/8 folded in) ----------------
    gemm_mfma<0, 1, 0><<<dim3(2, NAT / 128), 256, 0, stream>>>(ligb, wqT, bq, qbb, NAT, 256, 256, 0.125f);

    // ---------------- protein branch + attention, chunked over graphs ----------
    for (int b0 = 0; b0 < BGR; b0 += CB) {
        int Mc = CB * LPN;
        conv_mfma<<<dim3(2, Mc / 128), 256, 0, stream>>>(pseq, embb, wtb, conv_b, pconvb, b0);
        gemm_mfma<0, 1, 0><<<dim3(2, Mc / 128), 256, 0, stream>>>(pconvb, wkT, bk, kbb, Mc, 256, 256, 1.f);
        // V^T = wv^T @ pconv^T  (row-major [256][Mc], bias per row)
        gemm_mfma<0, 1, 1><<<dim3(Mc / 128, 2), 256, 0, stream>>>(wvT, pconvb, bv, vtb, 256, Mc, 256, 1.f);
        attn2_k<<<CB * 4, 256, 0, stream>>>(qbb, kbb, vtb, pseq, ctxbb, b0, Mc);
    }

    // ---------------- attention out proj + LN + FFN + LN ----------------
    gemm_mfma<0, 0, 0><<<dim3(2, NAT / 128), 256, 0, stream>>>(ctxbb, woT, bo, attno, NAT, 256, 256, 1.f);
    lnres_k<<<NAT, 256, 0, stream>>>(lig, attno, ln1_g, ln1_b, ybuf, ybb);
    gemm_mfma<2, 1, 0><<<dim3(8, NAT / 128), 256, 0, stream>>>(ybb, f1T, ffb1, ffbb, NAT, 1024, 256, 1.f);
    gemm_mfma<0, 0, 0><<<dim3(2, NAT / 128), 256, 0, stream>>>(ffbb, f2T, ffb2, ff2o, NAT, 256, 1024, 1.f);
    lnres_k<<<NAT, 256, 0, stream>>>(ybuf, ff2o, ln2_g, ln2_b, y2, nullptr);

    // ---------------- pool + MLP head (fp32, tiny) ----------------
    pool_k<<<BGR, 256, 0, stream>>>(y2, pooled);
    gemm_k<1><<<dim3(4, 4), 256, 0, stream>>>(pooled, fc1_w, fc1_b, fc1o, 256, 256, 256);
    gemm_k<0><<<dim3(1, 4), 256, 0, stream>>>(fc1o, fc2_w, fc2_b, (float*)d_out, 256, 1, 256);
}

// Round 5
// 1210.787 us; speedup vs baseline: 3.7502x; 1.3084x over previous
//
#include <hip/hip_runtime.h>
#include <hip/hip_bf16.h>
#include <cstdint>
#include <cstddef>

#define NAT 16384
#define NED 65536
#define ETOT (NED + NAT)
#define BGR 256
#define MAXQ 64
#define FIN 64
#define HID 256
#define LPN 1024
#define HD 64

typedef __bf16 bf16x8 __attribute__((ext_vector_type(8)));
typedef float floatx4 __attribute__((ext_vector_type(4)));

// ---------------- fp32 GEMM (small head matmuls only) ----------------
template<int ACT>
__global__ __launch_bounds__(256) void gemm_k(const float* __restrict__ A,
    const float* __restrict__ Bm, const float* __restrict__ bias,
    float* __restrict__ C, int M, int Nn, int K)
{
    __shared__ float As[16][68];
    __shared__ float Bs[16][68];
    const int t  = threadIdx.x;
    const int m0 = blockIdx.y * 64, n0 = blockIdx.x * 64;
    const int tm = (t & 15) * 4, tn = (t >> 4) * 4;
    const int lm = t >> 2,  lkc = (t & 3) * 4;
    const int lkk = t >> 4, lnc = (t & 15) * 4;
    float acc[4][4] = {};
    for (int k0 = 0; k0 < K; k0 += 16) {
        float4 av = *(const float4*)(A + (size_t)(m0 + lm) * K + k0 + lkc);
        As[lkc + 0][lm] = av.x; As[lkc + 1][lm] = av.y;
        As[lkc + 2][lm] = av.z; As[lkc + 3][lm] = av.w;
        if (n0 + lnc + 3 < Nn) {
            float4 bv = *(const float4*)(Bm + (size_t)(k0 + lkk) * Nn + n0 + lnc);
            Bs[lkk][lnc + 0] = bv.x; Bs[lkk][lnc + 1] = bv.y;
            Bs[lkk][lnc + 2] = bv.z; Bs[lkk][lnc + 3] = bv.w;
        } else {
            for (int j = 0; j < 4; j++) {
                int n = n0 + lnc + j;
                Bs[lkk][lnc + j] = (n < Nn) ? Bm[(size_t)(k0 + lkk) * Nn + n] : 0.f;
            }
        }
        __syncthreads();
#pragma unroll
        for (int kk = 0; kk < 16; kk++) {
            float4 af = *(const float4*)&As[kk][tm];
            float4 bf = *(const float4*)&Bs[kk][tn];
            float a_[4] = {af.x, af.y, af.z, af.w};
            float b_[4] = {bf.x, bf.y, bf.z, bf.w};
#pragma unroll
            for (int i = 0; i < 4; i++)
#pragma unroll
                for (int j = 0; j < 4; j++) acc[i][j] += a_[i] * b_[j];
        }
        __syncthreads();
    }
#pragma unroll
    for (int i = 0; i < 4; i++) {
#pragma unroll
        for (int j = 0; j < 4; j++) {
            int n = n0 + tn + j;
            if (n < Nn) {
                float v = acc[i][j] + (bias ? bias[n] : 0.f);
                if (ACT == 1) v = fmaxf(v, 0.f);
                C[(size_t)(m0 + tm + i) * Nn + n] = v;
            }
        }
    }
}

// ---------------- bf16 MFMA GEMM: C = act((A@Bt^T + bias) * escale) ----------
template<int ACT, int OUTBF16, int BIASROW>
__global__ __launch_bounds__(256) void gemm_mfma(const __bf16* __restrict__ A,
    const __bf16* __restrict__ Bt, const float* __restrict__ bias,
    void* __restrict__ Cout, int M, int Nn, int K, float escale)
{
    __shared__ __bf16 As[128][40];
    __shared__ __bf16 Bs[128][40];
    const int t = threadIdx.x;
    const int m0 = blockIdx.y * 128, n0 = blockIdx.x * 128;
    const int wave = t >> 6, lane = t & 63;
    const int wm = (wave >> 1) * 64, wn = (wave & 1) * 64;
    const int quad = lane >> 4, l16 = lane & 15;
    floatx4 acc[4][4] = {};
    for (int k0 = 0; k0 < K; k0 += 32) {
#pragma unroll
        for (int i = 0; i < 2; i++) {
            int idx = t + i * 256;
            int r = idx >> 2, sg = (idx & 3) * 8;
            *(uint4*)&As[r][sg] = *(const uint4*)(A + (size_t)(m0 + r) * K + k0 + sg);
            *(uint4*)&Bs[r][sg] = *(const uint4*)(Bt + (size_t)(n0 + r) * K + k0 + sg);
        }
        __syncthreads();
        bf16x8 af[4], bfr[4];
#pragma unroll
        for (int mi = 0; mi < 4; mi++) af[mi]  = *(const bf16x8*)&As[wm + mi * 16 + l16][quad * 8];
#pragma unroll
        for (int nj = 0; nj < 4; nj++) bfr[nj] = *(const bf16x8*)&Bs[wn + nj * 16 + l16][quad * 8];
#pragma unroll
        for (int mi = 0; mi < 4; mi++)
#pragma unroll
            for (int nj = 0; nj < 4; nj++)
                acc[mi][nj] = __builtin_amdgcn_mfma_f32_16x16x32_bf16(af[mi], bfr[nj], acc[mi][nj], 0, 0, 0);
        __syncthreads();
    }
#pragma unroll
    for (int mi = 0; mi < 4; mi++)
#pragma unroll
        for (int nj = 0; nj < 4; nj++) {
            int col = n0 + wn + nj * 16 + l16;
#pragma unroll
            for (int r = 0; r < 4; r++) {
                int row = m0 + wm + mi * 16 + quad * 4 + r;
                float bval = bias ? (BIASROW ? bias[row] : bias[col]) : 0.f;
                float v = (acc[mi][nj][r] + bval) * escale;
                if (ACT == 1) v = fmaxf(v, 0.f);
                if (ACT == 2) v = 0.5f * v * (1.f + erff(v * 0.70710678118654752f));
                if (OUTBF16) ((__bf16*)Cout)[(size_t)row * Nn + col] = (__bf16)v;
                else         ((float*)Cout)[(size_t)row * Nn + col] = v;
            }
        }
}

// ---------------- conv1d as bf16 MFMA implicit GEMM, fused embedding gather ----
__global__ __launch_bounds__(256) void conv_mfma(const int* __restrict__ seq,
    const __bf16* __restrict__ embb, const __bf16* __restrict__ wtb,
    const float* __restrict__ bias, __bf16* __restrict__ C, int b_base)
{
    __shared__ __bf16 As[128][40];
    __shared__ __bf16 Bs[128][40];
    __shared__ int toks[130];
    const int t = threadIdx.x;
    const int m0 = blockIdx.y * 128, n0 = blockIdx.x * 128;
    const int b = b_base + (m0 >> 10), l0 = m0 & 1023;
    if (t < 130) {
        int l = l0 + t - 1;
        toks[t] = (l >= 0 && l < LPN) ? seq[b * LPN + l] : -1;
    }
    const int wave = t >> 6, lane = t & 63;
    const int wm = (wave >> 1) * 64, wn = (wave & 1) * 64;
    const int quad = lane >> 4, l16 = lane & 15;
    floatx4 acc[4][4] = {};
    __syncthreads();
    for (int k0 = 0; k0 < 768; k0 += 32) {
        int dl = k0 >> 8, c0 = k0 & 255;
#pragma unroll
        for (int i = 0; i < 2; i++) {
            int idx = t + i * 256;
            int r = idx >> 2, sg = (idx & 3) * 8;
            int tok = toks[r + dl];
            uint4 av = make_uint4(0u, 0u, 0u, 0u);
            if (tok >= 0) av = *(const uint4*)(embb + (size_t)tok * HID + c0 + sg);
            *(uint4*)&As[r][sg] = av;
            *(uint4*)&Bs[r][sg] = *(const uint4*)(wtb + (size_t)(n0 + r) * 768 + k0 + sg);
        }
        __syncthreads();
        bf16x8 af[4], bfr[4];
#pragma unroll
        for (int mi = 0; mi < 4; mi++) af[mi]  = *(const bf16x8*)&As[wm + mi * 16 + l16][quad * 8];
#pragma unroll
        for (int nj = 0; nj < 4; nj++) bfr[nj] = *(const bf16x8*)&Bs[wn + nj * 16 + l16][quad * 8];
#pragma unroll
        for (int mi = 0; mi < 4; mi++)
#pragma unroll
            for (int nj = 0; nj < 4; nj++)
                acc[mi][nj] = __builtin_amdgcn_mfma_f32_16x16x32_bf16(af[mi], bfr[nj], acc[mi][nj], 0, 0, 0);
        __syncthreads();
    }
#pragma unroll
    for (int mi = 0; mi < 4; mi++)
#pragma unroll
        for (int nj = 0; nj < 4; nj++) {
            int col = n0 + wn + nj * 16 + l16;
            float bval = bias[col];
#pragma unroll
            for (int r = 0; r < 4; r++) {
                int row = m0 + wm + mi * 16 + quad * 4 + r;
                float v = fmaxf(acc[mi][nj][r] + bval, 0.f);
                C[(size_t)row * 256 + col] = (__bf16)v;
            }
        }
}

// ---------------- conversion kernels ----------------
__global__ void cvt_k(const float* __restrict__ in, __bf16* __restrict__ out, int n)
{
    int i = blockIdx.x * 256 + threadIdx.x;
    if (i < n) out[i] = (__bf16)in[i];
}

__global__ void cvtT_k(const float* __restrict__ in, __bf16* __restrict__ out, int K, int N)
{
    int i = blockIdx.x * 256 + threadIdx.x;
    if (i >= K * N) return;
    int n = i / K, k = i - n * K;
    out[i] = (__bf16)in[(size_t)k * N + n];
}

__global__ void cvtwt_k(const float* __restrict__ cw, __bf16* __restrict__ wtb)
{
    int i = blockIdx.x * 256 + threadIdx.x;     // < 196608
    int n = i / 768, r = i - n * 768;
    int dl = r >> 8, kk = r & 255;
    wtb[i] = (__bf16)cw[(size_t)n * 768 + kk * 3 + dl];
}

// ---------------- CSR build (edge_index constant across layers) ----------------
__global__ void deg_k(const int* __restrict__ ei, int* __restrict__ deg)
{
    int e = blockIdx.x * 256 + threadIdx.x;
    if (e < NED) atomicAdd(&deg[ei[NED + e]], 1);
}

// exclusive scan of 16384 degrees -> rowptr[16385]; 1 block, 256 threads x 64 elems
__global__ __launch_bounds__(256) void scan_k(const int* __restrict__ deg, int* __restrict__ rowptr)
{
    __shared__ int part[256];
    int t = threadIdx.x;
    int base = t * 64;
    int s = 0;
#pragma unroll
    for (int i = 0; i < 64; i++) s += deg[base + i];
    part[t] = s;
    __syncthreads();
    for (int off = 1; off < 256; off <<= 1) {
        int v = (t >= off) ? part[t - off] : 0;
        __syncthreads();
        part[t] += v;
        __syncthreads();
    }
    int run = t ? part[t - 1] : 0;
    for (int i = 0; i < 64; i++) { rowptr[base + i] = run; run += deg[base + i]; }
    if (t == 255) rowptr[16384] = run;
}

__global__ void scat_k(const int* __restrict__ ei, int* __restrict__ fill,
                       const int* __restrict__ rowptr, int* __restrict__ csrc)
{
    int e = blockIdx.x * 256 + threadIdx.x;
    if (e >= NED) return;
    int d = ei[NED + e];
    int pos = rowptr[d] + atomicAdd(&fill[d], 1);
    csrc[pos] = ei[e];
}

// ---------------- GAT: a_src/a_dst dots ----------------
__global__ __launch_bounds__(256) void asad_k(const float* __restrict__ hg,
    const float* __restrict__ as_, const float* __restrict__ ad_,
    float* __restrict__ a_s, float* __restrict__ a_d)
{
    int n = blockIdx.x, t = threadIdx.x;
    float h0 = hg[(size_t)n * 512 + t];
    float h1 = hg[(size_t)n * 512 + 256 + t];
    float p0 = h0 * as_[t], p1 = h1 * as_[256 + t];
    float p2 = h0 * ad_[t], p3 = h1 * ad_[256 + t];
#pragma unroll
    for (int off = 32; off >= 1; off >>= 1) {
        p0 += __shfl_down(p0, off, 64);
        p1 += __shfl_down(p1, off, 64);
        p2 += __shfl_down(p2, off, 64);
        p3 += __shfl_down(p3, off, 64);
    }
    __shared__ float red[4][4];
    int wave = t >> 6, lane = t & 63;
    if (lane == 0) { red[wave][0] = p0; red[wave][1] = p1; red[wave][2] = p2; red[wave][3] = p3; }
    __syncthreads();
    if (t < 4) {
        float v = red[0][t] + red[1][t] + red[2][t] + red[3][t];
        if (t == 0) a_s[n * 2 + 0] = v;
        if (t == 1) a_s[n * 2 + 1] = v;
        if (t == 2) a_d[n * 2 + 0] = v;
        if (t == 3) a_d[n * 2 + 1] = v;
    }
}

// ---------------- fused GAT aggregation: softmax over incoming edges + self,
// weighted gather, head-mean, bias, elu. One wave per dst node. ----------------
__global__ __launch_bounds__(256) void gat_agg(const int* __restrict__ rowptr,
    const int* __restrict__ csrc, const float* __restrict__ hg,
    const float* __restrict__ a_s, const float* __restrict__ a_d,
    const float* __restrict__ bias, float* __restrict__ out, __bf16* __restrict__ outb)
{
    const int wave = threadIdx.x >> 6, lane = threadIdx.x & 63;
    const int d = blockIdx.x * 4 + wave;
    const int beg = rowptr[d], end = rowptr[d + 1];
    const float ad0 = a_d[d * 2 + 0], ad1 = a_d[d * 2 + 1];
    // self-loop e-values
    float e0 = a_s[d * 2 + 0] + ad0; e0 = (e0 > 0.f) ? e0 : 0.2f * e0;
    float e1 = a_s[d * 2 + 1] + ad1; e1 = (e1 > 0.f) ? e1 : 0.2f * e1;
    // pass 1: max (wave-uniform scalar loop)
    float m0 = e0, m1 = e1;
    for (int p = beg; p < end; p++) {
        int s = csrc[p];
        float v0 = a_s[s * 2 + 0] + ad0; v0 = (v0 > 0.f) ? v0 : 0.2f * v0;
        float v1 = a_s[s * 2 + 1] + ad1; v1 = (v1 > 0.f) ? v1 : 0.2f * v1;
        m0 = fmaxf(m0, v0); m1 = fmaxf(m1, v1);
    }
    // pass 2: denominators
    float den0 = __expf(e0 - m0), den1 = __expf(e1 - m1);
    for (int p = beg; p < end; p++) {
        int s = csrc[p];
        float v0 = a_s[s * 2 + 0] + ad0; v0 = (v0 > 0.f) ? v0 : 0.2f * v0;
        float v1 = a_s[s * 2 + 1] + ad1; v1 = (v1 > 0.f) ? v1 : 0.2f * v1;
        den0 += __expf(v0 - m0); den1 += __expf(v1 - m1);
    }
    const float inv0 = 1.f / den0, inv1 = 1.f / den1;
    // pass 3: weighted accumulate; lane owns 8 channels of the 512
    const int ch = lane * 8;
    const int g = ch >> 8;
    const float mg = g ? m1 : m0, invg = g ? inv1 : inv0, adg = g ? ad1 : ad0;
    float acc[8] = {};
    {   // self loop
        float al = __expf((g ? e1 : e0) - mg) * invg;
        const float* hp = hg + (size_t)d * 512 + ch;
        float4 x0 = *(const float4*)hp, x1 = *(const float4*)(hp + 4);
        acc[0] += x0.x * al; acc[1] += x0.y * al; acc[2] += x0.z * al; acc[3] += x0.w * al;
        acc[4] += x1.x * al; acc[5] += x1.y * al; acc[6] += x1.z * al; acc[7] += x1.w * al;
    }
    for (int p = beg; p < end; p++) {
        int s = csrc[p];
        float v = a_s[s * 2 + g] + adg; v = (v > 0.f) ? v : 0.2f * v;
        float al = __expf(v - mg) * invg;
        const float* hp = hg + (size_t)s * 512 + ch;
        float4 x0 = *(const float4*)hp, x1 = *(const float4*)(hp + 4);
        acc[0] += x0.x * al; acc[1] += x0.y * al; acc[2] += x0.z * al; acc[3] += x0.w * al;
        acc[4] += x1.x * al; acc[5] += x1.y * al; acc[6] += x1.z * al; acc[7] += x1.w * al;
    }
    // head-mean: pair lane i <-> i+32 (head0 ch c with head1 ch c+256)
    float other[8];
#pragma unroll
    for (int j = 0; j < 8; j++) other[j] = __shfl_xor(acc[j], 32, 64);
    if (lane < 32) {
#pragma unroll
        for (int j = 0; j < 8; j++) {
            float v = 0.5f * (acc[j] + other[j]) + bias[ch + j];
            v = (v > 0.f) ? v : expm1f(v);
            out[(size_t)d * 256 + ch + j] = v;
            outb[(size_t)d * 256 + ch + j] = (__bf16)v;
        }
    }
}

// ---------------- MFMA flash cross-attention ----------------
__global__ __launch_bounds__(256) void attn2_k(const __bf16* __restrict__ Qb,
    const __bf16* __restrict__ Kb, const __bf16* __restrict__ Vtb,
    const int* __restrict__ seq, __bf16* __restrict__ O, int b0, int ldV)
{
    __shared__ __bf16 Ps[4][16][72];
    __shared__ float mask_s[LPN];
    const int t = threadIdx.x;
    const int bl = blockIdx.x >> 2, h = blockIdx.x & 3;
    const int b = b0 + bl;
    const int w = t >> 6, lane = t & 63;
    const int quad = lane >> 4, l16 = lane & 15;
    for (int i = t; i < LPN; i += 256)
        mask_s[i] = (seq[b * LPN + i] == 0) ? -1e9f : 0.f;
    const __bf16* qrow = Qb + (size_t)(b * 64 + w * 16 + l16) * HID + h * HD;
    bf16x8 aq0 = *(const bf16x8*)(qrow + quad * 8);
    bf16x8 aq1 = *(const bf16x8*)(qrow + 32 + quad * 8);
    float m_run[4] = {-3e38f, -3e38f, -3e38f, -3e38f};
    float l_run[4] = {0.f, 0.f, 0.f, 0.f};
    floatx4 ctx[4] = {};
    __syncthreads();
    for (int kp0 = 0; kp0 < LPN; kp0 += 64) {
        floatx4 s[4];
#pragma unroll
        for (int nj = 0; nj < 4; nj++) {
            const __bf16* krow = Kb + (size_t)(bl * LPN + kp0 + nj * 16 + l16) * HID + h * HD;
            bf16x8 bk0 = *(const bf16x8*)(krow + quad * 8);
            bf16x8 bk1 = *(const bf16x8*)(krow + 32 + quad * 8);
            floatx4 z = {0.f, 0.f, 0.f, 0.f};
            s[nj] = __builtin_amdgcn_mfma_f32_16x16x32_bf16(aq0, bk0, z, 0, 0, 0);
            s[nj] = __builtin_amdgcn_mfma_f32_16x16x32_bf16(aq1, bk1, s[nj], 0, 0, 0);
        }
#pragma unroll
        for (int nj = 0; nj < 4; nj++) {
            float mval = mask_s[kp0 + nj * 16 + l16];
#pragma unroll
            for (int r = 0; r < 4; r++) s[nj][r] += mval;
        }
        float alpha[4];
#pragma unroll
        for (int r = 0; r < 4; r++) {
            float mx = fmaxf(fmaxf(s[0][r], s[1][r]), fmaxf(s[2][r], s[3][r]));
#pragma unroll
            for (int off = 1; off < 16; off <<= 1) mx = fmaxf(mx, __shfl_xor(mx, off, 64));
            float mn = fmaxf(m_run[r], mx);
            alpha[r] = __expf(m_run[r] - mn);
            m_run[r] = mn;
            float rs = 0.f;
#pragma unroll
            for (int nj = 0; nj < 4; nj++) {
                float p = __expf(s[nj][r] - mn);
                s[nj][r] = p;
                rs += p;
            }
#pragma unroll
            for (int off = 1; off < 16; off <<= 1) rs += __shfl_xor(rs, off, 64);
            l_run[r] = l_run[r] * alpha[r] + rs;
        }
#pragma unroll
        for (int nj = 0; nj < 4; nj++)
#pragma unroll
            for (int r = 0; r < 4; r++)
                Ps[w][quad * 4 + r][nj * 16 + l16] = (__bf16)s[nj][r];
        bf16x8 pa0 = *(const bf16x8*)&Ps[w][l16][quad * 8];
        bf16x8 pa1 = *(const bf16x8*)&Ps[w][l16][32 + quad * 8];
#pragma unroll
        for (int dj = 0; dj < 4; dj++) {
#pragma unroll
            for (int r = 0; r < 4; r++) ctx[dj][r] *= alpha[r];
            const __bf16* vrow = Vtb + (size_t)(h * HD + dj * 16 + l16) * ldV + bl * LPN + kp0;
            bf16x8 bv0 = *(const bf16x8*)(vrow + quad * 8);
            bf16x8 bv1 = *(const bf16x8*)(vrow + 32 + quad * 8);
            ctx[dj] = __builtin_amdgcn_mfma_f32_16x16x32_bf16(pa0, bv0, ctx[dj], 0, 0, 0);
            ctx[dj] = __builtin_amdgcn_mfma_f32_16x16x32_bf16(pa1, bv1, ctx[dj], 0, 0, 0);
        }
    }
#pragma unroll
    for (int dj = 0; dj < 4; dj++)
#pragma unroll
        for (int r = 0; r < 4; r++) {
            int q = b * 64 + w * 16 + quad * 4 + r;
            int d = h * HD + dj * 16 + l16;
            O[(size_t)q * HID + d] = (__bf16)(ctx[dj][r] / l_run[r]);
        }
}

// ---------------- LayerNorm(residual) ----------------
__device__ __forceinline__ float blockSum256(float v, float* red)
{
#pragma unroll
    for (int off = 32; off >= 1; off >>= 1) v += __shfl_down(v, off, 64);
    int wave = threadIdx.x >> 6, lane = threadIdx.x & 63;
    if (lane == 0) red[wave] = v;
    __syncthreads();
    float s = red[0] + red[1] + red[2] + red[3];
    __syncthreads();
    return s;
}

__global__ __launch_bounds__(256) void lnres_k(const float* __restrict__ A,
    const float* __restrict__ Bb, const float* __restrict__ g,
    const float* __restrict__ be, float* __restrict__ Y, __bf16* __restrict__ Yb)
{
    __shared__ float red[4];
    int r = blockIdx.x, t = threadIdx.x;
    float v = A[(size_t)r * 256 + t] + Bb[(size_t)r * 256 + t];
    float mean = blockSum256(v, red) * (1.f / 256.f);
    float d = v - mean;
    float var = blockSum256(d * d, red) * (1.f / 256.f);
    float o = d * rsqrtf(var + 1e-5f) * g[t] + be[t];
    Y[(size_t)r * 256 + t] = o;
    if (Yb) Yb[(size_t)r * 256 + t] = (__bf16)o;
}

// ---------------- mean pool ----------------
__global__ void pool_k(const float* __restrict__ Y, float* __restrict__ P)
{
    int b = blockIdx.x, c = threadIdx.x;
    float s = 0.f;
#pragma unroll 8
    for (int q = 0; q < 64; q++) s += Y[(size_t)(b * 64 + q) * 256 + c];
    P[(size_t)b * 256 + c] = s / (64.f + 1e-6f);
}

// ---------------- launch ----------------
extern "C" void kernel_launch(void* const* d_in, const int* in_sizes, int n_in,
                              void* d_out, int out_size, void* d_ws, size_t ws_size,
                              hipStream_t stream)
{
    const float* x     = (const float*)d_in[0];
    const int*   ei    = (const int*)d_in[1];
    const int*   pseq  = (const int*)d_in[3];
    const float* w1  = (const float*)d_in[4];
    const float* as1 = (const float*)d_in[5];
    const float* ad1 = (const float*)d_in[6];
    const float* b1  = (const float*)d_in[7];
    const float* w2  = (const float*)d_in[8];
    const float* as2 = (const float*)d_in[9];
    const float* ad2 = (const float*)d_in[10];
    const float* b2  = (const float*)d_in[11];
    const float* w3  = (const float*)d_in[12];
    const float* as3 = (const float*)d_in[13];
    const float* ad3 = (const float*)d_in[14];
    const float* b3  = (const float*)d_in[15];
    const float* emb    = (const float*)d_in[16];
    const float* conv_w = (const float*)d_in[17];
    const float* conv_b = (const float*)d_in[18];
    const float* wq = (const float*)d_in[19];
    const float* bq = (const float*)d_in[20];
    const float* wk = (const float*)d_in[21];
    const float* bk = (const float*)d_in[22];
    const float* wv = (const float*)d_in[23];
    const float* bv = (const float*)d_in[24];
    const float* wo = (const float*)d_in[25];
    const float* bo = (const float*)d_in[26];
    const float* ln1_g = (const float*)d_in[27];
    const float* ln1_b = (const float*)d_in[28];
    const float* ffw1  = (const float*)d_in[29];
    const float* ffb1  = (const float*)d_in[30];
    const float* ffw2  = (const float*)d_in[31];
    const float* ffb2  = (const float*)d_in[32];
    const float* ln2_g = (const float*)d_in[33];
    const float* ln2_b = (const float*)d_in[34];
    const float* fc1_w = (const float*)d_in[35];
    const float* fc1_b = (const float*)d_in[36];
    const float* fc2_w = (const float*)d_in[37];
    const float* fc2_b = (const float*)d_in[38];
    (void)in_sizes; (void)n_in; (void)out_size;

    char* ws = (char*)d_ws;
    size_t off = 0;
    auto alloc = [&](size_t bytes) -> char* {
        char* p = ws + off;
        off += (bytes + 255) & ~(size_t)255;
        return p;
    };
    // ---- fixed arena ----
    float* hg    = (float*)alloc((size_t)NAT * 512 * 4);   // 32 MB
    float* og    = (float*)alloc((size_t)NAT * 512 * 4);   // 32 MB; attno|ybuf aliases
    float* hb0   = (float*)alloc((size_t)NAT * 256 * 4);   // lig fp32
    float* hb1   = (float*)alloc((size_t)NAT * 256 * 4);   // later ff2o
    __bf16* xb   = (__bf16*)alloc((size_t)NAT * FIN * 2);
    __bf16* hbb  = (__bf16*)alloc((size_t)NAT * 256 * 2);
    __bf16* qbb  = (__bf16*)alloc((size_t)NAT * 256 * 2);
    __bf16* ctxbb= (__bf16*)alloc((size_t)NAT * 256 * 2);
    __bf16* ybb  = (__bf16*)alloc((size_t)NAT * 256 * 2);
    float* a_s   = (float*)alloc((size_t)NAT * 2 * 4);
    float* a_d   = (float*)alloc((size_t)NAT * 2 * 4);
    int* deg     = (int*)alloc((size_t)NAT * 4);
    int* fill    = (int*)alloc((size_t)NAT * 4);
    int* rowptr  = (int*)alloc((size_t)(NAT + 1) * 4);
    int* csrc    = (int*)alloc((size_t)NED * 4);
    float* pooled = (float*)alloc((size_t)256 * 256 * 4);
    float* fc1o   = (float*)alloc((size_t)256 * 256 * 4);
    __bf16* embb = (__bf16*)alloc((size_t)22 * 256 * 2);
    __bf16* wtb  = (__bf16*)alloc((size_t)256 * 768 * 2);
    __bf16* w1T  = (__bf16*)alloc((size_t)512 * 64 * 2);
    __bf16* w2T  = (__bf16*)alloc((size_t)512 * 256 * 2);
    __bf16* w3T  = (__bf16*)alloc((size_t)512 * 256 * 2);
    __bf16* wkT  = (__bf16*)alloc((size_t)256 * 256 * 2);
    __bf16* wvT  = (__bf16*)alloc((size_t)256 * 256 * 2);
    __bf16* wqT  = (__bf16*)alloc((size_t)256 * 256 * 2);
    __bf16* woT  = (__bf16*)alloc((size_t)256 * 256 * 2);
    __bf16* f1T  = (__bf16*)alloc((size_t)1024 * 256 * 2);
    __bf16* f2T  = (__bf16*)alloc((size_t)256 * 1024 * 2);
    // ---- variable region ----
    size_t fixed_end = off;
    size_t rem = (ws_size > fixed_end) ? ws_size - fixed_end : 0;
    const size_t G1 = (size_t)LPN * 256 * 2;
    const size_t ffneed = (size_t)NAT * 1024 * 2 + (size_t)NAT * 256 * 4;
    int CB = 8;
    {
        const int cands[5] = {128, 64, 32, 16, 8};
        for (int ci = 0; ci < 5; ci++) {
            size_t regneed = 3 * (size_t)cands[ci] * G1;
            if (regneed < ffneed) regneed = ffneed;
            if (regneed <= rem) { CB = cands[ci]; break; }
        }
    }
    char* region   = ws + fixed_end;
    __bf16* pconvb = (__bf16*)region;
    __bf16* kbb    = (__bf16*)(region + (size_t)CB * G1);
    __bf16* vtb    = (__bf16*)(region + 2 * (size_t)CB * G1);
    __bf16* ffbb   = (__bf16*)region;
    float*  y2     = (float*)(region + (size_t)NAT * 1024 * 2);
    float* attno = og;
    float* ybuf  = og + (size_t)NAT * 256;
    float* ff2o  = hb1;

    // ---------------- CSR build (once; edge_index constant across layers) -----
    hipMemsetAsync(deg, 0, (size_t)NAT * 4, stream);
    hipMemsetAsync(fill, 0, (size_t)NAT * 4, stream);
    deg_k<<<NED / 256, 256, 0, stream>>>(ei, deg);
    scan_k<<<1, 256, 0, stream>>>(deg, rowptr);
    scat_k<<<NED / 256, 256, 0, stream>>>(ei, fill, rowptr, csrc);

    // ---------------- weight / input conversions ----------------
    cvt_k<<<(NAT * FIN + 255) / 256, 256, 0, stream>>>(x, xb, NAT * FIN);
    cvt_k<<<(22 * 256 + 255) / 256, 256, 0, stream>>>(emb, embb, 22 * 256);
    cvtwt_k<<<768, 256, 0, stream>>>(conv_w, wtb);
    cvtT_k<<<(64 * 512 + 255) / 256, 256, 0, stream>>>(w1, w1T, 64, 512);
    cvtT_k<<<(256 * 512 + 255) / 256, 256, 0, stream>>>(w2, w2T, 256, 512);
    cvtT_k<<<(256 * 512 + 255) / 256, 256, 0, stream>>>(w3, w3T, 256, 512);
    cvtT_k<<<256, 256, 0, stream>>>(wk, wkT, 256, 256);
    cvtT_k<<<256, 256, 0, stream>>>(wv, wvT, 256, 256);
    cvtT_k<<<256, 256, 0, stream>>>(wq, wqT, 256, 256);
    cvtT_k<<<256, 256, 0, stream>>>(wo, woT, 256, 256);
    cvtT_k<<<1024, 256, 0, stream>>>(ffw1, f1T, 256, 1024);
    cvtT_k<<<1024, 256, 0, stream>>>(ffw2, f2T, 1024, 256);

    // ---------------- ligand GNN: 3 GAT layers ----------------
    const __bf16* WT[3] = {w1T, w2T, w3T};
    const float* asl[3] = {as1, as2, as3};
    const float* adl[3] = {ad1, ad2, ad3};
    const float* bl[3]  = {b1, b2, b3};
    float* houts[3] = {hb0, hb1, hb0};
    const __bf16* hinb = xb;
    int Kdim = FIN;
    for (int l = 0; l < 3; l++) {
        gemm_mfma<0, 0, 0><<<dim3(4, NAT / 128), 256, 0, stream>>>(hinb, WT[l], nullptr, hg, NAT, 512, Kdim, 1.f);
        asad_k<<<NAT, 256, 0, stream>>>(hg, asl[l], adl[l], a_s, a_d);
        gat_agg<<<NAT / 4, 256, 0, stream>>>(rowptr, csrc, hg, a_s, a_d, bl[l], houts[l], hbb);
        hinb = hbb;
        Kdim = HID;
    }
    const float* lig = hb0;
    const __bf16* ligb = hbb;

    // ---------------- Q projection (scale 1/8 folded in) ----------------
    gemm_mfma<0, 1, 0><<<dim3(2, NAT / 128), 256, 0, stream>>>(ligb, wqT, bq, qbb, NAT, 256, 256, 0.125f);

    // ---------------- protein branch + attention, chunked over graphs ----------
    for (int b0 = 0; b0 < BGR; b0 += CB) {
        int Mc = CB * LPN;
        conv_mfma<<<dim3(2, Mc / 128), 256, 0, stream>>>(pseq, embb, wtb, conv_b, pconvb, b0);
        gemm_mfma<0, 1, 0><<<dim3(2, Mc / 128), 256, 0, stream>>>(pconvb, wkT, bk, kbb, Mc, 256, 256, 1.f);
        gemm_mfma<0, 1, 1><<<dim3(Mc / 128, 2), 256, 0, stream>>>(wvT, pconvb, bv, vtb, 256, Mc, 256, 1.f);
        attn2_k<<<CB * 4, 256, 0, stream>>>(qbb, kbb, vtb, pseq, ctxbb, b0, Mc);
    }

    // ---------------- attention out proj + LN + FFN + LN ----------------
    gemm_mfma<0, 0, 0><<<dim3(2, NAT / 128), 256, 0, stream>>>(ctxbb, woT, bo, attno, NAT, 256, 256, 1.f);
    lnres_k<<<NAT, 256, 0, stream>>>(lig, attno, ln1_g, ln1_b, ybuf, ybb);
    gemm_mfma<2, 1, 0><<<dim3(8, NAT / 128), 256, 0, stream>>>(ybb, f1T, ffb1, ffbb, NAT, 1024, 256, 1.f);
    gemm_mfma<0, 0, 0><<<dim3(2, NAT / 128), 256, 0, stream>>>(ffbb, f2T, ffb2, ff2o, NAT, 256, 1024, 1.f);
    lnres_k<<<NAT, 256, 0, stream>>>(ybuf, ff2o, ln2_g, ln2_b, y2, nullptr);

    // ---------------- pool + MLP head (fp32, tiny) ----------------
    pool_k<<<BGR, 256, 0, stream>>>(y2, pooled);
    gemm_k<1><<<dim3(4, 4), 256, 0, stream>>>(pooled, fc1_w, fc1_b, fc1o, 256, 256, 256);
    gemm_k<0><<<dim3(1, 4), 256, 0, stream>>>(fc1o, fc2_w, fc2_b, (float*)d_out, 256, 1, 256);
}

// Round 6
// 1143.754 us; speedup vs baseline: 3.9700x; 1.0586x over previous
//
#include <hip/hip_runtime.h>
#include <hip/hip_bf16.h>
#include <cstdint>
#include <cstddef>

#define NAT 16384
#define NED 65536
#define BGR 256
#define FIN 64
#define HID 256
#define LPN 1024
#define HD 64

typedef __bf16 bf16x8 __attribute__((ext_vector_type(8)));
typedef float floatx4 __attribute__((ext_vector_type(4)));

// async global->LDS 16B; dest = wave-uniform base + lane*16 (linear layout!)
__device__ __forceinline__ void gl2lds16(const void* g, void* l)
{
    __builtin_amdgcn_global_load_lds(
        (const __attribute__((address_space(1))) unsigned int*)g,
        (__attribute__((address_space(3))) unsigned int*)l, 16, 0, 0);
}

// ---------------- fp32 GEMM (tiny head matmuls only) ----------------
template<int ACT>
__global__ __launch_bounds__(256) void gemm_k(const float* __restrict__ A,
    const float* __restrict__ Bm, const float* __restrict__ bias,
    float* __restrict__ C, int M, int Nn, int K)
{
    __shared__ float As[16][68];
    __shared__ float Bs[16][68];
    const int t  = threadIdx.x;
    const int m0 = blockIdx.y * 64, n0 = blockIdx.x * 64;
    const int tm = (t & 15) * 4, tn = (t >> 4) * 4;
    const int lm = t >> 2,  lkc = (t & 3) * 4;
    const int lkk = t >> 4, lnc = (t & 15) * 4;
    float acc[4][4] = {};
    for (int k0 = 0; k0 < K; k0 += 16) {
        float4 av = *(const float4*)(A + (size_t)(m0 + lm) * K + k0 + lkc);
        As[lkc + 0][lm] = av.x; As[lkc + 1][lm] = av.y;
        As[lkc + 2][lm] = av.z; As[lkc + 3][lm] = av.w;
        if (n0 + lnc + 3 < Nn) {
            float4 bv = *(const float4*)(Bm + (size_t)(k0 + lkk) * Nn + n0 + lnc);
            Bs[lkk][lnc + 0] = bv.x; Bs[lkk][lnc + 1] = bv.y;
            Bs[lkk][lnc + 2] = bv.z; Bs[lkk][lnc + 3] = bv.w;
        } else {
            for (int j = 0; j < 4; j++) {
                int n = n0 + lnc + j;
                Bs[lkk][lnc + j] = (n < Nn) ? Bm[(size_t)(k0 + lkk) * Nn + n] : 0.f;
            }
        }
        __syncthreads();
#pragma unroll
        for (int kk = 0; kk < 16; kk++) {
            float4 af = *(const float4*)&As[kk][tm];
            float4 bf = *(const float4*)&Bs[kk][tn];
            float a_[4] = {af.x, af.y, af.z, af.w};
            float b_[4] = {bf.x, bf.y, bf.z, bf.w};
#pragma unroll
            for (int i = 0; i < 4; i++)
#pragma unroll
                for (int j = 0; j < 4; j++) acc[i][j] += a_[i] * b_[j];
        }
        __syncthreads();
    }
#pragma unroll
    for (int i = 0; i < 4; i++) {
#pragma unroll
        for (int j = 0; j < 4; j++) {
            int n = n0 + tn + j;
            if (n < Nn) {
                float v = acc[i][j] + (bias ? bias[n] : 0.f);
                if (ACT == 1) v = fmaxf(v, 0.f);
                C[(size_t)(m0 + tm + i) * Nn + n] = v;
            }
        }
    }
}

// ---------------- bf16 MFMA GEMM, global_load_lds staging + XOR swizzle -------
// A[M,K] bf16 rm, Bt[N,K] bf16 rm. M%128==0, N%128==0, K%32==0.
// LDS [128][32] unpadded; 16B segment s of row r holds global seg (s^(r&3)).
template<int ACT, int OUTBF16, int BIASROW>
__global__ __launch_bounds__(256) void gemm_mfma(const __bf16* __restrict__ A,
    const __bf16* __restrict__ Bt, const float* __restrict__ bias,
    void* __restrict__ Cout, int M, int Nn, int K, float escale)
{
    __shared__ __bf16 As[128][32];
    __shared__ __bf16 Bs[128][32];
    const int t = threadIdx.x;
    const int m0 = blockIdx.y * 128, n0 = blockIdx.x * 128;
    const int wave = t >> 6, lane = t & 63;
    const int wm = (wave >> 1) * 64, wn = (wave & 1) * 64;
    const int quad = lane >> 4, l16 = lane & 15;
    const int r0 = t >> 2, s0 = t & 3, g0 = (s0 ^ (r0 & 3)) * 8;
    const int r1 = r0 + 64,            g1 = (s0 ^ (r1 & 3)) * 8;
    const int fso = (quad ^ (l16 & 3)) * 8;      // fragment seg (physical)
    floatx4 acc[4][4] = {};
    for (int k0 = 0; k0 < K; k0 += 32) {
        gl2lds16(A + (size_t)(m0 + r0) * K + k0 + g0, &As[r0][s0 * 8]);
        gl2lds16(A + (size_t)(m0 + r1) * K + k0 + g1, &As[r1][s0 * 8]);
        gl2lds16(Bt + (size_t)(n0 + r0) * K + k0 + g0, &Bs[r0][s0 * 8]);
        gl2lds16(Bt + (size_t)(n0 + r1) * K + k0 + g1, &Bs[r1][s0 * 8]);
        __syncthreads();
        bf16x8 af[4], bfr[4];
#pragma unroll
        for (int mi = 0; mi < 4; mi++) af[mi]  = *(const bf16x8*)&As[wm + mi * 16 + l16][fso];
#pragma unroll
        for (int nj = 0; nj < 4; nj++) bfr[nj] = *(const bf16x8*)&Bs[wn + nj * 16 + l16][fso];
#pragma unroll
        for (int mi = 0; mi < 4; mi++)
#pragma unroll
            for (int nj = 0; nj < 4; nj++)
                acc[mi][nj] = __builtin_amdgcn_mfma_f32_16x16x32_bf16(af[mi], bfr[nj], acc[mi][nj], 0, 0, 0);
        __syncthreads();
    }
#pragma unroll
    for (int mi = 0; mi < 4; mi++)
#pragma unroll
        for (int nj = 0; nj < 4; nj++) {
            int col = n0 + wn + nj * 16 + l16;
#pragma unroll
            for (int r = 0; r < 4; r++) {
                int row = m0 + wm + mi * 16 + quad * 4 + r;
                float bval = bias ? (BIASROW ? bias[row] : bias[col]) : 0.f;
                float v = (acc[mi][nj][r] + bval) * escale;
                if (ACT == 1) v = fmaxf(v, 0.f);
                if (ACT == 2) v = 0.5f * v * (1.f + erff(v * 0.70710678118654752f));
                if (OUTBF16) ((__bf16*)Cout)[(size_t)row * Nn + col] = (__bf16)v;
                else         ((float*)Cout)[(size_t)row * Nn + col] = v;
            }
        }
}

// ---------------- GAT feature GEMM: hg bf16 + fused a_s/a_d epilogue ----------
// Nn = 512 fixed; head g = n0>>8 is block-uniform. a_s/a_d pre-zeroed.
__global__ __launch_bounds__(256) void gemm_gat(const __bf16* __restrict__ A,
    const __bf16* __restrict__ Bt, const float* __restrict__ as_f,
    const float* __restrict__ ad_f, __bf16* __restrict__ Hg,
    float* __restrict__ a_s, float* __restrict__ a_d, int K)
{
    __shared__ __bf16 As[128][32];
    __shared__ __bf16 Bs[128][32];
    const int t = threadIdx.x;
    const int m0 = blockIdx.y * 128, n0 = blockIdx.x * 128;
    const int wave = t >> 6, lane = t & 63;
    const int wm = (wave >> 1) * 64, wn = (wave & 1) * 64;
    const int quad = lane >> 4, l16 = lane & 15;
    const int r0 = t >> 2, s0 = t & 3, g0 = (s0 ^ (r0 & 3)) * 8;
    const int r1 = r0 + 64,            g1 = (s0 ^ (r1 & 3)) * 8;
    const int fso = (quad ^ (l16 & 3)) * 8;
    floatx4 acc[4][4] = {};
    for (int k0 = 0; k0 < K; k0 += 32) {
        gl2lds16(A + (size_t)(m0 + r0) * K + k0 + g0, &As[r0][s0 * 8]);
        gl2lds16(A + (size_t)(m0 + r1) * K + k0 + g1, &As[r1][s0 * 8]);
        gl2lds16(Bt + (size_t)(n0 + r0) * K + k0 + g0, &Bs[r0][s0 * 8]);
        gl2lds16(Bt + (size_t)(n0 + r1) * K + k0 + g1, &Bs[r1][s0 * 8]);
        __syncthreads();
        bf16x8 af[4], bfr[4];
#pragma unroll
        for (int mi = 0; mi < 4; mi++) af[mi]  = *(const bf16x8*)&As[wm + mi * 16 + l16][fso];
#pragma unroll
        for (int nj = 0; nj < 4; nj++) bfr[nj] = *(const bf16x8*)&Bs[wn + nj * 16 + l16][fso];
#pragma unroll
        for (int mi = 0; mi < 4; mi++)
#pragma unroll
            for (int nj = 0; nj < 4; nj++)
                acc[mi][nj] = __builtin_amdgcn_mfma_f32_16x16x32_bf16(af[mi], bfr[nj], acc[mi][nj], 0, 0, 0);
        __syncthreads();
    }
    const int g = n0 >> 8;                 // head for this col block
#pragma unroll
    for (int mi = 0; mi < 4; mi++) {
#pragma unroll
        for (int r = 0; r < 4; r++) {
            float ps = 0.f, pd = 0.f;
#pragma unroll
            for (int nj = 0; nj < 4; nj++) {
                int col = n0 + wn + nj * 16 + l16;
                float v = acc[mi][nj][r];
                ps += v * as_f[col];
                pd += v * ad_f[col];
            }
#pragma unroll
            for (int off = 1; off < 16; off <<= 1) {
                ps += __shfl_xor(ps, off, 64);
                pd += __shfl_xor(pd, off, 64);
            }
            if (l16 == 0) {
                int row = m0 + wm + mi * 16 + quad * 4 + r;
                atomicAdd(&a_s[row * 2 + g], ps);
                atomicAdd(&a_d[row * 2 + g], pd);
            }
        }
    }
#pragma unroll
    for (int mi = 0; mi < 4; mi++)
#pragma unroll
        for (int nj = 0; nj < 4; nj++) {
            int col = n0 + wn + nj * 16 + l16;
#pragma unroll
            for (int r = 0; r < 4; r++) {
                int row = m0 + wm + mi * 16 + quad * 4 + r;
                Hg[(size_t)row * 512 + col] = (__bf16)acc[mi][nj][r];
            }
        }
}

// ---------------- conv1d implicit GEMM, fused embed gather, async staging -----
__global__ __launch_bounds__(256) void conv_mfma(const int* __restrict__ seq,
    const __bf16* __restrict__ embb, const __bf16* __restrict__ wtb,
    const float* __restrict__ bias, __bf16* __restrict__ C, int b_base,
    const __bf16* __restrict__ zrow)
{
    __shared__ __bf16 As[128][32];
    __shared__ __bf16 Bs[128][32];
    __shared__ int toks[130];
    const int t = threadIdx.x;
    const int m0 = blockIdx.y * 128, n0 = blockIdx.x * 128;
    const int b = b_base + (m0 >> 10), l0 = m0 & 1023;
    if (t < 130) {
        int l = l0 + t - 1;
        toks[t] = (l >= 0 && l < LPN) ? seq[b * LPN + l] : -1;
    }
    const int wave = t >> 6, lane = t & 63;
    const int wm = (wave >> 1) * 64, wn = (wave & 1) * 64;
    const int quad = lane >> 4, l16 = lane & 15;
    const int r0 = t >> 2, s0 = t & 3, g0 = (s0 ^ (r0 & 3)) * 8;
    const int r1 = r0 + 64,            g1 = (s0 ^ (r1 & 3)) * 8;
    const int fso = (quad ^ (l16 & 3)) * 8;
    floatx4 acc[4][4] = {};
    __syncthreads();
    for (int k0 = 0; k0 < 768; k0 += 32) {
        int dl = k0 >> 8, c0 = k0 & 255;
        int tok0 = toks[r0 + dl], tok1 = toks[r1 + dl];
        const __bf16* ga0 = (tok0 >= 0) ? embb + (size_t)tok0 * HID + c0 + g0 : zrow + g0;
        const __bf16* ga1 = (tok1 >= 0) ? embb + (size_t)tok1 * HID + c0 + g1 : zrow + g1;
        gl2lds16(ga0, &As[r0][s0 * 8]);
        gl2lds16(ga1, &As[r1][s0 * 8]);
        gl2lds16(wtb + (size_t)(n0 + r0) * 768 + k0 + g0, &Bs[r0][s0 * 8]);
        gl2lds16(wtb + (size_t)(n0 + r1) * 768 + k0 + g1, &Bs[r1][s0 * 8]);
        __syncthreads();
        bf16x8 af[4], bfr[4];
#pragma unroll
        for (int mi = 0; mi < 4; mi++) af[mi]  = *(const bf16x8*)&As[wm + mi * 16 + l16][fso];
#pragma unroll
        for (int nj = 0; nj < 4; nj++) bfr[nj] = *(const bf16x8*)&Bs[wn + nj * 16 + l16][fso];
#pragma unroll
        for (int mi = 0; mi < 4; mi++)
#pragma unroll
            for (int nj = 0; nj < 4; nj++)
                acc[mi][nj] = __builtin_amdgcn_mfma_f32_16x16x32_bf16(af[mi], bfr[nj], acc[mi][nj], 0, 0, 0);
        __syncthreads();
    }
#pragma unroll
    for (int mi = 0; mi < 4; mi++)
#pragma unroll
        for (int nj = 0; nj < 4; nj++) {
            int col = n0 + wn + nj * 16 + l16;
            float bval = bias[col];
#pragma unroll
            for (int r = 0; r < 4; r++) {
                int row = m0 + wm + mi * 16 + quad * 4 + r;
                float v = fmaxf(acc[mi][nj][r] + bval, 0.f);
                C[(size_t)row * 256 + col] = (__bf16)v;
            }
        }
}

// ---------------- conversion kernels ----------------
__global__ void cvt_k(const float* __restrict__ in, __bf16* __restrict__ out, int n)
{
    int i = blockIdx.x * 256 + threadIdx.x;
    if (i < n) out[i] = (__bf16)in[i];
}

__global__ void cvtT_k(const float* __restrict__ in, __bf16* __restrict__ out, int K, int N)
{
    int i = blockIdx.x * 256 + threadIdx.x;
    if (i >= K * N) return;
    int n = i / K, k = i - n * K;
    out[i] = (__bf16)in[(size_t)k * N + n];
}

__global__ void cvtwt_k(const float* __restrict__ cw, __bf16* __restrict__ wtb)
{
    int i = blockIdx.x * 256 + threadIdx.x;     // < 196608
    int n = i / 768, r = i - n * 768;
    int dl = r >> 8, kk = r & 255;
    wtb[i] = (__bf16)cw[(size_t)n * 768 + kk * 3 + dl];
}

// ---------------- CSR build ----------------
__global__ void deg_k(const int* __restrict__ ei, int* __restrict__ deg)
{
    int e = blockIdx.x * 256 + threadIdx.x;
    if (e < NED) atomicAdd(&deg[ei[NED + e]], 1);
}

__global__ __launch_bounds__(256) void scan_k(const int* __restrict__ deg, int* __restrict__ rowptr)
{
    __shared__ int part[256];
    int t = threadIdx.x;
    int base = t * 64;
    int s = 0;
#pragma unroll
    for (int i = 0; i < 64; i++) s += deg[base + i];
    part[t] = s;
    __syncthreads();
    for (int off = 1; off < 256; off <<= 1) {
        int v = (t >= off) ? part[t - off] : 0;
        __syncthreads();
        part[t] += v;
        __syncthreads();
    }
    int run = t ? part[t - 1] : 0;
    for (int i = 0; i < 64; i++) { rowptr[base + i] = run; run += deg[base + i]; }
    if (t == 255) rowptr[16384] = run;
}

__global__ void scat_k(const int* __restrict__ ei, int* __restrict__ fill,
                       const int* __restrict__ rowptr, int* __restrict__ csrc)
{
    int e = blockIdx.x * 256 + threadIdx.x;
    if (e >= NED) return;
    int d = ei[NED + e];
    int pos = rowptr[d] + atomicAdd(&fill[d], 1);
    csrc[pos] = ei[e];
}

// ---------------- fused GAT aggregation (bf16 features) ----------------
__global__ __launch_bounds__(256) void gat_agg(const int* __restrict__ rowptr,
    const int* __restrict__ csrc, const __bf16* __restrict__ hgb,
    const float* __restrict__ a_s, const float* __restrict__ a_d,
    const float* __restrict__ bias, float* __restrict__ out, __bf16* __restrict__ outb)
{
    const int wave = threadIdx.x >> 6, lane = threadIdx.x & 63;
    const int d = blockIdx.x * 4 + wave;
    const int beg = rowptr[d], end = rowptr[d + 1];
    const float ad0 = a_d[d * 2 + 0], ad1 = a_d[d * 2 + 1];
    float e0 = a_s[d * 2 + 0] + ad0; e0 = (e0 > 0.f) ? e0 : 0.2f * e0;
    float e1 = a_s[d * 2 + 1] + ad1; e1 = (e1 > 0.f) ? e1 : 0.2f * e1;
    float m0 = e0, m1 = e1;
    for (int p = beg; p < end; p++) {
        int s = csrc[p];
        float v0 = a_s[s * 2 + 0] + ad0; v0 = (v0 > 0.f) ? v0 : 0.2f * v0;
        float v1 = a_s[s * 2 + 1] + ad1; v1 = (v1 > 0.f) ? v1 : 0.2f * v1;
        m0 = fmaxf(m0, v0); m1 = fmaxf(m1, v1);
    }
    float den0 = __expf(e0 - m0), den1 = __expf(e1 - m1);
    for (int p = beg; p < end; p++) {
        int s = csrc[p];
        float v0 = a_s[s * 2 + 0] + ad0; v0 = (v0 > 0.f) ? v0 : 0.2f * v0;
        float v1 = a_s[s * 2 + 1] + ad1; v1 = (v1 > 0.f) ? v1 : 0.2f * v1;
        den0 += __expf(v0 - m0); den1 += __expf(v1 - m1);
    }
    const float inv0 = 1.f / den0, inv1 = 1.f / den1;
    const int ch = lane * 8;
    const int g = ch >> 8;
    const float mg = g ? m1 : m0, invg = g ? inv1 : inv0, adg = g ? ad1 : ad0;
    float acc[8] = {};
    {
        float al = __expf((g ? e1 : e0) - mg) * invg;
        bf16x8 hv = *(const bf16x8*)(hgb + (size_t)d * 512 + ch);
#pragma unroll
        for (int j = 0; j < 8; j++) acc[j] += (float)hv[j] * al;
    }
    for (int p = beg; p < end; p++) {
        int s = csrc[p];
        float v = a_s[s * 2 + g] + adg; v = (v > 0.f) ? v : 0.2f * v;
        float al = __expf(v - mg) * invg;
        bf16x8 hv = *(const bf16x8*)(hgb + (size_t)s * 512 + ch);
#pragma unroll
        for (int j = 0; j < 8; j++) acc[j] += (float)hv[j] * al;
    }
    float other[8];
#pragma unroll
    for (int j = 0; j < 8; j++) other[j] = __shfl_xor(acc[j], 32, 64);
    if (lane < 32) {
#pragma unroll
        for (int j = 0; j < 8; j++) {
            float v = 0.5f * (acc[j] + other[j]) + bias[ch + j];
            v = (v > 0.f) ? v : expm1f(v);
            if (out) out[(size_t)d * 256 + ch + j] = v;
            outb[(size_t)d * 256 + ch + j] = (__bf16)v;
        }
    }
}

// ---------------- MFMA flash cross-attention ----------------
__global__ __launch_bounds__(256) void attn2_k(const __bf16* __restrict__ Qb,
    const __bf16* __restrict__ Kb, const __bf16* __restrict__ Vtb,
    const int* __restrict__ seq, __bf16* __restrict__ O, int b0, int ldV)
{
    __shared__ __bf16 Ps[4][16][72];
    __shared__ float mask_s[LPN];
    const int t = threadIdx.x;
    const int bl = blockIdx.x >> 2, h = blockIdx.x & 3;
    const int b = b0 + bl;
    const int w = t >> 6, lane = t & 63;
    const int quad = lane >> 4, l16 = lane & 15;
    for (int i = t; i < LPN; i += 256)
        mask_s[i] = (seq[b * LPN + i] == 0) ? -1e9f : 0.f;
    const __bf16* qrow = Qb + (size_t)(b * 64 + w * 16 + l16) * HID + h * HD;
    bf16x8 aq0 = *(const bf16x8*)(qrow + quad * 8);
    bf16x8 aq1 = *(const bf16x8*)(qrow + 32 + quad * 8);
    float m_run[4] = {-3e38f, -3e38f, -3e38f, -3e38f};
    float l_run[4] = {0.f, 0.f, 0.f, 0.f};
    floatx4 ctx[4] = {};
    __syncthreads();
    for (int kp0 = 0; kp0 < LPN; kp0 += 64) {
        floatx4 s[4];
#pragma unroll
        for (int nj = 0; nj < 4; nj++) {
            const __bf16* krow = Kb + (size_t)(bl * LPN + kp0 + nj * 16 + l16) * HID + h * HD;
            bf16x8 bk0 = *(const bf16x8*)(krow + quad * 8);
            bf16x8 bk1 = *(const bf16x8*)(krow + 32 + quad * 8);
            floatx4 z = {0.f, 0.f, 0.f, 0.f};
            s[nj] = __builtin_amdgcn_mfma_f32_16x16x32_bf16(aq0, bk0, z, 0, 0, 0);
            s[nj] = __builtin_amdgcn_mfma_f32_16x16x32_bf16(aq1, bk1, s[nj], 0, 0, 0);
        }
#pragma unroll
        for (int nj = 0; nj < 4; nj++) {
            float mval = mask_s[kp0 + nj * 16 + l16];
#pragma unroll
            for (int r = 0; r < 4; r++) s[nj][r] += mval;
        }
        float alpha[4];
#pragma unroll
        for (int r = 0; r < 4; r++) {
            float mx = fmaxf(fmaxf(s[0][r], s[1][r]), fmaxf(s[2][r], s[3][r]));
#pragma unroll
            for (int off = 1; off < 16; off <<= 1) mx = fmaxf(mx, __shfl_xor(mx, off, 64));
            float mn = fmaxf(m_run[r], mx);
            alpha[r] = __expf(m_run[r] - mn);
            m_run[r] = mn;
            float rs = 0.f;
#pragma unroll
            for (int nj = 0; nj < 4; nj++) {
                float p = __expf(s[nj][r] - mn);
                s[nj][r] = p;
                rs += p;
            }
#pragma unroll
            for (int off = 1; off < 16; off <<= 1) rs += __shfl_xor(rs, off, 64);
            l_run[r] = l_run[r] * alpha[r] + rs;
        }
#pragma unroll
        for (int nj = 0; nj < 4; nj++)
#pragma unroll
            for (int r = 0; r < 4; r++)
                Ps[w][quad * 4 + r][nj * 16 + l16] = (__bf16)s[nj][r];
        bf16x8 pa0 = *(const bf16x8*)&Ps[w][l16][quad * 8];
        bf16x8 pa1 = *(const bf16x8*)&Ps[w][l16][32 + quad * 8];
#pragma unroll
        for (int dj = 0; dj < 4; dj++) {
#pragma unroll
            for (int r = 0; r < 4; r++) ctx[dj][r] *= alpha[r];
            const __bf16* vrow = Vtb + (size_t)(h * HD + dj * 16 + l16) * ldV + bl * LPN + kp0;
            bf16x8 bv0 = *(const bf16x8*)(vrow + quad * 8);
            bf16x8 bv1 = *(const bf16x8*)(vrow + 32 + quad * 8);
            ctx[dj] = __builtin_amdgcn_mfma_f32_16x16x32_bf16(pa0, bv0, ctx[dj], 0, 0, 0);
            ctx[dj] = __builtin_amdgcn_mfma_f32_16x16x32_bf16(pa1, bv1, ctx[dj], 0, 0, 0);
        }
    }
#pragma unroll
    for (int dj = 0; dj < 4; dj++)
#pragma unroll
        for (int r = 0; r < 4; r++) {
            int q = b * 64 + w * 16 + quad * 4 + r;
            int d = h * HD + dj * 16 + l16;
            O[(size_t)q * HID + d] = (__bf16)(ctx[dj][r] / l_run[r]);
        }
}

// ---------------- LayerNorm(residual) ----------------
__device__ __forceinline__ float blockSum256(float v, float* red)
{
#pragma unroll
    for (int off = 32; off >= 1; off >>= 1) v += __shfl_down(v, off, 64);
    int wave = threadIdx.x >> 6, lane = threadIdx.x & 63;
    if (lane == 0) red[wave] = v;
    __syncthreads();
    float s = red[0] + red[1] + red[2] + red[3];
    __syncthreads();
    return s;
}

__global__ __launch_bounds__(256) void lnres_k(const float* __restrict__ A,
    const float* __restrict__ Bb, const float* __restrict__ g,
    const float* __restrict__ be, float* __restrict__ Y, __bf16* __restrict__ Yb)
{
    __shared__ float red[4];
    int r = blockIdx.x, t = threadIdx.x;
    float v = A[(size_t)r * 256 + t] + Bb[(size_t)r * 256 + t];
    float mean = blockSum256(v, red) * (1.f / 256.f);
    float d = v - mean;
    float var = blockSum256(d * d, red) * (1.f / 256.f);
    float o = d * rsqrtf(var + 1e-5f) * g[t] + be[t];
    Y[(size_t)r * 256 + t] = o;
    if (Yb) Yb[(size_t)r * 256 + t] = (__bf16)o;
}

// ---------------- mean pool ----------------
__global__ void pool_k(const float* __restrict__ Y, float* __restrict__ P)
{
    int b = blockIdx.x, c = threadIdx.x;
    float s = 0.f;
#pragma unroll 8
    for (int q = 0; q < 64; q++) s += Y[(size_t)(b * 64 + q) * 256 + c];
    P[(size_t)b * 256 + c] = s / (64.f + 1e-6f);
}

// ---------------- launch ----------------
extern "C" void kernel_launch(void* const* d_in, const int* in_sizes, int n_in,
                              void* d_out, int out_size, void* d_ws, size_t ws_size,
                              hipStream_t stream)
{
    const float* x     = (const float*)d_in[0];
    const int*   ei    = (const int*)d_in[1];
    const int*   pseq  = (const int*)d_in[3];
    const float* w1  = (const float*)d_in[4];
    const float* as1 = (const float*)d_in[5];
    const float* ad1 = (const float*)d_in[6];
    const float* b1  = (const float*)d_in[7];
    const float* w2  = (const float*)d_in[8];
    const float* as2 = (const float*)d_in[9];
    const float* ad2 = (const float*)d_in[10];
    const float* b2  = (const float*)d_in[11];
    const float* w3  = (const float*)d_in[12];
    const float* as3 = (const float*)d_in[13];
    const float* ad3 = (const float*)d_in[14];
    const float* b3  = (const float*)d_in[15];
    const float* emb    = (const float*)d_in[16];
    const float* conv_w = (const float*)d_in[17];
    const float* conv_b = (const float*)d_in[18];
    const float* wq = (const float*)d_in[19];
    const float* bq = (const float*)d_in[20];
    const float* wk = (const float*)d_in[21];
    const float* bk = (const float*)d_in[22];
    const float* wv = (const float*)d_in[23];
    const float* bv = (const float*)d_in[24];
    const float* wo = (const float*)d_in[25];
    const float* bo = (const float*)d_in[26];
    const float* ln1_g = (const float*)d_in[27];
    const float* ln1_b = (const float*)d_in[28];
    const float* ffw1  = (const float*)d_in[29];
    const float* ffb1  = (const float*)d_in[30];
    const float* ffw2  = (const float*)d_in[31];
    const float* ffb2  = (const float*)d_in[32];
    const float* ln2_g = (const float*)d_in[33];
    const float* ln2_b = (const float*)d_in[34];
    const float* fc1_w = (const float*)d_in[35];
    const float* fc1_b = (const float*)d_in[36];
    const float* fc2_w = (const float*)d_in[37];
    const float* fc2_b = (const float*)d_in[38];
    (void)in_sizes; (void)n_in; (void)out_size;

    char* ws = (char*)d_ws;
    size_t off = 0;
    auto alloc = [&](size_t bytes) -> char* {
        char* p = ws + off;
        off += (bytes + 255) & ~(size_t)255;
        return p;
    };
    // ---- fixed arena ----
    __bf16* hgb  = (__bf16*)alloc((size_t)NAT * 512 * 2);  // 16 MB GAT features
    float* og    = (float*)alloc((size_t)NAT * 512 * 4);   // attno|ybuf aliases
    float* hb0   = (float*)alloc((size_t)NAT * 256 * 4);   // lig fp32 (layer 3)
    float* hb1   = (float*)alloc((size_t)NAT * 256 * 4);   // ff2o
    __bf16* xb   = (__bf16*)alloc((size_t)NAT * FIN * 2);
    __bf16* hbb  = (__bf16*)alloc((size_t)NAT * 256 * 2);
    __bf16* qbb  = (__bf16*)alloc((size_t)NAT * 256 * 2);
    __bf16* ctxbb= (__bf16*)alloc((size_t)NAT * 256 * 2);
    __bf16* ybb  = (__bf16*)alloc((size_t)NAT * 256 * 2);
    float* a_s   = (float*)alloc((size_t)NAT * 2 * 4);
    float* a_d   = (float*)alloc((size_t)NAT * 2 * 4);
    int* deg     = (int*)alloc((size_t)NAT * 4);
    int* fill    = (int*)alloc((size_t)NAT * 4);
    int* rowptr  = (int*)alloc((size_t)(NAT + 1) * 4);
    int* csrc    = (int*)alloc((size_t)NED * 4);
    float* pooled = (float*)alloc((size_t)256 * 256 * 4);
    float* fc1o   = (float*)alloc((size_t)256 * 256 * 4);
    __bf16* embb = (__bf16*)alloc((size_t)22 * 256 * 2);
    __bf16* wtb  = (__bf16*)alloc((size_t)256 * 768 * 2);
    __bf16* zpad = (__bf16*)alloc(256);
    __bf16* w1T  = (__bf16*)alloc((size_t)512 * 64 * 2);
    __bf16* w2T  = (__bf16*)alloc((size_t)512 * 256 * 2);
    __bf16* w3T  = (__bf16*)alloc((size_t)512 * 256 * 2);
    __bf16* wkT  = (__bf16*)alloc((size_t)256 * 256 * 2);
    __bf16* wvT  = (__bf16*)alloc((size_t)256 * 256 * 2);
    __bf16* wqT  = (__bf16*)alloc((size_t)256 * 256 * 2);
    __bf16* woT  = (__bf16*)alloc((size_t)256 * 256 * 2);
    __bf16* f1T  = (__bf16*)alloc((size_t)1024 * 256 * 2);
    __bf16* f2T  = (__bf16*)alloc((size_t)256 * 1024 * 2);
    // ---- variable region ----
    size_t fixed_end = off;
    size_t rem = (ws_size > fixed_end) ? ws_size - fixed_end : 0;
    const size_t G1 = (size_t)LPN * 256 * 2;
    const size_t ffneed = (size_t)NAT * 1024 * 2 + (size_t)NAT * 256 * 4;
    int CB = 8;
    {
        const int cands[5] = {128, 64, 32, 16, 8};
        for (int ci = 0; ci < 5; ci++) {
            size_t regneed = 3 * (size_t)cands[ci] * G1;
            if (regneed < ffneed) regneed = ffneed;
            if (regneed <= rem) { CB = cands[ci]; break; }
        }
    }
    char* region   = ws + fixed_end;
    __bf16* pconvb = (__bf16*)region;
    __bf16* kbb    = (__bf16*)(region + (size_t)CB * G1);
    __bf16* vtb    = (__bf16*)(region + 2 * (size_t)CB * G1);
    __bf16* ffbb   = (__bf16*)region;
    float*  y2     = (float*)(region + (size_t)NAT * 1024 * 2);
    float* attno = og;
    float* ybuf  = og + (size_t)NAT * 256;
    float* ff2o  = hb1;

    // ---------------- CSR build + zero page ----------------
    hipMemsetAsync(deg, 0, (size_t)NAT * 4, stream);
    hipMemsetAsync(fill, 0, (size_t)NAT * 4, stream);
    hipMemsetAsync(zpad, 0, 256, stream);
    deg_k<<<NED / 256, 256, 0, stream>>>(ei, deg);
    scan_k<<<1, 256, 0, stream>>>(deg, rowptr);
    scat_k<<<NED / 256, 256, 0, stream>>>(ei, fill, rowptr, csrc);

    // ---------------- weight / input conversions ----------------
    cvt_k<<<(NAT * FIN + 255) / 256, 256, 0, stream>>>(x, xb, NAT * FIN);
    cvt_k<<<(22 * 256 + 255) / 256, 256, 0, stream>>>(emb, embb, 22 * 256);
    cvtwt_k<<<768, 256, 0, stream>>>(conv_w, wtb);
    cvtT_k<<<(64 * 512 + 255) / 256, 256, 0, stream>>>(w1, w1T, 64, 512);
    cvtT_k<<<(256 * 512 + 255) / 256, 256, 0, stream>>>(w2, w2T, 256, 512);
    cvtT_k<<<(256 * 512 + 255) / 256, 256, 0, stream>>>(w3, w3T, 256, 512);
    cvtT_k<<<256, 256, 0, stream>>>(wk, wkT, 256, 256);
    cvtT_k<<<256, 256, 0, stream>>>(wv, wvT, 256, 256);
    cvtT_k<<<256, 256, 0, stream>>>(wq, wqT, 256, 256);
    cvtT_k<<<256, 256, 0, stream>>>(wo, woT, 256, 256);
    cvtT_k<<<1024, 256, 0, stream>>>(ffw1, f1T, 256, 1024);
    cvtT_k<<<1024, 256, 0, stream>>>(ffw2, f2T, 1024, 256);

    // ---------------- ligand GNN: 3 GAT layers ----------------
    const __bf16* WT[3] = {w1T, w2T, w3T};
    const float* asl[3] = {as1, as2, as3};
    const float* adl[3] = {ad1, ad2, ad3};
    const float* bl[3]  = {b1, b2, b3};
    float* houts[3] = {nullptr, nullptr, hb0};
    const __bf16* hinb = xb;
    int Kdim = FIN;
    for (int l = 0; l < 3; l++) {
        hipMemsetAsync(a_s, 0, (size_t)NAT * 2 * 4, stream);
        hipMemsetAsync(a_d, 0, (size_t)NAT * 2 * 4, stream);
        gemm_gat<<<dim3(4, NAT / 128), 256, 0, stream>>>(hinb, WT[l], asl[l], adl[l], hgb, a_s, a_d, Kdim);
        gat_agg<<<NAT / 4, 256, 0, stream>>>(rowptr, csrc, hgb, a_s, a_d, bl[l], houts[l], hbb);
        hinb = hbb;
        Kdim = HID;
    }
    const float* lig = hb0;
    const __bf16* ligb = hbb;

    // ---------------- Q projection (scale 1/8 folded in) ----------------
    gemm_mfma<0, 1, 0><<<dim3(2, NAT / 128), 256, 0, stream>>>(ligb, wqT, bq, qbb, NAT, 256, 256, 0.125f);

    // ---------------- protein branch + attention, chunked over graphs ----------
    for (int b0 = 0; b0 < BGR; b0 += CB) {
        int Mc = CB * LPN;
        conv_mfma<<<dim3(2, Mc / 128), 256, 0, stream>>>(pseq, embb, wtb, conv_b, pconvb, b0, zpad);
        gemm_mfma<0, 1, 0><<<dim3(2, Mc / 128), 256, 0, stream>>>(pconvb, wkT, bk, kbb, Mc, 256, 256, 1.f);
        gemm_mfma<0, 1, 1><<<dim3(Mc / 128, 2), 256, 0, stream>>>(wvT, pconvb, bv, vtb, 256, Mc, 256, 1.f);
        attn2_k<<<CB * 4, 256, 0, stream>>>(qbb, kbb, vtb, pseq, ctxbb, b0, Mc);
    }

    // ---------------- attention out proj + LN + FFN + LN ----------------
    gemm_mfma<0, 0, 0><<<dim3(2, NAT / 128), 256, 0, stream>>>(ctxbb, woT, bo, attno, NAT, 256, 256, 1.f);
    lnres_k<<<NAT, 256, 0, stream>>>(lig, attno, ln1_g, ln1_b, ybuf, ybb);
    gemm_mfma<2, 1, 0><<<dim3(8, NAT / 128), 256, 0, stream>>>(ybb, f1T, ffb1, ffbb, NAT, 1024, 256, 1.f);
    gemm_mfma<0, 0, 0><<<dim3(2, NAT / 128), 256, 0, stream>>>(ffbb, f2T, ffb2, ff2o, NAT, 256, 1024, 1.f);
    lnres_k<<<NAT, 256, 0, stream>>>(ybuf, ff2o, ln2_g, ln2_b, y2, nullptr);

    // ---------------- pool + MLP head (fp32, tiny) ----------------
    pool_k<<<BGR, 256, 0, stream>>>(y2, pooled);
    gemm_k<1><<<dim3(4, 4), 256, 0, stream>>>(pooled, fc1_w, fc1_b, fc1o, 256, 256, 256);
    gemm_k<0><<<dim3(1, 4), 256, 0, stream>>>(fc1o, fc2_w, fc2_b, (float*)d_out, 256, 1, 256);
}

// Round 7
// 1081.012 us; speedup vs baseline: 4.2004x; 1.0580x over previous
//
#include <hip/hip_runtime.h>
#include <hip/hip_bf16.h>
#include <cstdint>
#include <cstddef>

#define NAT 16384
#define NED 65536
#define BGR 256
#define FIN 64
#define HID 256
#define LPN 1024
#define HD 64

typedef __bf16 bf16x8 __attribute__((ext_vector_type(8)));
typedef float floatx4 __attribute__((ext_vector_type(4)));

// async global->LDS 16B; dest = wave-uniform base + lane*16 (linear layout!)
__device__ __forceinline__ void gl2lds16(const void* g, void* l)
{
    __builtin_amdgcn_global_load_lds(
        (const __attribute__((address_space(1))) unsigned int*)g,
        (__attribute__((address_space(3))) unsigned int*)l, 16, 0, 0);
}

// ---------------- bf16 MFMA GEMM, async staging + XOR swizzle ----------------
// A[M,K] bf16 rm, Bt[N,K] bf16 rm. M%128==0, N%128==0, K%32==0. Tile 128x128.
template<int ACT, int OUTBF16, int BIASROW>
__global__ __launch_bounds__(256) void gemm_mfma(const __bf16* __restrict__ A,
    const __bf16* __restrict__ Bt, const float* __restrict__ bias,
    void* __restrict__ Cout, int M, int Nn, int K, float escale)
{
    __shared__ __bf16 As[128][32];
    __shared__ __bf16 Bs[128][32];
    const int t = threadIdx.x;
    const int m0 = blockIdx.y * 128, n0 = blockIdx.x * 128;
    const int wave = t >> 6, lane = t & 63;
    const int wm = (wave >> 1) * 64, wn = (wave & 1) * 64;
    const int quad = lane >> 4, l16 = lane & 15;
    const int r0 = t >> 2, s0 = t & 3, g0 = (s0 ^ (r0 & 3)) * 8;
    const int r1 = r0 + 64,            g1 = (s0 ^ (r1 & 3)) * 8;
    const int fso = (quad ^ (l16 & 3)) * 8;
    floatx4 acc[4][4] = {};
    for (int k0 = 0; k0 < K; k0 += 32) {
        gl2lds16(A + (size_t)(m0 + r0) * K + k0 + g0, &As[r0][s0 * 8]);
        gl2lds16(A + (size_t)(m0 + r1) * K + k0 + g1, &As[r1][s0 * 8]);
        gl2lds16(Bt + (size_t)(n0 + r0) * K + k0 + g0, &Bs[r0][s0 * 8]);
        gl2lds16(Bt + (size_t)(n0 + r1) * K + k0 + g1, &Bs[r1][s0 * 8]);
        __syncthreads();
        bf16x8 af[4], bfr[4];
#pragma unroll
        for (int mi = 0; mi < 4; mi++) af[mi]  = *(const bf16x8*)&As[wm + mi * 16 + l16][fso];
#pragma unroll
        for (int nj = 0; nj < 4; nj++) bfr[nj] = *(const bf16x8*)&Bs[wn + nj * 16 + l16][fso];
#pragma unroll
        for (int mi = 0; mi < 4; mi++)
#pragma unroll
            for (int nj = 0; nj < 4; nj++)
                acc[mi][nj] = __builtin_amdgcn_mfma_f32_16x16x32_bf16(af[mi], bfr[nj], acc[mi][nj], 0, 0, 0);
        __syncthreads();
    }
#pragma unroll
    for (int mi = 0; mi < 4; mi++)
#pragma unroll
        for (int nj = 0; nj < 4; nj++) {
            int col = n0 + wn + nj * 16 + l16;
#pragma unroll
            for (int r = 0; r < 4; r++) {
                int row = m0 + wm + mi * 16 + quad * 4 + r;
                float bval = bias ? (BIASROW ? bias[row] : bias[col]) : 0.f;
                float v = (acc[mi][nj][r] + bval) * escale;
                if (ACT == 1) v = fmaxf(v, 0.f);
                if (ACT == 2) v = 0.5f * v * (1.f + erff(v * 0.70710678118654752f));
                if (OUTBF16) ((__bf16*)Cout)[(size_t)row * Nn + col] = (__bf16)v;
                else         ((float*)Cout)[(size_t)row * Nn + col] = v;
            }
        }
}

// ---------------- wide-tile (128x256) bf16 MFMA GEMM, bf16 out ----------------
template<int ACT>
__global__ __launch_bounds__(256) void gemm_w(const __bf16* __restrict__ A,
    const __bf16* __restrict__ Bt, const float* __restrict__ bias,
    __bf16* __restrict__ C, int M, int Nn, int K)
{
    __shared__ __bf16 As[128][32];
    __shared__ __bf16 Bs[256][32];
    const int t = threadIdx.x;
    const int m0 = blockIdx.y * 128, n0 = blockIdx.x * 256;
    const int wave = t >> 6, lane = t & 63;
    const int wm = (wave >> 1) * 64, wn = (wave & 1) * 128;
    const int quad = lane >> 4, l16 = lane & 15;
    const int ra = t >> 2, s0 = t & 3;
    const int fso = (quad ^ (l16 & 3)) * 8;
    floatx4 acc[4][8] = {};
    for (int k0 = 0; k0 < K; k0 += 32) {
        {
            int g0 = (s0 ^ (ra & 3)) * 8;
            int r1 = ra + 64, g1 = (s0 ^ (r1 & 3)) * 8;
            gl2lds16(A + (size_t)(m0 + ra) * K + k0 + g0, &As[ra][s0 * 8]);
            gl2lds16(A + (size_t)(m0 + r1) * K + k0 + g1, &As[r1][s0 * 8]);
        }
#pragma unroll
        for (int i = 0; i < 4; i++) {
            int rb = ra + i * 64;
            int gb = (s0 ^ (rb & 3)) * 8;
            gl2lds16(Bt + (size_t)(n0 + rb) * K + k0 + gb, &Bs[rb][s0 * 8]);
        }
        __syncthreads();
        bf16x8 af[4], bfr[8];
#pragma unroll
        for (int mi = 0; mi < 4; mi++) af[mi]  = *(const bf16x8*)&As[wm + mi * 16 + l16][fso];
#pragma unroll
        for (int nj = 0; nj < 8; nj++) bfr[nj] = *(const bf16x8*)&Bs[wn + nj * 16 + l16][fso];
#pragma unroll
        for (int mi = 0; mi < 4; mi++)
#pragma unroll
            for (int nj = 0; nj < 8; nj++)
                acc[mi][nj] = __builtin_amdgcn_mfma_f32_16x16x32_bf16(af[mi], bfr[nj], acc[mi][nj], 0, 0, 0);
        __syncthreads();
    }
#pragma unroll
    for (int mi = 0; mi < 4; mi++)
#pragma unroll
        for (int nj = 0; nj < 8; nj++) {
            int col = n0 + wn + nj * 16 + l16;
            float bval = bias[col];
#pragma unroll
            for (int r = 0; r < 4; r++) {
                int row = m0 + wm + mi * 16 + quad * 4 + r;
                float v = acc[mi][nj][r] + bval;
                if (ACT == 1) v = fmaxf(v, 0.f);
                if (ACT == 2) v = 0.5f * v * (1.f + erff(v * 0.70710678118654752f));
                C[(size_t)row * Nn + col] = (__bf16)v;
            }
        }
}

// ---------------- GAT feature GEMM: bf16 hg + partial a_s/a_d (no atomics) ----
__global__ __launch_bounds__(256) void gemm_gat(const __bf16* __restrict__ A,
    const __bf16* __restrict__ Bt, const float* __restrict__ as_f,
    const float* __restrict__ ad_f, __bf16* __restrict__ Hg,
    float* __restrict__ part, int K)
{
    __shared__ __bf16 As[128][32];
    __shared__ __bf16 Bs[128][32];
    const int t = threadIdx.x;
    const int m0 = blockIdx.y * 128, n0 = blockIdx.x * 128;
    const int wave = t >> 6, lane = t & 63;
    const int wm = (wave >> 1) * 64, wn = (wave & 1) * 64;
    const int quad = lane >> 4, l16 = lane & 15;
    const int r0 = t >> 2, s0 = t & 3, g0 = (s0 ^ (r0 & 3)) * 8;
    const int r1 = r0 + 64,            g1 = (s0 ^ (r1 & 3)) * 8;
    const int fso = (quad ^ (l16 & 3)) * 8;
    floatx4 acc[4][4] = {};
    for (int k0 = 0; k0 < K; k0 += 32) {
        gl2lds16(A + (size_t)(m0 + r0) * K + k0 + g0, &As[r0][s0 * 8]);
        gl2lds16(A + (size_t)(m0 + r1) * K + k0 + g1, &As[r1][s0 * 8]);
        gl2lds16(Bt + (size_t)(n0 + r0) * K + k0 + g0, &Bs[r0][s0 * 8]);
        gl2lds16(Bt + (size_t)(n0 + r1) * K + k0 + g1, &Bs[r1][s0 * 8]);
        __syncthreads();
        bf16x8 af[4], bfr[4];
#pragma unroll
        for (int mi = 0; mi < 4; mi++) af[mi]  = *(const bf16x8*)&As[wm + mi * 16 + l16][fso];
#pragma unroll
        for (int nj = 0; nj < 4; nj++) bfr[nj] = *(const bf16x8*)&Bs[wn + nj * 16 + l16][fso];
#pragma unroll
        for (int mi = 0; mi < 4; mi++)
#pragma unroll
            for (int nj = 0; nj < 4; nj++)
                acc[mi][nj] = __builtin_amdgcn_mfma_f32_16x16x32_bf16(af[mi], bfr[nj], acc[mi][nj], 0, 0, 0);
        __syncthreads();
    }
    // partial a_s/a_d for this (colblock, wave-col-half): slot = cb*2 + (wn>>6)
    const int slot = blockIdx.x * 2 + (wn >> 6);
#pragma unroll
    for (int mi = 0; mi < 4; mi++) {
#pragma unroll
        for (int r = 0; r < 4; r++) {
            float ps = 0.f, pd = 0.f;
#pragma unroll
            for (int nj = 0; nj < 4; nj++) {
                int col = n0 + wn + nj * 16 + l16;
                float v = acc[mi][nj][r];
                ps += v * as_f[col];
                pd += v * ad_f[col];
            }
#pragma unroll
            for (int off = 1; off < 16; off <<= 1) {
                ps += __shfl_xor(ps, off, 64);
                pd += __shfl_xor(pd, off, 64);
            }
            if (l16 == 0) {
                int row = m0 + wm + mi * 16 + quad * 4 + r;
                part[(size_t)(slot * 2 + 0) * NAT + row] = ps;
                part[(size_t)(slot * 2 + 1) * NAT + row] = pd;
            }
        }
    }
#pragma unroll
    for (int mi = 0; mi < 4; mi++)
#pragma unroll
        for (int nj = 0; nj < 4; nj++) {
            int col = n0 + wn + nj * 16 + l16;
#pragma unroll
            for (int r = 0; r < 4; r++) {
                int row = m0 + wm + mi * 16 + quad * 4 + r;
                Hg[(size_t)row * 512 + col] = (__bf16)acc[mi][nj][r];
            }
        }
}

// fold 8 column-partials into a_s/a_d
__global__ void fold_k(const float* __restrict__ part, float* __restrict__ a_s,
                       float* __restrict__ a_d)
{
    int n = blockIdx.x * 256 + threadIdx.x;
    float s0 = 0.f, d0 = 0.f, s1 = 0.f, d1 = 0.f;
#pragma unroll
    for (int sl = 0; sl < 4; sl++) {
        s0 += part[(size_t)(sl * 2 + 0) * NAT + n];
        d0 += part[(size_t)(sl * 2 + 1) * NAT + n];
        s1 += part[(size_t)((sl + 4) * 2 + 0) * NAT + n];
        d1 += part[(size_t)((sl + 4) * 2 + 1) * NAT + n];
    }
    a_s[n * 2 + 0] = s0; a_s[n * 2 + 1] = s1;
    a_d[n * 2 + 0] = d0; a_d[n * 2 + 1] = d1;
}

// ---------------- conv1d implicit GEMM, fused embed gather, async staging -----
__global__ __launch_bounds__(256) void conv_mfma(const int* __restrict__ seq,
    const __bf16* __restrict__ embb, const __bf16* __restrict__ wtb,
    const float* __restrict__ bias, __bf16* __restrict__ C, int b_base,
    const __bf16* __restrict__ zrow)
{
    __shared__ __bf16 As[128][32];
    __shared__ __bf16 Bs[128][32];
    __shared__ int toks[130];
    const int t = threadIdx.x;
    const int m0 = blockIdx.y * 128, n0 = blockIdx.x * 128;
    const int b = b_base + (m0 >> 10), l0 = m0 & 1023;
    if (t < 130) {
        int l = l0 + t - 1;
        toks[t] = (l >= 0 && l < LPN) ? seq[b * LPN + l] : -1;
    }
    const int wave = t >> 6, lane = t & 63;
    const int wm = (wave >> 1) * 64, wn = (wave & 1) * 64;
    const int quad = lane >> 4, l16 = lane & 15;
    const int r0 = t >> 2, s0 = t & 3, g0 = (s0 ^ (r0 & 3)) * 8;
    const int r1 = r0 + 64,            g1 = (s0 ^ (r1 & 3)) * 8;
    const int fso = (quad ^ (l16 & 3)) * 8;
    floatx4 acc[4][4] = {};
    __syncthreads();
    for (int k0 = 0; k0 < 768; k0 += 32) {
        int dl = k0 >> 8, c0 = k0 & 255;
        int tok0 = toks[r0 + dl], tok1 = toks[r1 + dl];
        const __bf16* ga0 = (tok0 >= 0) ? embb + (size_t)tok0 * HID + c0 + g0 : zrow + g0;
        const __bf16* ga1 = (tok1 >= 0) ? embb + (size_t)tok1 * HID + c0 + g1 : zrow + g1;
        gl2lds16(ga0, &As[r0][s0 * 8]);
        gl2lds16(ga1, &As[r1][s0 * 8]);
        gl2lds16(wtb + (size_t)(n0 + r0) * 768 + k0 + g0, &Bs[r0][s0 * 8]);
        gl2lds16(wtb + (size_t)(n0 + r1) * 768 + k0 + g1, &Bs[r1][s0 * 8]);
        __syncthreads();
        bf16x8 af[4], bfr[4];
#pragma unroll
        for (int mi = 0; mi < 4; mi++) af[mi]  = *(const bf16x8*)&As[wm + mi * 16 + l16][fso];
#pragma unroll
        for (int nj = 0; nj < 4; nj++) bfr[nj] = *(const bf16x8*)&Bs[wn + nj * 16 + l16][fso];
#pragma unroll
        for (int mi = 0; mi < 4; mi++)
#pragma unroll
            for (int nj = 0; nj < 4; nj++)
                acc[mi][nj] = __builtin_amdgcn_mfma_f32_16x16x32_bf16(af[mi], bfr[nj], acc[mi][nj], 0, 0, 0);
        __syncthreads();
    }
#pragma unroll
    for (int mi = 0; mi < 4; mi++)
#pragma unroll
        for (int nj = 0; nj < 4; nj++) {
            int col = n0 + wn + nj * 16 + l16;
            float bval = bias[col];
#pragma unroll
            for (int r = 0; r < 4; r++) {
                int row = m0 + wm + mi * 16 + quad * 4 + r;
                float v = fmaxf(acc[mi][nj][r] + bval, 0.f);
                C[(size_t)row * 256 + col] = (__bf16)v;
            }
        }
}

// ---------------- single fused conversion kernel ----------------
struct Segs {
    const float* src[12];
    __bf16* dst[12];
    int kdim[12];
    int ndim[12];
    int mode[12];          // 0 copy, 1 transpose, 2 conv-weight
    int start[13];
};

__global__ void cvtall_k(Segs S, int total)
{
    int i = blockIdx.x * 256 + threadIdx.x;
    if (i >= total) return;
    int s = 0;
    while (i >= S.start[s + 1]) s++;
    int j = i - S.start[s];
    if (S.mode[s] == 0) {
        S.dst[s][j] = (__bf16)S.src[s][j];
    } else if (S.mode[s] == 1) {
        int K = S.kdim[s], N = S.ndim[s];
        int n = j / K, k = j - n * K;
        S.dst[s][j] = (__bf16)S.src[s][(size_t)k * N + n];
    } else {
        int n = j / 768, r = j - n * 768;
        int dl = r >> 8, kk = r & 255;
        S.dst[s][j] = (__bf16)S.src[s][(size_t)n * 768 + kk * 3 + dl];
    }
}

// ---------------- CSR build ----------------
__global__ void deg_k(const int* __restrict__ ei, int* __restrict__ deg)
{
    int e = blockIdx.x * 256 + threadIdx.x;
    if (e < NED) atomicAdd(&deg[ei[NED + e]], 1);
}

__global__ __launch_bounds__(256) void scan_k(const int* __restrict__ deg, int* __restrict__ rowptr)
{
    __shared__ int part[256];
    int t = threadIdx.x;
    int base = t * 64;
    int s = 0;
#pragma unroll
    for (int i = 0; i < 64; i++) s += deg[base + i];
    part[t] = s;
    __syncthreads();
    for (int off = 1; off < 256; off <<= 1) {
        int v = (t >= off) ? part[t - off] : 0;
        __syncthreads();
        part[t] += v;
        __syncthreads();
    }
    int run = t ? part[t - 1] : 0;
    for (int i = 0; i < 64; i++) { rowptr[base + i] = run; run += deg[base + i]; }
    if (t == 255) rowptr[16384] = run;
}

__global__ void scat_k(const int* __restrict__ ei, int* __restrict__ fill,
                       const int* __restrict__ rowptr, int* __restrict__ csrc)
{
    int e = blockIdx.x * 256 + threadIdx.x;
    if (e >= NED) return;
    int d = ei[NED + e];
    int pos = rowptr[d] + atomicAdd(&fill[d], 1);
    csrc[pos] = ei[e];
}

// ---------------- fused GAT aggregation (bf16 features) ----------------
__global__ __launch_bounds__(256) void gat_agg(const int* __restrict__ rowptr,
    const int* __restrict__ csrc, const __bf16* __restrict__ hgb,
    const float* __restrict__ a_s, const float* __restrict__ a_d,
    const float* __restrict__ bias, float* __restrict__ out, __bf16* __restrict__ outb)
{
    const int wave = threadIdx.x >> 6, lane = threadIdx.x & 63;
    const int d = blockIdx.x * 4 + wave;
    const int beg = rowptr[d], end = rowptr[d + 1];
    const float ad0 = a_d[d * 2 + 0], ad1 = a_d[d * 2 + 1];
    float e0 = a_s[d * 2 + 0] + ad0; e0 = (e0 > 0.f) ? e0 : 0.2f * e0;
    float e1 = a_s[d * 2 + 1] + ad1; e1 = (e1 > 0.f) ? e1 : 0.2f * e1;
    float m0 = e0, m1 = e1;
    for (int p = beg; p < end; p++) {
        int s = csrc[p];
        float v0 = a_s[s * 2 + 0] + ad0; v0 = (v0 > 0.f) ? v0 : 0.2f * v0;
        float v1 = a_s[s * 2 + 1] + ad1; v1 = (v1 > 0.f) ? v1 : 0.2f * v1;
        m0 = fmaxf(m0, v0); m1 = fmaxf(m1, v1);
    }
    float den0 = __expf(e0 - m0), den1 = __expf(e1 - m1);
    for (int p = beg; p < end; p++) {
        int s = csrc[p];
        float v0 = a_s[s * 2 + 0] + ad0; v0 = (v0 > 0.f) ? v0 : 0.2f * v0;
        float v1 = a_s[s * 2 + 1] + ad1; v1 = (v1 > 0.f) ? v1 : 0.2f * v1;
        den0 += __expf(v0 - m0); den1 += __expf(v1 - m1);
    }
    const float inv0 = 1.f / den0, inv1 = 1.f / den1;
    const int ch = lane * 8;
    const int g = ch >> 8;
    const float mg = g ? m1 : m0, invg = g ? inv1 : inv0, adg = g ? ad1 : ad0;
    float acc[8] = {};
    {
        float al = __expf((g ? e1 : e0) - mg) * invg;
        bf16x8 hv = *(const bf16x8*)(hgb + (size_t)d * 512 + ch);
#pragma unroll
        for (int j = 0; j < 8; j++) acc[j] += (float)hv[j] * al;
    }
    for (int p = beg; p < end; p++) {
        int s = csrc[p];
        float v = a_s[s * 2 + g] + adg; v = (v > 0.f) ? v : 0.2f * v;
        float al = __expf(v - mg) * invg;
        bf16x8 hv = *(const bf16x8*)(hgb + (size_t)s * 512 + ch);
#pragma unroll
        for (int j = 0; j < 8; j++) acc[j] += (float)hv[j] * al;
    }
    float other[8];
#pragma unroll
    for (int j = 0; j < 8; j++) other[j] = __shfl_xor(acc[j], 32, 64);
    if (lane < 32) {
#pragma unroll
        for (int j = 0; j < 8; j++) {
            float v = 0.5f * (acc[j] + other[j]) + bias[ch + j];
            v = (v > 0.f) ? v : expm1f(v);
            if (out) out[(size_t)d * 256 + ch + j] = v;
            outb[(size_t)d * 256 + ch + j] = (__bf16)v;
        }
    }
}

// ---------------- MFMA flash cross-attention ----------------
__global__ __launch_bounds__(256) void attn2_k(const __bf16* __restrict__ Qb,
    const __bf16* __restrict__ Kb, const __bf16* __restrict__ Vtb,
    const int* __restrict__ seq, __bf16* __restrict__ O, int b0, int ldV)
{
    __shared__ __bf16 Ps[4][16][72];
    __shared__ float mask_s[LPN];
    const int t = threadIdx.x;
    const int bl = blockIdx.x >> 2, h = blockIdx.x & 3;
    const int b = b0 + bl;
    const int w = t >> 6, lane = t & 63;
    const int quad = lane >> 4, l16 = lane & 15;
    for (int i = t; i < LPN; i += 256)
        mask_s[i] = (seq[b * LPN + i] == 0) ? -1e9f : 0.f;
    const __bf16* qrow = Qb + (size_t)(b * 64 + w * 16 + l16) * HID + h * HD;
    bf16x8 aq0 = *(const bf16x8*)(qrow + quad * 8);
    bf16x8 aq1 = *(const bf16x8*)(qrow + 32 + quad * 8);
    float m_run[4] = {-3e38f, -3e38f, -3e38f, -3e38f};
    float l_run[4] = {0.f, 0.f, 0.f, 0.f};
    floatx4 ctx[4] = {};
    __syncthreads();
    for (int kp0 = 0; kp0 < LPN; kp0 += 64) {
        floatx4 s[4];
#pragma unroll
        for (int nj = 0; nj < 4; nj++) {
            const __bf16* krow = Kb + (size_t)(bl * LPN + kp0 + nj * 16 + l16) * HID + h * HD;
            bf16x8 bk0 = *(const bf16x8*)(krow + quad * 8);
            bf16x8 bk1 = *(const bf16x8*)(krow + 32 + quad * 8);
            floatx4 z = {0.f, 0.f, 0.f, 0.f};
            s[nj] = __builtin_amdgcn_mfma_f32_16x16x32_bf16(aq0, bk0, z, 0, 0, 0);
            s[nj] = __builtin_amdgcn_mfma_f32_16x16x32_bf16(aq1, bk1, s[nj], 0, 0, 0);
        }
#pragma unroll
        for (int nj = 0; nj < 4; nj++) {
            float mval = mask_s[kp0 + nj * 16 + l16];
#pragma unroll
            for (int r = 0; r < 4; r++) s[nj][r] += mval;
        }
        float alpha[4];
#pragma unroll
        for (int r = 0; r < 4; r++) {
            float mx = fmaxf(fmaxf(s[0][r], s[1][r]), fmaxf(s[2][r], s[3][r]));
#pragma unroll
            for (int off = 1; off < 16; off <<= 1) mx = fmaxf(mx, __shfl_xor(mx, off, 64));
            float mn = fmaxf(m_run[r], mx);
            alpha[r] = __expf(m_run[r] - mn);
            m_run[r] = mn;
            float rs = 0.f;
#pragma unroll
            for (int nj = 0; nj < 4; nj++) {
                float p = __expf(s[nj][r] - mn);
                s[nj][r] = p;
                rs += p;
            }
#pragma unroll
            for (int off = 1; off < 16; off <<= 1) rs += __shfl_xor(rs, off, 64);
            l_run[r] = l_run[r] * alpha[r] + rs;
        }
#pragma unroll
        for (int nj = 0; nj < 4; nj++)
#pragma unroll
            for (int r = 0; r < 4; r++)
                Ps[w][quad * 4 + r][nj * 16 + l16] = (__bf16)s[nj][r];
        bf16x8 pa0 = *(const bf16x8*)&Ps[w][l16][quad * 8];
        bf16x8 pa1 = *(const bf16x8*)&Ps[w][l16][32 + quad * 8];
#pragma unroll
        for (int dj = 0; dj < 4; dj++) {
#pragma unroll
            for (int r = 0; r < 4; r++) ctx[dj][r] *= alpha[r];
            const __bf16* vrow = Vtb + (size_t)(h * HD + dj * 16 + l16) * ldV + bl * LPN + kp0;
            bf16x8 bv0 = *(const bf16x8*)(vrow + quad * 8);
            bf16x8 bv1 = *(const bf16x8*)(vrow + 32 + quad * 8);
            ctx[dj] = __builtin_amdgcn_mfma_f32_16x16x32_bf16(pa0, bv0, ctx[dj], 0, 0, 0);
            ctx[dj] = __builtin_amdgcn_mfma_f32_16x16x32_bf16(pa1, bv1, ctx[dj], 0, 0, 0);
        }
    }
#pragma unroll
    for (int dj = 0; dj < 4; dj++)
#pragma unroll
        for (int r = 0; r < 4; r++) {
            int q = b * 64 + w * 16 + quad * 4 + r;
            int d = h * HD + dj * 16 + l16;
            O[(size_t)q * HID + d] = (__bf16)(ctx[dj][r] / l_run[r]);
        }
}

// ---------------- LayerNorm(residual) ----------------
__device__ __forceinline__ float blockSum256(float v, float* red)
{
#pragma unroll
    for (int off = 32; off >= 1; off >>= 1) v += __shfl_down(v, off, 64);
    int wave = threadIdx.x >> 6, lane = threadIdx.x & 63;
    if (lane == 0) red[wave] = v;
    __syncthreads();
    float s = red[0] + red[1] + red[2] + red[3];
    __syncthreads();
    return s;
}

__global__ __launch_bounds__(256) void lnres_k(const float* __restrict__ A,
    const float* __restrict__ Bb, const float* __restrict__ g,
    const float* __restrict__ be, float* __restrict__ Y, __bf16* __restrict__ Yb)
{
    __shared__ float red[4];
    int r = blockIdx.x, t = threadIdx.x;
    float v = A[(size_t)r * 256 + t] + Bb[(size_t)r * 256 + t];
    float mean = blockSum256(v, red) * (1.f / 256.f);
    float d = v - mean;
    float var = blockSum256(d * d, red) * (1.f / 256.f);
    float o = d * rsqrtf(var + 1e-5f) * g[t] + be[t];
    Y[(size_t)r * 256 + t] = o;
    if (Yb) Yb[(size_t)r * 256 + t] = (__bf16)o;
}

// ---------------- fused head: mean-pool + fc1(relu) + fc2 ----------------
__global__ __launch_bounds__(256) void head_k(const float* __restrict__ Y,
    const float* __restrict__ fc1w, const float* __restrict__ fc1b,
    const float* __restrict__ fc2w, const float* __restrict__ fc2b,
    float* __restrict__ out)
{
    __shared__ float pooled[256];
    __shared__ float h[256];
    __shared__ float red[4];
    int b = blockIdx.x, t = threadIdx.x;
    float s = 0.f;
#pragma unroll 8
    for (int q = 0; q < 64; q++) s += Y[(size_t)(b * 64 + q) * 256 + t];
    pooled[t] = s / (64.f + 1e-6f);
    __syncthreads();
    float a = 0.f;
    for (int k = 0; k < 256; k += 4) {
        a += pooled[k + 0] * fc1w[(k + 0) * 256 + t];
        a += pooled[k + 1] * fc1w[(k + 1) * 256 + t];
        a += pooled[k + 2] * fc1w[(k + 2) * 256 + t];
        a += pooled[k + 3] * fc1w[(k + 3) * 256 + t];
    }
    h[t] = fmaxf(a + fc1b[t], 0.f);
    __syncthreads();
    float p = h[t] * fc2w[t];
    p = blockSum256(p, red);
    if (t == 0) out[b] = p + fc2b[0];
}

// ---------------- launch ----------------
extern "C" void kernel_launch(void* const* d_in, const int* in_sizes, int n_in,
                              void* d_out, int out_size, void* d_ws, size_t ws_size,
                              hipStream_t stream)
{
    const float* x     = (const float*)d_in[0];
    const int*   ei    = (const int*)d_in[1];
    const int*   pseq  = (const int*)d_in[3];
    const float* w1  = (const float*)d_in[4];
    const float* as1 = (const float*)d_in[5];
    const float* ad1 = (const float*)d_in[6];
    const float* b1  = (const float*)d_in[7];
    const float* w2  = (const float*)d_in[8];
    const float* as2 = (const float*)d_in[9];
    const float* ad2 = (const float*)d_in[10];
    const float* b2  = (const float*)d_in[11];
    const float* w3  = (const float*)d_in[12];
    const float* as3 = (const float*)d_in[13];
    const float* ad3 = (const float*)d_in[14];
    const float* b3  = (const float*)d_in[15];
    const float* emb    = (const float*)d_in[16];
    const float* conv_w = (const float*)d_in[17];
    const float* conv_b = (const float*)d_in[18];
    const float* wq = (const float*)d_in[19];
    const float* bq = (const float*)d_in[20];
    const float* wk = (const float*)d_in[21];
    const float* bk = (const float*)d_in[22];
    const float* wv = (const float*)d_in[23];
    const float* bv = (const float*)d_in[24];
    const float* wo = (const float*)d_in[25];
    const float* bo = (const float*)d_in[26];
    const float* ln1_g = (const float*)d_in[27];
    const float* ln1_b = (const float*)d_in[28];
    const float* ffw1  = (const float*)d_in[29];
    const float* ffb1  = (const float*)d_in[30];
    const float* ffw2  = (const float*)d_in[31];
    const float* ffb2  = (const float*)d_in[32];
    const float* ln2_g = (const float*)d_in[33];
    const float* ln2_b = (const float*)d_in[34];
    const float* fc1_w = (const float*)d_in[35];
    const float* fc1_b = (const float*)d_in[36];
    const float* fc2_w = (const float*)d_in[37];
    const float* fc2_b = (const float*)d_in[38];
    (void)in_sizes; (void)n_in; (void)out_size;

    char* ws = (char*)d_ws;
    size_t off = 0;
    auto alloc = [&](size_t bytes) -> char* {
        char* p = ws + off;
        off += (bytes + 255) & ~(size_t)255;
        return p;
    };
    // ---- fixed arena ----
    __bf16* hgb  = (__bf16*)alloc((size_t)NAT * 512 * 2);
    float* og    = (float*)alloc((size_t)NAT * 512 * 4);
    float* hb0   = (float*)alloc((size_t)NAT * 256 * 4);
    float* hb1   = (float*)alloc((size_t)NAT * 256 * 4);
    __bf16* xb   = (__bf16*)alloc((size_t)NAT * FIN * 2);
    __bf16* hbb  = (__bf16*)alloc((size_t)NAT * 256 * 2);
    __bf16* qbb  = (__bf16*)alloc((size_t)NAT * 256 * 2);
    __bf16* ctxbb= (__bf16*)alloc((size_t)NAT * 256 * 2);
    __bf16* ybb  = (__bf16*)alloc((size_t)NAT * 256 * 2);
    float* a_s   = (float*)alloc((size_t)NAT * 2 * 4);
    float* a_d   = (float*)alloc((size_t)NAT * 2 * 4);
    float* asd_p = (float*)alloc((size_t)16 * NAT * 4);
    int* deg     = (int*)alloc((size_t)NAT * 4);
    int* fill    = (int*)alloc((size_t)NAT * 4);
    int* rowptr  = (int*)alloc((size_t)(NAT + 1) * 4);
    int* csrc    = (int*)alloc((size_t)NED * 4);
    __bf16* embb = (__bf16*)alloc((size_t)22 * 256 * 2);
    __bf16* wtb  = (__bf16*)alloc((size_t)256 * 768 * 2);
    __bf16* zpad = (__bf16*)alloc(256);
    __bf16* w1T  = (__bf16*)alloc((size_t)512 * 64 * 2);
    __bf16* w2T  = (__bf16*)alloc((size_t)512 * 256 * 2);
    __bf16* w3T  = (__bf16*)alloc((size_t)512 * 256 * 2);
    __bf16* wkT  = (__bf16*)alloc((size_t)256 * 256 * 2);
    __bf16* wvT  = (__bf16*)alloc((size_t)256 * 256 * 2);
    __bf16* wqT  = (__bf16*)alloc((size_t)256 * 256 * 2);
    __bf16* woT  = (__bf16*)alloc((size_t)256 * 256 * 2);
    __bf16* f1T  = (__bf16*)alloc((size_t)1024 * 256 * 2);
    __bf16* f2T  = (__bf16*)alloc((size_t)256 * 1024 * 2);
    // ---- variable region ----
    size_t fixed_end = off;
    size_t rem = (ws_size > fixed_end) ? ws_size - fixed_end : 0;
    const size_t G1 = (size_t)LPN * 256 * 2;
    const size_t ffneed = (size_t)NAT * 1024 * 2 + (size_t)NAT * 256 * 4;
    int CB = 8;
    {
        const int cands[6] = {256, 128, 64, 32, 16, 8};
        for (int ci = 0; ci < 6; ci++) {
            size_t regneed = 3 * (size_t)cands[ci] * G1;
            if (regneed < ffneed) regneed = ffneed;
            if (regneed <= rem) { CB = cands[ci]; break; }
        }
    }
    char* region   = ws + fixed_end;
    __bf16* pconvb = (__bf16*)region;
    __bf16* kbb    = (__bf16*)(region + (size_t)CB * G1);
    __bf16* vtb    = (__bf16*)(region + 2 * (size_t)CB * G1);
    __bf16* ffbb   = (__bf16*)region;
    float*  y2     = (float*)(region + (size_t)NAT * 1024 * 2);
    float* attno = og;
    float* ybuf  = og + (size_t)NAT * 256;
    float* ff2o  = hb1;

    // ---------------- CSR build + zero page ----------------
    hipMemsetAsync(deg, 0, (size_t)NAT * 8, stream);   // deg + fill (adjacent)
    hipMemsetAsync(zpad, 0, 256, stream);
    deg_k<<<NED / 256, 256, 0, stream>>>(ei, deg);
    scan_k<<<1, 256, 0, stream>>>(deg, rowptr);
    scat_k<<<NED / 256, 256, 0, stream>>>(ei, fill, rowptr, csrc);

    // ---------------- all conversions in one dispatch ----------------
    {
        Segs S;
        const float* srcs[12] = {x, emb, conv_w, w1, w2, w3, wk, wv, wq, wo, ffw1, ffw2};
        __bf16* dsts[12] = {xb, embb, wtb, w1T, w2T, w3T, wkT, wvT, wqT, woT, f1T, f2T};
        int kd[12] = {0, 0, 0, 64, 256, 256, 256, 256, 256, 256, 256, 1024};
        int nd[12] = {0, 0, 0, 512, 512, 512, 256, 256, 256, 256, 1024, 256};
        int md[12] = {0, 0, 2, 1, 1, 1, 1, 1, 1, 1, 1, 1};
        int cnt[12] = {NAT * FIN, 22 * 256, 196608, 32768, 131072, 131072,
                       65536, 65536, 65536, 65536, 262144, 262144};
        int run = 0;
        for (int i = 0; i < 12; i++) {
            S.src[i] = srcs[i]; S.dst[i] = dsts[i];
            S.kdim[i] = kd[i]; S.ndim[i] = nd[i]; S.mode[i] = md[i];
            S.start[i] = run; run += cnt[i];
        }
        S.start[12] = run;
        cvtall_k<<<(run + 255) / 256, 256, 0, stream>>>(S, run);
    }

    // ---------------- ligand GNN: 3 GAT layers ----------------
    const __bf16* WT[3] = {w1T, w2T, w3T};
    const float* asl[3] = {as1, as2, as3};
    const float* adl[3] = {ad1, ad2, ad3};
    const float* bl[3]  = {b1, b2, b3};
    float* houts[3] = {nullptr, nullptr, hb0};
    const __bf16* hinb = xb;
    int Kdim = FIN;
    for (int l = 0; l < 3; l++) {
        gemm_gat<<<dim3(4, NAT / 128), 256, 0, stream>>>(hinb, WT[l], asl[l], adl[l], hgb, asd_p, Kdim);
        fold_k<<<NAT / 256, 256, 0, stream>>>(asd_p, a_s, a_d);
        gat_agg<<<NAT / 4, 256, 0, stream>>>(rowptr, csrc, hgb, a_s, a_d, bl[l], houts[l], hbb);
        hinb = hbb;
        Kdim = HID;
    }
    const float* lig = hb0;
    const __bf16* ligb = hbb;

    // ---------------- Q projection (scale 1/8 folded in) ----------------
    gemm_mfma<0, 1, 0><<<dim3(2, NAT / 128), 256, 0, stream>>>(ligb, wqT, bq, qbb, NAT, 256, 256, 0.125f);

    // ---------------- protein branch + attention, chunked over graphs ----------
    for (int b0 = 0; b0 < BGR; b0 += CB) {
        int Mc = CB * LPN;
        conv_mfma<<<dim3(2, Mc / 128), 256, 0, stream>>>(pseq, embb, wtb, conv_b, pconvb, b0, zpad);
        gemm_mfma<0, 1, 0><<<dim3(2, Mc / 128), 256, 0, stream>>>(pconvb, wkT, bk, kbb, Mc, 256, 256, 1.f);
        gemm_mfma<0, 1, 1><<<dim3(Mc / 128, 2), 256, 0, stream>>>(wvT, pconvb, bv, vtb, 256, Mc, 256, 1.f);
        attn2_k<<<CB * 4, 256, 0, stream>>>(qbb, kbb, vtb, pseq, ctxbb, b0, Mc);
    }

    // ---------------- attention out proj + LN + FFN + LN ----------------
    gemm_mfma<0, 0, 0><<<dim3(2, NAT / 128), 256, 0, stream>>>(ctxbb, woT, bo, attno, NAT, 256, 256, 1.f);
    lnres_k<<<NAT, 256, 0, stream>>>(lig, attno, ln1_g, ln1_b, ybuf, ybb);
    gemm_w<2><<<dim3(4, NAT / 128), 256, 0, stream>>>(ybb, f1T, ffb1, ffbb, NAT, 1024, 256);
    gemm_mfma<0, 0, 0><<<dim3(2, NAT / 128), 256, 0, stream>>>(ffbb, f2T, ffb2, ff2o, NAT, 256, 1024, 1.f);
    lnres_k<<<NAT, 256, 0, stream>>>(ybuf, ff2o, ln2_g, ln2_b, y2, nullptr);

    // ---------------- fused head ----------------
    head_k<<<BGR, 256, 0, stream>>>(y2, fc1_w, fc1_b, fc2_w, fc2_b, (float*)d_out);
}

// Round 8
// 941.291 us; speedup vs baseline: 4.8239x; 1.1484x over previous
//
#include <hip/hip_runtime.h>
#include <hip/hip_bf16.h>
#include <cstdint>
#include <cstddef>

#define NAT 16384
#define NED 65536
#define BGR 256
#define FIN 64
#define HID 256
#define LPN 1024
#define HD 64

typedef __bf16 bf16x8 __attribute__((ext_vector_type(8)));
typedef float floatx4 __attribute__((ext_vector_type(4)));

// async global->LDS 16B; dest = wave-uniform base + lane*16 (linear layout!)
__device__ __forceinline__ void gl2lds16(const void* g, void* l)
{
    __builtin_amdgcn_global_load_lds(
        (const __attribute__((address_space(1))) unsigned int*)g,
        (__attribute__((address_space(3))) unsigned int*)l, 16, 0, 0);
}

// ---------------- bf16 MFMA GEMM, 8-wave (512t) 128x128 tile ----------------
// A[M,K] bf16 rm, Bt[N,K] bf16 rm. M%128==0, N%128==0, K%32==0.
// LDS rows unpadded; 16B seg s of row r holds global seg (s^(r&3)).
template<int ACT, int OUTBF16, int BIASROW>
__global__ __launch_bounds__(512) void gemm_mfma(const __bf16* __restrict__ A,
    const __bf16* __restrict__ Bt, const float* __restrict__ bias,
    void* __restrict__ Cout, int M, int Nn, int K, float escale)
{
    __shared__ __bf16 As[128][32];
    __shared__ __bf16 Bs[128][32];
    const int t = threadIdx.x;
    const int m0 = blockIdx.y * 128, n0 = blockIdx.x * 128;
    const int w = t >> 6, lane = t & 63;
    const int wm = (w & 3) * 32, wn = (w >> 2) * 64;
    const int quad = lane >> 4, l16 = lane & 15;
    const int r0 = t >> 2, s0 = t & 3, g0 = (s0 ^ (r0 & 3)) * 8;
    const int fso = (quad ^ (l16 & 3)) * 8;
    floatx4 acc[2][4] = {};
    for (int k0 = 0; k0 < K; k0 += 32) {
        gl2lds16(A + (size_t)(m0 + r0) * K + k0 + g0, &As[r0][s0 * 8]);
        gl2lds16(Bt + (size_t)(n0 + r0) * K + k0 + g0, &Bs[r0][s0 * 8]);
        __syncthreads();
        bf16x8 af[2], bfr[4];
#pragma unroll
        for (int mi = 0; mi < 2; mi++) af[mi]  = *(const bf16x8*)&As[wm + mi * 16 + l16][fso];
#pragma unroll
        for (int nj = 0; nj < 4; nj++) bfr[nj] = *(const bf16x8*)&Bs[wn + nj * 16 + l16][fso];
#pragma unroll
        for (int mi = 0; mi < 2; mi++)
#pragma unroll
            for (int nj = 0; nj < 4; nj++)
                acc[mi][nj] = __builtin_amdgcn_mfma_f32_16x16x32_bf16(af[mi], bfr[nj], acc[mi][nj], 0, 0, 0);
        __syncthreads();
    }
#pragma unroll
    for (int mi = 0; mi < 2; mi++)
#pragma unroll
        for (int nj = 0; nj < 4; nj++) {
            int col = n0 + wn + nj * 16 + l16;
#pragma unroll
            for (int r = 0; r < 4; r++) {
                int row = m0 + wm + mi * 16 + quad * 4 + r;
                float bval = bias ? (BIASROW ? bias[row] : bias[col]) : 0.f;
                float v = (acc[mi][nj][r] + bval) * escale;
                if (ACT == 1) v = fmaxf(v, 0.f);
                if (ACT == 2) v = 0.5f * v * (1.f + erff(v * 0.70710678118654752f));
                if (OUTBF16) ((__bf16*)Cout)[(size_t)row * Nn + col] = (__bf16)v;
                else         ((float*)Cout)[(size_t)row * Nn + col] = v;
            }
        }
}

// ---------------- merged K-proj + V^T-proj (z selects), 8-wave ----------------
// z=0: kbb[Mc,256] = pconv @ wkT^T + bk ;  z=1: vtb[256,Mc] = wvT @ pconv^T + bv(row)
__global__ __launch_bounds__(512) void kv_mfma(const __bf16* __restrict__ pconv,
    const __bf16* __restrict__ wkT, const __bf16* __restrict__ wvT,
    const float* __restrict__ bk, const float* __restrict__ bv,
    __bf16* __restrict__ kbb, __bf16* __restrict__ vtb, int Mc)
{
    __shared__ __bf16 As[128][32];
    __shared__ __bf16 Bs[128][32];
    const int t = threadIdx.x;
    const int z = blockIdx.z;
    const int m0 = z ? blockIdx.y * 128 : blockIdx.x * 128;
    const int n0 = z ? blockIdx.x * 128 : blockIdx.y * 128;
    const __bf16* A  = z ? wvT   : pconv;
    const __bf16* Bt = z ? pconv : wkT;
    const int Nn = z ? Mc : 256;
    const int w = t >> 6, lane = t & 63;
    const int wm = (w & 3) * 32, wn = (w >> 2) * 64;
    const int quad = lane >> 4, l16 = lane & 15;
    const int r0 = t >> 2, s0 = t & 3, g0 = (s0 ^ (r0 & 3)) * 8;
    const int fso = (quad ^ (l16 & 3)) * 8;
    floatx4 acc[2][4] = {};
    for (int k0 = 0; k0 < 256; k0 += 32) {
        gl2lds16(A + (size_t)(m0 + r0) * 256 + k0 + g0, &As[r0][s0 * 8]);
        gl2lds16(Bt + (size_t)(n0 + r0) * 256 + k0 + g0, &Bs[r0][s0 * 8]);
        __syncthreads();
        bf16x8 af[2], bfr[4];
#pragma unroll
        for (int mi = 0; mi < 2; mi++) af[mi]  = *(const bf16x8*)&As[wm + mi * 16 + l16][fso];
#pragma unroll
        for (int nj = 0; nj < 4; nj++) bfr[nj] = *(const bf16x8*)&Bs[wn + nj * 16 + l16][fso];
#pragma unroll
        for (int mi = 0; mi < 2; mi++)
#pragma unroll
            for (int nj = 0; nj < 4; nj++)
                acc[mi][nj] = __builtin_amdgcn_mfma_f32_16x16x32_bf16(af[mi], bfr[nj], acc[mi][nj], 0, 0, 0);
        __syncthreads();
    }
    __bf16* out = z ? vtb : kbb;
#pragma unroll
    for (int mi = 0; mi < 2; mi++)
#pragma unroll
        for (int nj = 0; nj < 4; nj++) {
            int col = n0 + wn + nj * 16 + l16;
#pragma unroll
            for (int r = 0; r < 4; r++) {
                int row = m0 + wm + mi * 16 + quad * 4 + r;
                float bval = z ? bv[row] : bk[col];
                out[(size_t)row * Nn + col] = (__bf16)(acc[mi][nj][r] + bval);
            }
        }
}

// ---------------- GAT feature GEMM, 8-wave: bf16 hg + partial a_s/a_d --------
__global__ __launch_bounds__(512) void gemm_gat(const __bf16* __restrict__ A,
    const __bf16* __restrict__ Bt, const float* __restrict__ as_f,
    const float* __restrict__ ad_f, __bf16* __restrict__ Hg,
    float* __restrict__ part, int K)
{
    __shared__ __bf16 As[128][32];
    __shared__ __bf16 Bs[128][32];
    const int t = threadIdx.x;
    const int m0 = blockIdx.y * 128, n0 = blockIdx.x * 128;
    const int w = t >> 6, lane = t & 63;
    const int wm = (w & 3) * 32, wn = (w >> 2) * 64;
    const int quad = lane >> 4, l16 = lane & 15;
    const int r0 = t >> 2, s0 = t & 3, g0 = (s0 ^ (r0 & 3)) * 8;
    const int fso = (quad ^ (l16 & 3)) * 8;
    floatx4 acc[2][4] = {};
    for (int k0 = 0; k0 < K; k0 += 32) {
        gl2lds16(A + (size_t)(m0 + r0) * K + k0 + g0, &As[r0][s0 * 8]);
        gl2lds16(Bt + (size_t)(n0 + r0) * K + k0 + g0, &Bs[r0][s0 * 8]);
        __syncthreads();
        bf16x8 af[2], bfr[4];
#pragma unroll
        for (int mi = 0; mi < 2; mi++) af[mi]  = *(const bf16x8*)&As[wm + mi * 16 + l16][fso];
#pragma unroll
        for (int nj = 0; nj < 4; nj++) bfr[nj] = *(const bf16x8*)&Bs[wn + nj * 16 + l16][fso];
#pragma unroll
        for (int mi = 0; mi < 2; mi++)
#pragma unroll
            for (int nj = 0; nj < 4; nj++)
                acc[mi][nj] = __builtin_amdgcn_mfma_f32_16x16x32_bf16(af[mi], bfr[nj], acc[mi][nj], 0, 0, 0);
        __syncthreads();
    }
    const int slot = blockIdx.x * 2 + (w >> 2);
#pragma unroll
    for (int mi = 0; mi < 2; mi++) {
#pragma unroll
        for (int r = 0; r < 4; r++) {
            float ps = 0.f, pd = 0.f;
#pragma unroll
            for (int nj = 0; nj < 4; nj++) {
                int col = n0 + wn + nj * 16 + l16;
                float v = acc[mi][nj][r];
                ps += v * as_f[col];
                pd += v * ad_f[col];
            }
#pragma unroll
            for (int off = 1; off < 16; off <<= 1) {
                ps += __shfl_xor(ps, off, 64);
                pd += __shfl_xor(pd, off, 64);
            }
            if (l16 == 0) {
                int row = m0 + wm + mi * 16 + quad * 4 + r;
                part[(size_t)(slot * 2 + 0) * NAT + row] = ps;
                part[(size_t)(slot * 2 + 1) * NAT + row] = pd;
            }
        }
    }
#pragma unroll
    for (int mi = 0; mi < 2; mi++)
#pragma unroll
        for (int nj = 0; nj < 4; nj++) {
            int col = n0 + wn + nj * 16 + l16;
#pragma unroll
            for (int r = 0; r < 4; r++) {
                int row = m0 + wm + mi * 16 + quad * 4 + r;
                Hg[(size_t)row * 512 + col] = (__bf16)acc[mi][nj][r];
            }
        }
}

// fold 8 column-partials into a_s/a_d
__global__ void fold_k(const float* __restrict__ part, float* __restrict__ a_s,
                       float* __restrict__ a_d)
{
    int n = blockIdx.x * 256 + threadIdx.x;
    float s0 = 0.f, d0 = 0.f, s1 = 0.f, d1 = 0.f;
#pragma unroll
    for (int sl = 0; sl < 4; sl++) {
        s0 += part[(size_t)(sl * 2 + 0) * NAT + n];
        d0 += part[(size_t)(sl * 2 + 1) * NAT + n];
        s1 += part[(size_t)((sl + 4) * 2 + 0) * NAT + n];
        d1 += part[(size_t)((sl + 4) * 2 + 1) * NAT + n];
    }
    a_s[n * 2 + 0] = s0; a_s[n * 2 + 1] = s1;
    a_d[n * 2 + 0] = d0; a_d[n * 2 + 1] = d1;
}

// ---------------- conv1d implicit GEMM, 8-wave, fused embed gather ------------
__global__ __launch_bounds__(512) void conv_mfma(const int* __restrict__ seq,
    const __bf16* __restrict__ embb, const __bf16* __restrict__ wtb,
    const float* __restrict__ bias, __bf16* __restrict__ C, int b_base,
    const __bf16* __restrict__ zrow)
{
    __shared__ __bf16 As[128][32];
    __shared__ __bf16 Bs[128][32];
    __shared__ int toks[130];
    const int t = threadIdx.x;
    const int m0 = blockIdx.y * 128, n0 = blockIdx.x * 128;
    const int b = b_base + (m0 >> 10), l0 = m0 & 1023;
    if (t < 130) {
        int l = l0 + t - 1;
        toks[t] = (l >= 0 && l < LPN) ? seq[b * LPN + l] : -1;
    }
    const int w = t >> 6, lane = t & 63;
    const int wm = (w & 3) * 32, wn = (w >> 2) * 64;
    const int quad = lane >> 4, l16 = lane & 15;
    const int r0 = t >> 2, s0 = t & 3, g0 = (s0 ^ (r0 & 3)) * 8;
    const int fso = (quad ^ (l16 & 3)) * 8;
    floatx4 acc[2][4] = {};
    __syncthreads();
    for (int k0 = 0; k0 < 768; k0 += 32) {
        int dl = k0 >> 8, c0 = k0 & 255;
        int tok0 = toks[r0 + dl];
        const __bf16* ga0 = (tok0 >= 0) ? embb + (size_t)tok0 * HID + c0 + g0 : zrow + g0;
        gl2lds16(ga0, &As[r0][s0 * 8]);
        gl2lds16(wtb + (size_t)(n0 + r0) * 768 + k0 + g0, &Bs[r0][s0 * 8]);
        __syncthreads();
        bf16x8 af[2], bfr[4];
#pragma unroll
        for (int mi = 0; mi < 2; mi++) af[mi]  = *(const bf16x8*)&As[wm + mi * 16 + l16][fso];
#pragma unroll
        for (int nj = 0; nj < 4; nj++) bfr[nj] = *(const bf16x8*)&Bs[wn + nj * 16 + l16][fso];
#pragma unroll
        for (int mi = 0; mi < 2; mi++)
#pragma unroll
            for (int nj = 0; nj < 4; nj++)
                acc[mi][nj] = __builtin_amdgcn_mfma_f32_16x16x32_bf16(af[mi], bfr[nj], acc[mi][nj], 0, 0, 0);
        __syncthreads();
    }
#pragma unroll
    for (int mi = 0; mi < 2; mi++)
#pragma unroll
        for (int nj = 0; nj < 4; nj++) {
            int col = n0 + wn + nj * 16 + l16;
            float bval = bias[col];
#pragma unroll
            for (int r = 0; r < 4; r++) {
                int row = m0 + wm + mi * 16 + quad * 4 + r;
                float v = fmaxf(acc[mi][nj][r] + bval, 0.f);
                C[(size_t)row * 256 + col] = (__bf16)v;
            }
        }
}

// ---------------- single fused conversion kernel ----------------
struct Segs {
    const float* src[12];
    __bf16* dst[12];
    int kdim[12];
    int ndim[12];
    int mode[12];          // 0 copy, 1 transpose, 2 conv-weight
    int start[13];
};

__global__ void cvtall_k(Segs S, int total)
{
    int i = blockIdx.x * 256 + threadIdx.x;
    if (i >= total) return;
    int s = 0;
    while (i >= S.start[s + 1]) s++;
    int j = i - S.start[s];
    if (S.mode[s] == 0) {
        S.dst[s][j] = (__bf16)S.src[s][j];
    } else if (S.mode[s] == 1) {
        int K = S.kdim[s], N = S.ndim[s];
        int n = j / K, k = j - n * K;
        S.dst[s][j] = (__bf16)S.src[s][(size_t)k * N + n];
    } else {
        int n = j / 768, r = j - n * 768;
        int dl = r >> 8, kk = r & 255;
        S.dst[s][j] = (__bf16)S.src[s][(size_t)n * 768 + kk * 3 + dl];
    }
}

// ---------------- CSR build ----------------
__global__ void deg_k(const int* __restrict__ ei, int* __restrict__ deg)
{
    int e = blockIdx.x * 256 + threadIdx.x;
    if (e < NED) atomicAdd(&deg[ei[NED + e]], 1);
}

__global__ __launch_bounds__(256) void scan_k(const int* __restrict__ deg, int* __restrict__ rowptr)
{
    __shared__ int part[256];
    int t = threadIdx.x;
    int base = t * 64;
    int s = 0;
#pragma unroll
    for (int i = 0; i < 64; i++) s += deg[base + i];
    part[t] = s;
    __syncthreads();
    for (int off = 1; off < 256; off <<= 1) {
        int v = (t >= off) ? part[t - off] : 0;
        __syncthreads();
        part[t] += v;
        __syncthreads();
    }
    int run = t ? part[t - 1] : 0;
    for (int i = 0; i < 64; i++) { rowptr[base + i] = run; run += deg[base + i]; }
    if (t == 255) rowptr[16384] = run;
}

__global__ void scat_k(const int* __restrict__ ei, int* __restrict__ fill,
                       const int* __restrict__ rowptr, int* __restrict__ csrc)
{
    int e = blockIdx.x * 256 + threadIdx.x;
    if (e >= NED) return;
    int d = ei[NED + e];
    int pos = rowptr[d] + atomicAdd(&fill[d], 1);
    csrc[pos] = ei[e];
}

// ---------------- fused GAT aggregation (bf16 features) ----------------
__global__ __launch_bounds__(256) void gat_agg(const int* __restrict__ rowptr,
    const int* __restrict__ csrc, const __bf16* __restrict__ hgb,
    const float* __restrict__ a_s, const float* __restrict__ a_d,
    const float* __restrict__ bias, float* __restrict__ out, __bf16* __restrict__ outb)
{
    const int wave = threadIdx.x >> 6, lane = threadIdx.x & 63;
    const int d = blockIdx.x * 4 + wave;
    const int beg = rowptr[d], end = rowptr[d + 1];
    const float ad0 = a_d[d * 2 + 0], ad1 = a_d[d * 2 + 1];
    float e0 = a_s[d * 2 + 0] + ad0; e0 = (e0 > 0.f) ? e0 : 0.2f * e0;
    float e1 = a_s[d * 2 + 1] + ad1; e1 = (e1 > 0.f) ? e1 : 0.2f * e1;
    float m0 = e0, m1 = e1;
    for (int p = beg; p < end; p++) {
        int s = csrc[p];
        float v0 = a_s[s * 2 + 0] + ad0; v0 = (v0 > 0.f) ? v0 : 0.2f * v0;
        float v1 = a_s[s * 2 + 1] + ad1; v1 = (v1 > 0.f) ? v1 : 0.2f * v1;
        m0 = fmaxf(m0, v0); m1 = fmaxf(m1, v1);
    }
    float den0 = __expf(e0 - m0), den1 = __expf(e1 - m1);
    for (int p = beg; p < end; p++) {
        int s = csrc[p];
        float v0 = a_s[s * 2 + 0] + ad0; v0 = (v0 > 0.f) ? v0 : 0.2f * v0;
        float v1 = a_s[s * 2 + 1] + ad1; v1 = (v1 > 0.f) ? v1 : 0.2f * v1;
        den0 += __expf(v0 - m0); den1 += __expf(v1 - m1);
    }
    const float inv0 = 1.f / den0, inv1 = 1.f / den1;
    const int ch = lane * 8;
    const int g = ch >> 8;
    const float mg = g ? m1 : m0, invg = g ? inv1 : inv0, adg = g ? ad1 : ad0;
    float acc[8] = {};
    {
        float al = __expf((g ? e1 : e0) - mg) * invg;
        bf16x8 hv = *(const bf16x8*)(hgb + (size_t)d * 512 + ch);
#pragma unroll
        for (int j = 0; j < 8; j++) acc[j] += (float)hv[j] * al;
    }
    for (int p = beg; p < end; p++) {
        int s = csrc[p];
        float v = a_s[s * 2 + g] + adg; v = (v > 0.f) ? v : 0.2f * v;
        float al = __expf(v - mg) * invg;
        bf16x8 hv = *(const bf16x8*)(hgb + (size_t)s * 512 + ch);
#pragma unroll
        for (int j = 0; j < 8; j++) acc[j] += (float)hv[j] * al;
    }
    float other[8];
#pragma unroll
    for (int j = 0; j < 8; j++) other[j] = __shfl_xor(acc[j], 32, 64);
    if (lane < 32) {
#pragma unroll
        for (int j = 0; j < 8; j++) {
            float v = 0.5f * (acc[j] + other[j]) + bias[ch + j];
            v = (v > 0.f) ? v : expm1f(v);
            if (out) out[(size_t)d * 256 + ch + j] = v;
            outb[(size_t)d * 256 + ch + j] = (__bf16)v;
        }
    }
}

// ---------------- MFMA flash cross-attention ----------------
__global__ __launch_bounds__(256) void attn2_k(const __bf16* __restrict__ Qb,
    const __bf16* __restrict__ Kb, const __bf16* __restrict__ Vtb,
    const int* __restrict__ seq, __bf16* __restrict__ O, int b0, int ldV)
{
    __shared__ __bf16 Ps[4][16][72];
    __shared__ float mask_s[LPN];
    const int t = threadIdx.x;
    const int bl = blockIdx.x >> 2, h = blockIdx.x & 3;
    const int b = b0 + bl;
    const int w = t >> 6, lane = t & 63;
    const int quad = lane >> 4, l16 = lane & 15;
    for (int i = t; i < LPN; i += 256)
        mask_s[i] = (seq[b * LPN + i] == 0) ? -1e9f : 0.f;
    const __bf16* qrow = Qb + (size_t)(b * 64 + w * 16 + l16) * HID + h * HD;
    bf16x8 aq0 = *(const bf16x8*)(qrow + quad * 8);
    bf16x8 aq1 = *(const bf16x8*)(qrow + 32 + quad * 8);
    float m_run[4] = {-3e38f, -3e38f, -3e38f, -3e38f};
    float l_run[4] = {0.f, 0.f, 0.f, 0.f};
    floatx4 ctx[4] = {};
    __syncthreads();
    for (int kp0 = 0; kp0 < LPN; kp0 += 64) {
        floatx4 s[4];
#pragma unroll
        for (int nj = 0; nj < 4; nj++) {
            const __bf16* krow = Kb + (size_t)(bl * LPN + kp0 + nj * 16 + l16) * HID + h * HD;
            bf16x8 bk0 = *(const bf16x8*)(krow + quad * 8);
            bf16x8 bk1 = *(const bf16x8*)(krow + 32 + quad * 8);
            floatx4 z = {0.f, 0.f, 0.f, 0.f};
            s[nj] = __builtin_amdgcn_mfma_f32_16x16x32_bf16(aq0, bk0, z, 0, 0, 0);
            s[nj] = __builtin_amdgcn_mfma_f32_16x16x32_bf16(aq1, bk1, s[nj], 0, 0, 0);
        }
#pragma unroll
        for (int nj = 0; nj < 4; nj++) {
            float mval = mask_s[kp0 + nj * 16 + l16];
#pragma unroll
            for (int r = 0; r < 4; r++) s[nj][r] += mval;
        }
        float alpha[4];
#pragma unroll
        for (int r = 0; r < 4; r++) {
            float mx = fmaxf(fmaxf(s[0][r], s[1][r]), fmaxf(s[2][r], s[3][r]));
#pragma unroll
            for (int off = 1; off < 16; off <<= 1) mx = fmaxf(mx, __shfl_xor(mx, off, 64));
            float mn = fmaxf(m_run[r], mx);
            alpha[r] = __expf(m_run[r] - mn);
            m_run[r] = mn;
            float rs = 0.f;
#pragma unroll
            for (int nj = 0; nj < 4; nj++) {
                float p = __expf(s[nj][r] - mn);
                s[nj][r] = p;
                rs += p;
            }
#pragma unroll
            for (int off = 1; off < 16; off <<= 1) rs += __shfl_xor(rs, off, 64);
            l_run[r] = l_run[r] * alpha[r] + rs;
        }
#pragma unroll
        for (int nj = 0; nj < 4; nj++)
#pragma unroll
            for (int r = 0; r < 4; r++)
                Ps[w][quad * 4 + r][nj * 16 + l16] = (__bf16)s[nj][r];
        bf16x8 pa0 = *(const bf16x8*)&Ps[w][l16][quad * 8];
        bf16x8 pa1 = *(const bf16x8*)&Ps[w][l16][32 + quad * 8];
#pragma unroll
        for (int dj = 0; dj < 4; dj++) {
#pragma unroll
            for (int r = 0; r < 4; r++) ctx[dj][r] *= alpha[r];
            const __bf16* vrow = Vtb + (size_t)(h * HD + dj * 16 + l16) * ldV + bl * LPN + kp0;
            bf16x8 bv0 = *(const bf16x8*)(vrow + quad * 8);
            bf16x8 bv1 = *(const bf16x8*)(vrow + 32 + quad * 8);
            ctx[dj] = __builtin_amdgcn_mfma_f32_16x16x32_bf16(pa0, bv0, ctx[dj], 0, 0, 0);
            ctx[dj] = __builtin_amdgcn_mfma_f32_16x16x32_bf16(pa1, bv1, ctx[dj], 0, 0, 0);
        }
    }
#pragma unroll
    for (int dj = 0; dj < 4; dj++)
#pragma unroll
        for (int r = 0; r < 4; r++) {
            int q = b * 64 + w * 16 + quad * 4 + r;
            int d = h * HD + dj * 16 + l16;
            O[(size_t)q * HID + d] = (__bf16)(ctx[dj][r] / l_run[r]);
        }
}

// ---------------- LayerNorm(residual) ----------------
__device__ __forceinline__ float blockSum256(float v, float* red)
{
#pragma unroll
    for (int off = 32; off >= 1; off >>= 1) v += __shfl_down(v, off, 64);
    int wave = threadIdx.x >> 6, lane = threadIdx.x & 63;
    if (lane == 0) red[wave] = v;
    __syncthreads();
    float s = red[0] + red[1] + red[2] + red[3];
    __syncthreads();
    return s;
}

__global__ __launch_bounds__(256) void lnres_k(const float* __restrict__ A,
    const float* __restrict__ Bb, const float* __restrict__ g,
    const float* __restrict__ be, float* __restrict__ Y, __bf16* __restrict__ Yb)
{
    __shared__ float red[4];
    int r = blockIdx.x, t = threadIdx.x;
    float v = A[(size_t)r * 256 + t] + Bb[(size_t)r * 256 + t];
    float mean = blockSum256(v, red) * (1.f / 256.f);
    float d = v - mean;
    float var = blockSum256(d * d, red) * (1.f / 256.f);
    float o = d * rsqrtf(var + 1e-5f) * g[t] + be[t];
    Y[(size_t)r * 256 + t] = o;
    if (Yb) Yb[(size_t)r * 256 + t] = (__bf16)o;
}

// ---------------- fused head: mean-pool + fc1(relu) + fc2 ----------------
__global__ __launch_bounds__(256) void head_k(const float* __restrict__ Y,
    const float* __restrict__ fc1w, const float* __restrict__ fc1b,
    const float* __restrict__ fc2w, const float* __restrict__ fc2b,
    float* __restrict__ out)
{
    __shared__ float pooled[256];
    __shared__ float h[256];
    __shared__ float red[4];
    int b = blockIdx.x, t = threadIdx.x;
    float s = 0.f;
#pragma unroll 8
    for (int q = 0; q < 64; q++) s += Y[(size_t)(b * 64 + q) * 256 + t];
    pooled[t] = s / (64.f + 1e-6f);
    __syncthreads();
    float a = 0.f;
    for (int k = 0; k < 256; k += 4) {
        a += pooled[k + 0] * fc1w[(k + 0) * 256 + t];
        a += pooled[k + 1] * fc1w[(k + 1) * 256 + t];
        a += pooled[k + 2] * fc1w[(k + 2) * 256 + t];
        a += pooled[k + 3] * fc1w[(k + 3) * 256 + t];
    }
    h[t] = fmaxf(a + fc1b[t], 0.f);
    __syncthreads();
    float p = h[t] * fc2w[t];
    p = blockSum256(p, red);
    if (t == 0) out[b] = p + fc2b[0];
}

// ---------------- launch ----------------
extern "C" void kernel_launch(void* const* d_in, const int* in_sizes, int n_in,
                              void* d_out, int out_size, void* d_ws, size_t ws_size,
                              hipStream_t stream)
{
    const float* x     = (const float*)d_in[0];
    const int*   ei    = (const int*)d_in[1];
    const int*   pseq  = (const int*)d_in[3];
    const float* w1  = (const float*)d_in[4];
    const float* as1 = (const float*)d_in[5];
    const float* ad1 = (const float*)d_in[6];
    const float* b1  = (const float*)d_in[7];
    const float* w2  = (const float*)d_in[8];
    const float* as2 = (const float*)d_in[9];
    const float* ad2 = (const float*)d_in[10];
    const float* b2  = (const float*)d_in[11];
    const float* w3  = (const float*)d_in[12];
    const float* as3 = (const float*)d_in[13];
    const float* ad3 = (const float*)d_in[14];
    const float* b3  = (const float*)d_in[15];
    const float* emb    = (const float*)d_in[16];
    const float* conv_w = (const float*)d_in[17];
    const float* conv_b = (const float*)d_in[18];
    const float* wq = (const float*)d_in[19];
    const float* bq = (const float*)d_in[20];
    const float* wk = (const float*)d_in[21];
    const float* bk = (const float*)d_in[22];
    const float* wv = (const float*)d_in[23];
    const float* bv = (const float*)d_in[24];
    const float* wo = (const float*)d_in[25];
    const float* bo = (const float*)d_in[26];
    const float* ln1_g = (const float*)d_in[27];
    const float* ln1_b = (const float*)d_in[28];
    const float* ffw1  = (const float*)d_in[29];
    const float* ffb1  = (const float*)d_in[30];
    const float* ffw2  = (const float*)d_in[31];
    const float* ffb2  = (const float*)d_in[32];
    const float* ln2_g = (const float*)d_in[33];
    const float* ln2_b = (const float*)d_in[34];
    const float* fc1_w = (const float*)d_in[35];
    const float* fc1_b = (const float*)d_in[36];
    const float* fc2_w = (const float*)d_in[37];
    const float* fc2_b = (const float*)d_in[38];
    (void)in_sizes; (void)n_in; (void)out_size;

    char* ws = (char*)d_ws;
    size_t off = 0;
    auto alloc = [&](size_t bytes) -> char* {
        char* p = ws + off;
        off += (bytes + 255) & ~(size_t)255;
        return p;
    };
    // ---- fixed arena ----
    __bf16* hgb  = (__bf16*)alloc((size_t)NAT * 512 * 2);
    float* og    = (float*)alloc((size_t)NAT * 512 * 4);
    float* hb0   = (float*)alloc((size_t)NAT * 256 * 4);
    float* hb1   = (float*)alloc((size_t)NAT * 256 * 4);
    __bf16* xb   = (__bf16*)alloc((size_t)NAT * FIN * 2);
    __bf16* hbb  = (__bf16*)alloc((size_t)NAT * 256 * 2);
    __bf16* qbb  = (__bf16*)alloc((size_t)NAT * 256 * 2);
    __bf16* ctxbb= (__bf16*)alloc((size_t)NAT * 256 * 2);
    __bf16* ybb  = (__bf16*)alloc((size_t)NAT * 256 * 2);
    float* a_s   = (float*)alloc((size_t)NAT * 2 * 4);
    float* a_d   = (float*)alloc((size_t)NAT * 2 * 4);
    float* asd_p = (float*)alloc((size_t)16 * NAT * 4);
    int* deg     = (int*)alloc((size_t)NAT * 4);
    int* fill    = (int*)alloc((size_t)NAT * 4);
    int* rowptr  = (int*)alloc((size_t)(NAT + 1) * 4);
    int* csrc    = (int*)alloc((size_t)NED * 4);
    __bf16* embb = (__bf16*)alloc((size_t)22 * 256 * 2);
    __bf16* wtb  = (__bf16*)alloc((size_t)256 * 768 * 2);
    __bf16* zpad = (__bf16*)alloc(256);
    __bf16* w1T  = (__bf16*)alloc((size_t)512 * 64 * 2);
    __bf16* w2T  = (__bf16*)alloc((size_t)512 * 256 * 2);
    __bf16* w3T  = (__bf16*)alloc((size_t)512 * 256 * 2);
    __bf16* wkT  = (__bf16*)alloc((size_t)256 * 256 * 2);
    __bf16* wvT  = (__bf16*)alloc((size_t)256 * 256 * 2);
    __bf16* wqT  = (__bf16*)alloc((size_t)256 * 256 * 2);
    __bf16* woT  = (__bf16*)alloc((size_t)256 * 256 * 2);
    __bf16* f1T  = (__bf16*)alloc((size_t)1024 * 256 * 2);
    __bf16* f2T  = (__bf16*)alloc((size_t)256 * 1024 * 2);
    // ---- variable region ----
    size_t fixed_end = off;
    size_t rem = (ws_size > fixed_end) ? ws_size - fixed_end : 0;
    const size_t G1 = (size_t)LPN * 256 * 2;
    const size_t ffneed = (size_t)NAT * 1024 * 2 + (size_t)NAT * 256 * 4;
    int CB = 8;
    {
        const int cands[6] = {256, 128, 64, 32, 16, 8};
        for (int ci = 0; ci < 6; ci++) {
            size_t regneed = 3 * (size_t)cands[ci] * G1;
            if (regneed < ffneed) regneed = ffneed;
            if (regneed <= rem) { CB = cands[ci]; break; }
        }
    }
    char* region   = ws + fixed_end;
    __bf16* pconvb = (__bf16*)region;
    __bf16* kbb    = (__bf16*)(region + (size_t)CB * G1);
    __bf16* vtb    = (__bf16*)(region + 2 * (size_t)CB * G1);
    __bf16* ffbb   = (__bf16*)region;
    float*  y2     = (float*)(region + (size_t)NAT * 1024 * 2);
    float* attno = og;
    float* ybuf  = og + (size_t)NAT * 256;
    float* ff2o  = hb1;

    // ---------------- CSR build + zero page ----------------
    hipMemsetAsync(deg, 0, (size_t)NAT * 8, stream);   // deg + fill (adjacent)
    hipMemsetAsync(zpad, 0, 256, stream);
    deg_k<<<NED / 256, 256, 0, stream>>>(ei, deg);
    scan_k<<<1, 256, 0, stream>>>(deg, rowptr);
    scat_k<<<NED / 256, 256, 0, stream>>>(ei, fill, rowptr, csrc);

    // ---------------- all conversions in one dispatch ----------------
    {
        Segs S;
        const float* srcs[12] = {x, emb, conv_w, w1, w2, w3, wk, wv, wq, wo, ffw1, ffw2};
        __bf16* dsts[12] = {xb, embb, wtb, w1T, w2T, w3T, wkT, wvT, wqT, woT, f1T, f2T};
        int kd[12] = {0, 0, 0, 64, 256, 256, 256, 256, 256, 256, 256, 1024};
        int nd[12] = {0, 0, 0, 512, 512, 512, 256, 256, 256, 256, 1024, 256};
        int md[12] = {0, 0, 2, 1, 1, 1, 1, 1, 1, 1, 1, 1};
        int cnt[12] = {NAT * FIN, 22 * 256, 196608, 32768, 131072, 131072,
                       65536, 65536, 65536, 65536, 262144, 262144};
        int run = 0;
        for (int i = 0; i < 12; i++) {
            S.src[i] = srcs[i]; S.dst[i] = dsts[i];
            S.kdim[i] = kd[i]; S.ndim[i] = nd[i]; S.mode[i] = md[i];
            S.start[i] = run; run += cnt[i];
        }
        S.start[12] = run;
        cvtall_k<<<(run + 255) / 256, 256, 0, stream>>>(S, run);
    }

    // ---------------- ligand GNN: 3 GAT layers ----------------
    const __bf16* WT[3] = {w1T, w2T, w3T};
    const float* asl[3] = {as1, as2, as3};
    const float* adl[3] = {ad1, ad2, ad3};
    const float* bl[3]  = {b1, b2, b3};
    float* houts[3] = {nullptr, nullptr, hb0};
    const __bf16* hinb = xb;
    int Kdim = FIN;
    for (int l = 0; l < 3; l++) {
        gemm_gat<<<dim3(4, NAT / 128), 512, 0, stream>>>(hinb, WT[l], asl[l], adl[l], hgb, asd_p, Kdim);
        fold_k<<<NAT / 256, 256, 0, stream>>>(asd_p, a_s, a_d);
        gat_agg<<<NAT / 4, 256, 0, stream>>>(rowptr, csrc, hgb, a_s, a_d, bl[l], houts[l], hbb);
        hinb = hbb;
        Kdim = HID;
    }
    const float* lig = hb0;
    const __bf16* ligb = hbb;

    // ---------------- Q projection (scale 1/8 folded in) ----------------
    gemm_mfma<0, 1, 0><<<dim3(2, NAT / 128), 512, 0, stream>>>(ligb, wqT, bq, qbb, NAT, 256, 256, 0.125f);

    // ---------------- protein branch + attention, chunked over graphs ----------
    for (int b0 = 0; b0 < BGR; b0 += CB) {
        int Mc = CB * LPN;
        conv_mfma<<<dim3(2, Mc / 128), 512, 0, stream>>>(pseq, embb, wtb, conv_b, pconvb, b0, zpad);
        kv_mfma<<<dim3(Mc / 128, 2, 2), 512, 0, stream>>>(pconvb, wkT, wvT, bk, bv, kbb, vtb, Mc);
        attn2_k<<<CB * 4, 256, 0, stream>>>(qbb, kbb, vtb, pseq, ctxbb, b0, Mc);
    }

    // ---------------- attention out proj + LN + FFN + LN ----------------
    gemm_mfma<0, 0, 0><<<dim3(2, NAT / 128), 512, 0, stream>>>(ctxbb, woT, bo, attno, NAT, 256, 256, 1.f);
    lnres_k<<<NAT, 256, 0, stream>>>(lig, attno, ln1_g, ln1_b, ybuf, ybb);
    gemm_mfma<2, 1, 0><<<dim3(8, NAT / 128), 512, 0, stream>>>(ybb, f1T, ffb1, ffbb, NAT, 1024, 256, 1.f);
    gemm_mfma<0, 0, 0><<<dim3(2, NAT / 128), 512, 0, stream>>>(ffbb, f2T, ffb2, ff2o, NAT, 256, 1024, 1.f);
    lnres_k<<<NAT, 256, 0, stream>>>(ybuf, ff2o, ln2_g, ln2_b, y2, nullptr);

    // ---------------- fused head ----------------
    head_k<<<BGR, 256, 0, stream>>>(y2, fc1_w, fc1_b, fc2_w, fc2_b, (float*)d_out);
}

// Round 9
// 893.536 us; speedup vs baseline: 5.0817x; 1.0534x over previous
//
#include <hip/hip_runtime.h>
#include <hip/hip_bf16.h>
#include <cstdint>
#include <cstddef>

#define NAT 16384
#define NED 65536
#define BGR 256
#define FIN 64
#define HID 256
#define LPN 1024
#define HD 64

typedef __bf16 bf16x8 __attribute__((ext_vector_type(8)));
typedef float floatx4 __attribute__((ext_vector_type(4)));

// async global->LDS 16B; dest = wave-uniform base + lane*16 (linear layout!)
__device__ __forceinline__ void gl2lds16(const void* g, void* l)
{
    __builtin_amdgcn_global_load_lds(
        (const __attribute__((address_space(1))) unsigned int*)g,
        (__attribute__((address_space(3))) unsigned int*)l, 16, 0, 0);
}

// ---------------- bf16 MFMA GEMM, 8-wave (512t) 128x128 tile ----------------
template<int ACT, int OUTBF16, int BIASROW>
__global__ __launch_bounds__(512) void gemm_mfma(const __bf16* __restrict__ A,
    const __bf16* __restrict__ Bt, const float* __restrict__ bias,
    void* __restrict__ Cout, int M, int Nn, int K, float escale)
{
    __shared__ __bf16 As[128][32];
    __shared__ __bf16 Bs[128][32];
    const int t = threadIdx.x;
    const int m0 = blockIdx.y * 128, n0 = blockIdx.x * 128;
    const int w = t >> 6, lane = t & 63;
    const int wm = (w & 3) * 32, wn = (w >> 2) * 64;
    const int quad = lane >> 4, l16 = lane & 15;
    const int r0 = t >> 2, s0 = t & 3, g0 = (s0 ^ (r0 & 3)) * 8;
    const int fso = (quad ^ (l16 & 3)) * 8;
    floatx4 acc[2][4] = {};
    for (int k0 = 0; k0 < K; k0 += 32) {
        gl2lds16(A + (size_t)(m0 + r0) * K + k0 + g0, &As[r0][s0 * 8]);
        gl2lds16(Bt + (size_t)(n0 + r0) * K + k0 + g0, &Bs[r0][s0 * 8]);
        __syncthreads();
        bf16x8 af[2], bfr[4];
#pragma unroll
        for (int mi = 0; mi < 2; mi++) af[mi]  = *(const bf16x8*)&As[wm + mi * 16 + l16][fso];
#pragma unroll
        for (int nj = 0; nj < 4; nj++) bfr[nj] = *(const bf16x8*)&Bs[wn + nj * 16 + l16][fso];
#pragma unroll
        for (int mi = 0; mi < 2; mi++)
#pragma unroll
            for (int nj = 0; nj < 4; nj++)
                acc[mi][nj] = __builtin_amdgcn_mfma_f32_16x16x32_bf16(af[mi], bfr[nj], acc[mi][nj], 0, 0, 0);
        __syncthreads();
    }
#pragma unroll
    for (int mi = 0; mi < 2; mi++)
#pragma unroll
        for (int nj = 0; nj < 4; nj++) {
            int col = n0 + wn + nj * 16 + l16;
#pragma unroll
            for (int r = 0; r < 4; r++) {
                int row = m0 + wm + mi * 16 + quad * 4 + r;
                float bval = bias ? (BIASROW ? bias[row] : bias[col]) : 0.f;
                float v = (acc[mi][nj][r] + bval) * escale;
                if (ACT == 1) v = fmaxf(v, 0.f);
                if (ACT == 2) v = 0.5f * v * (1.f + erff(v * 0.70710678118654752f));
                if (OUTBF16) ((__bf16*)Cout)[(size_t)row * Nn + col] = (__bf16)v;
                else         ((float*)Cout)[(size_t)row * Nn + col] = v;
            }
        }
}

// ---------------- merged K-proj + V^T-proj (z selects), 8-wave ----------------
__global__ __launch_bounds__(512) void kv_mfma(const __bf16* __restrict__ pconv,
    const __bf16* __restrict__ wkT, const __bf16* __restrict__ wvT,
    const float* __restrict__ bk, const float* __restrict__ bv,
    __bf16* __restrict__ kbb, __bf16* __restrict__ vtb, int Mc)
{
    __shared__ __bf16 As[128][32];
    __shared__ __bf16 Bs[128][32];
    const int t = threadIdx.x;
    const int z = blockIdx.z;
    const int m0 = z ? blockIdx.y * 128 : blockIdx.x * 128;
    const int n0 = z ? blockIdx.x * 128 : blockIdx.y * 128;
    const __bf16* A  = z ? wvT   : pconv;
    const __bf16* Bt = z ? pconv : wkT;
    const int Nn = z ? Mc : 256;
    const int w = t >> 6, lane = t & 63;
    const int wm = (w & 3) * 32, wn = (w >> 2) * 64;
    const int quad = lane >> 4, l16 = lane & 15;
    const int r0 = t >> 2, s0 = t & 3, g0 = (s0 ^ (r0 & 3)) * 8;
    const int fso = (quad ^ (l16 & 3)) * 8;
    floatx4 acc[2][4] = {};
    for (int k0 = 0; k0 < 256; k0 += 32) {
        gl2lds16(A + (size_t)(m0 + r0) * 256 + k0 + g0, &As[r0][s0 * 8]);
        gl2lds16(Bt + (size_t)(n0 + r0) * 256 + k0 + g0, &Bs[r0][s0 * 8]);
        __syncthreads();
        bf16x8 af[2], bfr[4];
#pragma unroll
        for (int mi = 0; mi < 2; mi++) af[mi]  = *(const bf16x8*)&As[wm + mi * 16 + l16][fso];
#pragma unroll
        for (int nj = 0; nj < 4; nj++) bfr[nj] = *(const bf16x8*)&Bs[wn + nj * 16 + l16][fso];
#pragma unroll
        for (int mi = 0; mi < 2; mi++)
#pragma unroll
            for (int nj = 0; nj < 4; nj++)
                acc[mi][nj] = __builtin_amdgcn_mfma_f32_16x16x32_bf16(af[mi], bfr[nj], acc[mi][nj], 0, 0, 0);
        __syncthreads();
    }
    __bf16* out = z ? vtb : kbb;
#pragma unroll
    for (int mi = 0; mi < 2; mi++)
#pragma unroll
        for (int nj = 0; nj < 4; nj++) {
            int col = n0 + wn + nj * 16 + l16;
#pragma unroll
            for (int r = 0; r < 4; r++) {
                int row = m0 + wm + mi * 16 + quad * 4 + r;
                float bval = z ? bv[row] : bk[col];
                out[(size_t)row * Nn + col] = (__bf16)(acc[mi][nj][r] + bval);
            }
        }
}

// ---------------- GAT feature GEMM, 8-wave: bf16 hg + partial a_s/a_d --------
__global__ __launch_bounds__(512) void gemm_gat(const __bf16* __restrict__ A,
    const __bf16* __restrict__ Bt, const float* __restrict__ as_f,
    const float* __restrict__ ad_f, __bf16* __restrict__ Hg,
    float* __restrict__ part, int K)
{
    __shared__ __bf16 As[128][32];
    __shared__ __bf16 Bs[128][32];
    const int t = threadIdx.x;
    const int m0 = blockIdx.y * 128, n0 = blockIdx.x * 128;
    const int w = t >> 6, lane = t & 63;
    const int wm = (w & 3) * 32, wn = (w >> 2) * 64;
    const int quad = lane >> 4, l16 = lane & 15;
    const int r0 = t >> 2, s0 = t & 3, g0 = (s0 ^ (r0 & 3)) * 8;
    const int fso = (quad ^ (l16 & 3)) * 8;
    floatx4 acc[2][4] = {};
    for (int k0 = 0; k0 < K; k0 += 32) {
        gl2lds16(A + (size_t)(m0 + r0) * K + k0 + g0, &As[r0][s0 * 8]);
        gl2lds16(Bt + (size_t)(n0 + r0) * K + k0 + g0, &Bs[r0][s0 * 8]);
        __syncthreads();
        bf16x8 af[2], bfr[4];
#pragma unroll
        for (int mi = 0; mi < 2; mi++) af[mi]  = *(const bf16x8*)&As[wm + mi * 16 + l16][fso];
#pragma unroll
        for (int nj = 0; nj < 4; nj++) bfr[nj] = *(const bf16x8*)&Bs[wn + nj * 16 + l16][fso];
#pragma unroll
        for (int mi = 0; mi < 2; mi++)
#pragma unroll
            for (int nj = 0; nj < 4; nj++)
                acc[mi][nj] = __builtin_amdgcn_mfma_f32_16x16x32_bf16(af[mi], bfr[nj], acc[mi][nj], 0, 0, 0);
        __syncthreads();
    }
    const int slot = blockIdx.x * 2 + (w >> 2);
#pragma unroll
    for (int mi = 0; mi < 2; mi++) {
#pragma unroll
        for (int r = 0; r < 4; r++) {
            float ps = 0.f, pd = 0.f;
#pragma unroll
            for (int nj = 0; nj < 4; nj++) {
                int col = n0 + wn + nj * 16 + l16;
                float v = acc[mi][nj][r];
                ps += v * as_f[col];
                pd += v * ad_f[col];
            }
#pragma unroll
            for (int off = 1; off < 16; off <<= 1) {
                ps += __shfl_xor(ps, off, 64);
                pd += __shfl_xor(pd, off, 64);
            }
            if (l16 == 0) {
                int row = m0 + wm + mi * 16 + quad * 4 + r;
                part[(size_t)(slot * 2 + 0) * NAT + row] = ps;
                part[(size_t)(slot * 2 + 1) * NAT + row] = pd;
            }
        }
    }
#pragma unroll
    for (int mi = 0; mi < 2; mi++)
#pragma unroll
        for (int nj = 0; nj < 4; nj++) {
            int col = n0 + wn + nj * 16 + l16;
#pragma unroll
            for (int r = 0; r < 4; r++) {
                int row = m0 + wm + mi * 16 + quad * 4 + r;
                Hg[(size_t)row * 512 + col] = (__bf16)acc[mi][nj][r];
            }
        }
}

// fold 8 column-partials into a_s/a_d
__global__ void fold_k(const float* __restrict__ part, float* __restrict__ a_s,
                       float* __restrict__ a_d)
{
    int n = blockIdx.x * 256 + threadIdx.x;
    float s0 = 0.f, d0 = 0.f, s1 = 0.f, d1 = 0.f;
#pragma unroll
    for (int sl = 0; sl < 4; sl++) {
        s0 += part[(size_t)(sl * 2 + 0) * NAT + n];
        d0 += part[(size_t)(sl * 2 + 1) * NAT + n];
        s1 += part[(size_t)((sl + 4) * 2 + 0) * NAT + n];
        d1 += part[(size_t)((sl + 4) * 2 + 1) * NAT + n];
    }
    a_s[n * 2 + 0] = s0; a_s[n * 2 + 1] = s1;
    a_d[n * 2 + 0] = d0; a_d[n * 2 + 1] = d1;
}

// ---------------- conv1d implicit GEMM, 8-wave, fused embed gather ------------
__global__ __launch_bounds__(512) void conv_mfma(const int* __restrict__ seq,
    const __bf16* __restrict__ embb, const __bf16* __restrict__ wtb,
    const float* __restrict__ bias, __bf16* __restrict__ C, int b_base,
    const __bf16* __restrict__ zrow)
{
    __shared__ __bf16 As[128][32];
    __shared__ __bf16 Bs[128][32];
    __shared__ int toks[130];
    const int t = threadIdx.x;
    const int m0 = blockIdx.y * 128, n0 = blockIdx.x * 128;
    const int b = b_base + (m0 >> 10), l0 = m0 & 1023;
    if (t < 130) {
        int l = l0 + t - 1;
        toks[t] = (l >= 0 && l < LPN) ? seq[b * LPN + l] : -1;
    }
    const int w = t >> 6, lane = t & 63;
    const int wm = (w & 3) * 32, wn = (w >> 2) * 64;
    const int quad = lane >> 4, l16 = lane & 15;
    const int r0 = t >> 2, s0 = t & 3, g0 = (s0 ^ (r0 & 3)) * 8;
    const int fso = (quad ^ (l16 & 3)) * 8;
    floatx4 acc[2][4] = {};
    __syncthreads();
    for (int k0 = 0; k0 < 768; k0 += 32) {
        int dl = k0 >> 8, c0 = k0 & 255;
        int tok0 = toks[r0 + dl];
        const __bf16* ga0 = (tok0 >= 0) ? embb + (size_t)tok0 * HID + c0 + g0 : zrow + g0;
        gl2lds16(ga0, &As[r0][s0 * 8]);
        gl2lds16(wtb + (size_t)(n0 + r0) * 768 + k0 + g0, &Bs[r0][s0 * 8]);
        __syncthreads();
        bf16x8 af[2], bfr[4];
#pragma unroll
        for (int mi = 0; mi < 2; mi++) af[mi]  = *(const bf16x8*)&As[wm + mi * 16 + l16][fso];
#pragma unroll
        for (int nj = 0; nj < 4; nj++) bfr[nj] = *(const bf16x8*)&Bs[wn + nj * 16 + l16][fso];
#pragma unroll
        for (int mi = 0; mi < 2; mi++)
#pragma unroll
            for (int nj = 0; nj < 4; nj++)
                acc[mi][nj] = __builtin_amdgcn_mfma_f32_16x16x32_bf16(af[mi], bfr[nj], acc[mi][nj], 0, 0, 0);
        __syncthreads();
    }
#pragma unroll
    for (int mi = 0; mi < 2; mi++)
#pragma unroll
        for (int nj = 0; nj < 4; nj++) {
            int col = n0 + wn + nj * 16 + l16;
            float bval = bias[col];
#pragma unroll
            for (int r = 0; r < 4; r++) {
                int row = m0 + wm + mi * 16 + quad * 4 + r;
                float v = fmaxf(acc[mi][nj][r] + bval, 0.f);
                C[(size_t)row * 256 + col] = (__bf16)v;
            }
        }
}

// ---------------- single fused conversion kernel ----------------
struct Segs {
    const float* src[12];
    __bf16* dst[12];
    int kdim[12];
    int ndim[12];
    int mode[12];          // 0 copy, 1 transpose, 2 conv-weight
    int start[13];
};

__global__ void cvtall_k(Segs S, int total)
{
    int i = blockIdx.x * 256 + threadIdx.x;
    if (i >= total) return;
    int s = 0;
    while (i >= S.start[s + 1]) s++;
    int j = i - S.start[s];
    if (S.mode[s] == 0) {
        S.dst[s][j] = (__bf16)S.src[s][j];
    } else if (S.mode[s] == 1) {
        int K = S.kdim[s], N = S.ndim[s];
        int n = j / K, k = j - n * K;
        S.dst[s][j] = (__bf16)S.src[s][(size_t)k * N + n];
    } else {
        int n = j / 768, r = j - n * 768;
        int dl = r >> 8, kk = r & 255;
        S.dst[s][j] = (__bf16)S.src[s][(size_t)n * 768 + kk * 3 + dl];
    }
}

// ---------------- CSR build ----------------
__global__ void deg_k(const int* __restrict__ ei, int* __restrict__ deg)
{
    int e = blockIdx.x * 256 + threadIdx.x;
    if (e < NED) atomicAdd(&deg[ei[NED + e]], 1);
}

__global__ __launch_bounds__(256) void scan_k(const int* __restrict__ deg, int* __restrict__ rowptr)
{
    __shared__ int part[256];
    int t = threadIdx.x;
    int base = t * 64;
    int s = 0;
#pragma unroll
    for (int i = 0; i < 64; i++) s += deg[base + i];
    part[t] = s;
    __syncthreads();
    for (int off = 1; off < 256; off <<= 1) {
        int v = (t >= off) ? part[t - off] : 0;
        __syncthreads();
        part[t] += v;
        __syncthreads();
    }
    int run = t ? part[t - 1] : 0;
    for (int i = 0; i < 64; i++) { rowptr[base + i] = run; run += deg[base + i]; }
    if (t == 255) rowptr[16384] = run;
}

__global__ void scat_k(const int* __restrict__ ei, int* __restrict__ fill,
                       const int* __restrict__ rowptr, int* __restrict__ csrc)
{
    int e = blockIdx.x * 256 + threadIdx.x;
    if (e >= NED) return;
    int d = ei[NED + e];
    int pos = rowptr[d] + atomicAdd(&fill[d], 1);
    csrc[pos] = ei[e];
}

// ---------------- fused GAT aggregation (bf16 features) ----------------
__global__ __launch_bounds__(256) void gat_agg(const int* __restrict__ rowptr,
    const int* __restrict__ csrc, const __bf16* __restrict__ hgb,
    const float* __restrict__ a_s, const float* __restrict__ a_d,
    const float* __restrict__ bias, float* __restrict__ out, __bf16* __restrict__ outb)
{
    const int wave = threadIdx.x >> 6, lane = threadIdx.x & 63;
    const int d = blockIdx.x * 4 + wave;
    const int beg = rowptr[d], end = rowptr[d + 1];
    const float ad0 = a_d[d * 2 + 0], ad1 = a_d[d * 2 + 1];
    float e0 = a_s[d * 2 + 0] + ad0; e0 = (e0 > 0.f) ? e0 : 0.2f * e0;
    float e1 = a_s[d * 2 + 1] + ad1; e1 = (e1 > 0.f) ? e1 : 0.2f * e1;
    float m0 = e0, m1 = e1;
    for (int p = beg; p < end; p++) {
        int s = csrc[p];
        float v0 = a_s[s * 2 + 0] + ad0; v0 = (v0 > 0.f) ? v0 : 0.2f * v0;
        float v1 = a_s[s * 2 + 1] + ad1; v1 = (v1 > 0.f) ? v1 : 0.2f * v1;
        m0 = fmaxf(m0, v0); m1 = fmaxf(m1, v1);
    }
    float den0 = __expf(e0 - m0), den1 = __expf(e1 - m1);
    for (int p = beg; p < end; p++) {
        int s = csrc[p];
        float v0 = a_s[s * 2 + 0] + ad0; v0 = (v0 > 0.f) ? v0 : 0.2f * v0;
        float v1 = a_s[s * 2 + 1] + ad1; v1 = (v1 > 0.f) ? v1 : 0.2f * v1;
        den0 += __expf(v0 - m0); den1 += __expf(v1 - m1);
    }
    const float inv0 = 1.f / den0, inv1 = 1.f / den1;
    const int ch = lane * 8;
    const int g = ch >> 8;
    const float mg = g ? m1 : m0, invg = g ? inv1 : inv0, adg = g ? ad1 : ad0;
    float acc[8] = {};
    {
        float al = __expf((g ? e1 : e0) - mg) * invg;
        bf16x8 hv = *(const bf16x8*)(hgb + (size_t)d * 512 + ch);
#pragma unroll
        for (int j = 0; j < 8; j++) acc[j] += (float)hv[j] * al;
    }
    for (int p = beg; p < end; p++) {
        int s = csrc[p];
        float v = a_s[s * 2 + g] + adg; v = (v > 0.f) ? v : 0.2f * v;
        float al = __expf(v - mg) * invg;
        bf16x8 hv = *(const bf16x8*)(hgb + (size_t)s * 512 + ch);
#pragma unroll
        for (int j = 0; j < 8; j++) acc[j] += (float)hv[j] * al;
    }
    float other[8];
#pragma unroll
    for (int j = 0; j < 8; j++) other[j] = __shfl_xor(acc[j], 32, 64);
    if (lane < 32) {
#pragma unroll
        for (int j = 0; j < 8; j++) {
            float v = 0.5f * (acc[j] + other[j]) + bias[ch + j];
            v = (v > 0.f) ? v : expm1f(v);
            if (out) out[(size_t)d * 256 + ch + j] = v;
            outb[(size_t)d * 256 + ch + j] = (__bf16)v;
        }
    }
}

// ---------------- MFMA flash cross-attention, LP split x4 ----------------
// block = (bl, h, sp): online softmax over positions [sp*256, sp*256+256).
// Writes normalized fp32 partial O [bl][h][sp][64q][64d] + (m,l) per q-row.
__global__ __launch_bounds__(256) void attn3_k(const __bf16* __restrict__ Qb,
    const __bf16* __restrict__ Kb, const __bf16* __restrict__ Vtb,
    const int* __restrict__ seq, float* __restrict__ Op, float* __restrict__ Ml,
    int b0, int ldV)
{
    __shared__ __bf16 Ps[4][16][72];
    __shared__ float mask_s[256];
    const int t = threadIdx.x;
    const int bl = blockIdx.x >> 4, h = (blockIdx.x >> 2) & 3, sp = blockIdx.x & 3;
    const int b = b0 + bl;
    const int w = t >> 6, lane = t & 63;
    const int quad = lane >> 4, l16 = lane & 15;
    if (t < 256)
        mask_s[t] = (seq[b * LPN + sp * 256 + t] == 0) ? -1e9f : 0.f;
    const __bf16* qrow = Qb + (size_t)(b * 64 + w * 16 + l16) * HID + h * HD;
    bf16x8 aq0 = *(const bf16x8*)(qrow + quad * 8);
    bf16x8 aq1 = *(const bf16x8*)(qrow + 32 + quad * 8);
    float m_run[4] = {-3e38f, -3e38f, -3e38f, -3e38f};
    float l_run[4] = {0.f, 0.f, 0.f, 0.f};
    floatx4 ctx[4] = {};
    __syncthreads();
    for (int kt = 0; kt < 4; kt++) {
        const int kp0 = sp * 256 + kt * 64;
        floatx4 s[4];
#pragma unroll
        for (int nj = 0; nj < 4; nj++) {
            const __bf16* krow = Kb + (size_t)(bl * LPN + kp0 + nj * 16 + l16) * HID + h * HD;
            bf16x8 bk0 = *(const bf16x8*)(krow + quad * 8);
            bf16x8 bk1 = *(const bf16x8*)(krow + 32 + quad * 8);
            floatx4 z = {0.f, 0.f, 0.f, 0.f};
            s[nj] = __builtin_amdgcn_mfma_f32_16x16x32_bf16(aq0, bk0, z, 0, 0, 0);
            s[nj] = __builtin_amdgcn_mfma_f32_16x16x32_bf16(aq1, bk1, s[nj], 0, 0, 0);
        }
#pragma unroll
        for (int nj = 0; nj < 4; nj++) {
            float mval = mask_s[kt * 64 + nj * 16 + l16];
#pragma unroll
            for (int r = 0; r < 4; r++) s[nj][r] += mval;
        }
        float alpha[4];
#pragma unroll
        for (int r = 0; r < 4; r++) {
            float mx = fmaxf(fmaxf(s[0][r], s[1][r]), fmaxf(s[2][r], s[3][r]));
#pragma unroll
            for (int off = 1; off < 16; off <<= 1) mx = fmaxf(mx, __shfl_xor(mx, off, 64));
            float mn = fmaxf(m_run[r], mx);
            alpha[r] = __expf(m_run[r] - mn);
            m_run[r] = mn;
            float rs = 0.f;
#pragma unroll
            for (int nj = 0; nj < 4; nj++) {
                float p = __expf(s[nj][r] - mn);
                s[nj][r] = p;
                rs += p;
            }
#pragma unroll
            for (int off = 1; off < 16; off <<= 1) rs += __shfl_xor(rs, off, 64);
            l_run[r] = l_run[r] * alpha[r] + rs;
        }
#pragma unroll
        for (int nj = 0; nj < 4; nj++)
#pragma unroll
            for (int r = 0; r < 4; r++)
                Ps[w][quad * 4 + r][nj * 16 + l16] = (__bf16)s[nj][r];
        bf16x8 pa0 = *(const bf16x8*)&Ps[w][l16][quad * 8];
        bf16x8 pa1 = *(const bf16x8*)&Ps[w][l16][32 + quad * 8];
#pragma unroll
        for (int dj = 0; dj < 4; dj++) {
#pragma unroll
            for (int r = 0; r < 4; r++) ctx[dj][r] *= alpha[r];
            const __bf16* vrow = Vtb + (size_t)(h * HD + dj * 16 + l16) * ldV + bl * LPN + kp0;
            bf16x8 bv0 = *(const bf16x8*)(vrow + quad * 8);
            bf16x8 bv1 = *(const bf16x8*)(vrow + 32 + quad * 8);
            ctx[dj] = __builtin_amdgcn_mfma_f32_16x16x32_bf16(pa0, bv0, ctx[dj], 0, 0, 0);
            ctx[dj] = __builtin_amdgcn_mfma_f32_16x16x32_bf16(pa1, bv1, ctx[dj], 0, 0, 0);
        }
    }
    const int base = ((bl * 4 + h) * 4 + sp) * 64;
#pragma unroll
    for (int dj = 0; dj < 4; dj++)
#pragma unroll
        for (int r = 0; r < 4; r++) {
            int q = w * 16 + quad * 4 + r;
            Op[(size_t)(base + q) * 64 + dj * 16 + l16] = ctx[dj][r] / l_run[r];
        }
    if (l16 == 0) {
#pragma unroll
        for (int r = 0; r < 4; r++) {
            int q = w * 16 + quad * 4 + r;
            Ml[(size_t)(base + q) * 2 + 0] = m_run[r];
            Ml[(size_t)(base + q) * 2 + 1] = l_run[r];
        }
    }
}

// combine 4 LP-split partials -> ctx bf16
__global__ __launch_bounds__(256) void combine_k(const float* __restrict__ Op,
    const float* __restrict__ Ml, __bf16* __restrict__ O, int b0)
{
    const int bl = blockIdx.x >> 6, q = blockIdx.x & 63;
    const int t = threadIdx.x;
    const int h = t >> 6, d = t & 63;
    const int base = (bl * 4 + h) * 4;
    float ms[4], ls[4], m = -3e38f;
#pragma unroll
    for (int sp = 0; sp < 4; sp++) {
        ms[sp] = Ml[(size_t)((base + sp) * 64 + q) * 2 + 0];
        ls[sp] = Ml[(size_t)((base + sp) * 64 + q) * 2 + 1];
        m = fmaxf(m, ms[sp]);
    }
    float L = 0.f, o = 0.f;
#pragma unroll
    for (int sp = 0; sp < 4; sp++) {
        float wgt = __expf(ms[sp] - m) * ls[sp];
        L += wgt;
        o += wgt * Op[(size_t)((base + sp) * 64 + q) * 64 + d];
    }
    O[((size_t)(b0 + bl) * 64 + q) * 256 + h * 64 + d] = (__bf16)(o / L);
}

// ---------------- LayerNorm(residual) ----------------
__device__ __forceinline__ float blockSum256(float v, float* red)
{
#pragma unroll
    for (int off = 32; off >= 1; off >>= 1) v += __shfl_down(v, off, 64);
    int wave = threadIdx.x >> 6, lane = threadIdx.x & 63;
    if (lane == 0) red[wave] = v;
    __syncthreads();
    float s = red[0] + red[1] + red[2] + red[3];
    __syncthreads();
    return s;
}

__global__ __launch_bounds__(256) void lnres_k(const float* __restrict__ A,
    const float* __restrict__ Bb, const float* __restrict__ g,
    const float* __restrict__ be, float* __restrict__ Y, __bf16* __restrict__ Yb)
{
    __shared__ float red[4];
    int r = blockIdx.x, t = threadIdx.x;
    float v = A[(size_t)r * 256 + t] + Bb[(size_t)r * 256 + t];
    float mean = blockSum256(v, red) * (1.f / 256.f);
    float d = v - mean;
    float var = blockSum256(d * d, red) * (1.f / 256.f);
    float o = d * rsqrtf(var + 1e-5f) * g[t] + be[t];
    Y[(size_t)r * 256 + t] = o;
    if (Yb) Yb[(size_t)r * 256 + t] = (__bf16)o;
}

// ---------------- fused head: mean-pool + fc1(relu) + fc2 ----------------
__global__ __launch_bounds__(256) void head_k(const float* __restrict__ Y,
    const float* __restrict__ fc1w, const float* __restrict__ fc1b,
    const float* __restrict__ fc2w, const float* __restrict__ fc2b,
    float* __restrict__ out)
{
    __shared__ float pooled[256];
    __shared__ float h[256];
    __shared__ float red[4];
    int b = blockIdx.x, t = threadIdx.x;
    float s = 0.f;
#pragma unroll 8
    for (int q = 0; q < 64; q++) s += Y[(size_t)(b * 64 + q) * 256 + t];
    pooled[t] = s / (64.f + 1e-6f);
    __syncthreads();
    float a = 0.f;
    for (int k = 0; k < 256; k += 4) {
        a += pooled[k + 0] * fc1w[(k + 0) * 256 + t];
        a += pooled[k + 1] * fc1w[(k + 1) * 256 + t];
        a += pooled[k + 2] * fc1w[(k + 2) * 256 + t];
        a += pooled[k + 3] * fc1w[(k + 3) * 256 + t];
    }
    h[t] = fmaxf(a + fc1b[t], 0.f);
    __syncthreads();
    float p = h[t] * fc2w[t];
    p = blockSum256(p, red);
    if (t == 0) out[b] = p + fc2b[0];
}

// ---------------- launch ----------------
extern "C" void kernel_launch(void* const* d_in, const int* in_sizes, int n_in,
                              void* d_out, int out_size, void* d_ws, size_t ws_size,
                              hipStream_t stream)
{
    const float* x     = (const float*)d_in[0];
    const int*   ei    = (const int*)d_in[1];
    const int*   pseq  = (const int*)d_in[3];
    const float* w1  = (const float*)d_in[4];
    const float* as1 = (const float*)d_in[5];
    const float* ad1 = (const float*)d_in[6];
    const float* b1  = (const float*)d_in[7];
    const float* w2  = (const float*)d_in[8];
    const float* as2 = (const float*)d_in[9];
    const float* ad2 = (const float*)d_in[10];
    const float* b2  = (const float*)d_in[11];
    const float* w3  = (const float*)d_in[12];
    const float* as3 = (const float*)d_in[13];
    const float* ad3 = (const float*)d_in[14];
    const float* b3  = (const float*)d_in[15];
    const float* emb    = (const float*)d_in[16];
    const float* conv_w = (const float*)d_in[17];
    const float* conv_b = (const float*)d_in[18];
    const float* wq = (const float*)d_in[19];
    const float* bq = (const float*)d_in[20];
    const float* wk = (const float*)d_in[21];
    const float* bk = (const float*)d_in[22];
    const float* wv = (const float*)d_in[23];
    const float* bv = (const float*)d_in[24];
    const float* wo = (const float*)d_in[25];
    const float* bo = (const float*)d_in[26];
    const float* ln1_g = (const float*)d_in[27];
    const float* ln1_b = (const float*)d_in[28];
    const float* ffw1  = (const float*)d_in[29];
    const float* ffb1  = (const float*)d_in[30];
    const float* ffw2  = (const float*)d_in[31];
    const float* ffb2  = (const float*)d_in[32];
    const float* ln2_g = (const float*)d_in[33];
    const float* ln2_b = (const float*)d_in[34];
    const float* fc1_w = (const float*)d_in[35];
    const float* fc1_b = (const float*)d_in[36];
    const float* fc2_w = (const float*)d_in[37];
    const float* fc2_b = (const float*)d_in[38];
    (void)in_sizes; (void)n_in; (void)out_size;

    char* ws = (char*)d_ws;
    size_t off = 0;
    auto alloc = [&](size_t bytes) -> char* {
        char* p = ws + off;
        off += (bytes + 255) & ~(size_t)255;
        return p;
    };
    // ---- fixed arena ----
    __bf16* hgb  = (__bf16*)alloc((size_t)NAT * 512 * 2);
    float* og    = (float*)alloc((size_t)NAT * 512 * 4);
    float* hb0   = (float*)alloc((size_t)NAT * 256 * 4);
    float* hb1   = (float*)alloc((size_t)NAT * 256 * 4);
    __bf16* xb   = (__bf16*)alloc((size_t)NAT * FIN * 2);
    __bf16* hbb  = (__bf16*)alloc((size_t)NAT * 256 * 2);
    __bf16* qbb  = (__bf16*)alloc((size_t)NAT * 256 * 2);
    __bf16* ctxbb= (__bf16*)alloc((size_t)NAT * 256 * 2);
    __bf16* ybb  = (__bf16*)alloc((size_t)NAT * 256 * 2);
    float* a_s   = (float*)alloc((size_t)NAT * 2 * 4);
    float* a_d   = (float*)alloc((size_t)NAT * 2 * 4);
    float* asd_p = (float*)alloc((size_t)16 * NAT * 4);
    int* deg     = (int*)alloc((size_t)NAT * 4);
    int* fill    = (int*)alloc((size_t)NAT * 4);
    int* rowptr  = (int*)alloc((size_t)(NAT + 1) * 4);
    int* csrc    = (int*)alloc((size_t)NED * 4);
    __bf16* embb = (__bf16*)alloc((size_t)22 * 256 * 2);
    __bf16* wtb  = (__bf16*)alloc((size_t)256 * 768 * 2);
    __bf16* zpad = (__bf16*)alloc(256);
    __bf16* w1T  = (__bf16*)alloc((size_t)512 * 64 * 2);
    __bf16* w2T  = (__bf16*)alloc((size_t)512 * 256 * 2);
    __bf16* w3T  = (__bf16*)alloc((size_t)512 * 256 * 2);
    __bf16* wkT  = (__bf16*)alloc((size_t)256 * 256 * 2);
    __bf16* wvT  = (__bf16*)alloc((size_t)256 * 256 * 2);
    __bf16* wqT  = (__bf16*)alloc((size_t)256 * 256 * 2);
    __bf16* woT  = (__bf16*)alloc((size_t)256 * 256 * 2);
    __bf16* f1T  = (__bf16*)alloc((size_t)1024 * 256 * 2);
    __bf16* f2T  = (__bf16*)alloc((size_t)256 * 1024 * 2);
    // ---- variable region ----
    size_t fixed_end = off;
    size_t rem = (ws_size > fixed_end) ? ws_size - fixed_end : 0;
    const size_t G1 = (size_t)LPN * 256 * 2;               // 0.5 MB: pconv/K/Vt per graph
    const size_t P1 = (size_t)4 * 4 * 64 * 64 * 4;         // 256 KB: partial O per graph
    const size_t M1 = (size_t)4 * 4 * 64 * 2 * 4;          // 8 KB: m,l per graph
    const size_t ffneed = (size_t)NAT * 1024 * 2 + (size_t)NAT * 256 * 4;
    int CB = 8;
    {
        const int cands[6] = {256, 128, 64, 32, 16, 8};
        for (int ci = 0; ci < 6; ci++) {
            size_t regneed = (size_t)cands[ci] * (3 * G1 + P1 + M1);
            if (regneed < ffneed) regneed = ffneed;
            if (regneed <= rem) { CB = cands[ci]; break; }
        }
    }
    char* region   = ws + fixed_end;
    __bf16* pconvb = (__bf16*)region;
    __bf16* kbb    = (__bf16*)(region + (size_t)CB * G1);
    __bf16* vtb    = (__bf16*)(region + 2 * (size_t)CB * G1);
    float*  opart  = (float*)(region + 3 * (size_t)CB * G1);
    float*  mlpart = (float*)(region + (size_t)CB * (3 * G1 + P1));
    __bf16* ffbb   = (__bf16*)region;
    float*  y2     = (float*)(region + (size_t)NAT * 1024 * 2);
    float* attno = og;
    float* ybuf  = og + (size_t)NAT * 256;
    float* ff2o  = hb1;

    // ---------------- CSR build + zero page ----------------
    hipMemsetAsync(deg, 0, (size_t)NAT * 8, stream);   // deg + fill (adjacent)
    hipMemsetAsync(zpad, 0, 256, stream);
    deg_k<<<NED / 256, 256, 0, stream>>>(ei, deg);
    scan_k<<<1, 256, 0, stream>>>(deg, rowptr);
    scat_k<<<NED / 256, 256, 0, stream>>>(ei, fill, rowptr, csrc);

    // ---------------- all conversions in one dispatch ----------------
    {
        Segs S;
        const float* srcs[12] = {x, emb, conv_w, w1, w2, w3, wk, wv, wq, wo, ffw1, ffw2};
        __bf16* dsts[12] = {xb, embb, wtb, w1T, w2T, w3T, wkT, wvT, wqT, woT, f1T, f2T};
        int kd[12] = {0, 0, 0, 64, 256, 256, 256, 256, 256, 256, 256, 1024};
        int nd[12] = {0, 0, 0, 512, 512, 512, 256, 256, 256, 256, 1024, 256};
        int md[12] = {0, 0, 2, 1, 1, 1, 1, 1, 1, 1, 1, 1};
        int cnt[12] = {NAT * FIN, 22 * 256, 196608, 32768, 131072, 131072,
                       65536, 65536, 65536, 65536, 262144, 262144};
        int run = 0;
        for (int i = 0; i < 12; i++) {
            S.src[i] = srcs[i]; S.dst[i] = dsts[i];
            S.kdim[i] = kd[i]; S.ndim[i] = nd[i]; S.mode[i] = md[i];
            S.start[i] = run; run += cnt[i];
        }
        S.start[12] = run;
        cvtall_k<<<(run + 255) / 256, 256, 0, stream>>>(S, run);
    }

    // ---------------- ligand GNN: 3 GAT layers ----------------
    const __bf16* WT[3] = {w1T, w2T, w3T};
    const float* asl[3] = {as1, as2, as3};
    const float* adl[3] = {ad1, ad2, ad3};
    const float* bl[3]  = {b1, b2, b3};
    float* houts[3] = {nullptr, nullptr, hb0};
    const __bf16* hinb = xb;
    int Kdim = FIN;
    for (int l = 0; l < 3; l++) {
        gemm_gat<<<dim3(4, NAT / 128), 512, 0, stream>>>(hinb, WT[l], asl[l], adl[l], hgb, asd_p, Kdim);
        fold_k<<<NAT / 256, 256, 0, stream>>>(asd_p, a_s, a_d);
        gat_agg<<<NAT / 4, 256, 0, stream>>>(rowptr, csrc, hgb, a_s, a_d, bl[l], houts[l], hbb);
        hinb = hbb;
        Kdim = HID;
    }
    const float* lig = hb0;
    const __bf16* ligb = hbb;

    // ---------------- Q projection (scale 1/8 folded in) ----------------
    gemm_mfma<0, 1, 0><<<dim3(2, NAT / 128), 512, 0, stream>>>(ligb, wqT, bq, qbb, NAT, 256, 256, 0.125f);

    // ---------------- protein branch + attention, chunked over graphs ----------
    for (int b0 = 0; b0 < BGR; b0 += CB) {
        int Mc = CB * LPN;
        conv_mfma<<<dim3(2, Mc / 128), 512, 0, stream>>>(pseq, embb, wtb, conv_b, pconvb, b0, zpad);
        kv_mfma<<<dim3(Mc / 128, 2, 2), 512, 0, stream>>>(pconvb, wkT, wvT, bk, bv, kbb, vtb, Mc);
        attn3_k<<<CB * 16, 256, 0, stream>>>(qbb, kbb, vtb, pseq, opart, mlpart, b0, Mc);
        combine_k<<<CB * 64, 256, 0, stream>>>(opart, mlpart, ctxbb, b0);
    }

    // ---------------- attention out proj + LN + FFN + LN ----------------
    gemm_mfma<0, 0, 0><<<dim3(2, NAT / 128), 512, 0, stream>>>(ctxbb, woT, bo, attno, NAT, 256, 256, 1.f);
    lnres_k<<<NAT, 256, 0, stream>>>(lig, attno, ln1_g, ln1_b, ybuf, ybb);
    gemm_mfma<2, 1, 0><<<dim3(8, NAT / 128), 512, 0, stream>>>(ybb, f1T, ffb1, ffbb, NAT, 1024, 256, 1.f);
    gemm_mfma<0, 0, 0><<<dim3(2, NAT / 128), 512, 0, stream>>>(ffbb, f2T, ffb2, ff2o, NAT, 256, 1024, 1.f);
    lnres_k<<<NAT, 256, 0, stream>>>(ybuf, ff2o, ln2_g, ln2_b, y2, nullptr);

    // ---------------- fused head ----------------
    head_k<<<BGR, 256, 0, stream>>>(y2, fc1_w, fc1_b, fc2_w, fc2_b, (float*)d_out);
}